// Round 2
// baseline (1603.909 us; speedup 1.0000x reference)
//
#include <hip/hip_runtime.h>
#include <hip/hip_fp16.h>

// AdaAttN fused pipeline, fp16 MFMA path, single-pass flash attention.
// B=8, C=512, Tc=8192, Ts=2048.
//
// ws layout (bytes):
//   Ft  [8][8192][512] fp16 :      0 .. 67,108,864
//   Gt  [8][2048][512] fp16 : 67,108,864 .. 83,886,080
//   H   [8][512][2048] fp16 : 83,886,080 .. 100,663,296
//   cmean [4096] f32        : 100,663,296
//   crstd [4096] f32        : 100,679,680
// total ~96 MB (unchanged from proven round-1 footprint).

#define B_ 8
#define C_ 512
#define TC 8192
#define TS 2048

typedef unsigned short u16;
typedef __attribute__((ext_vector_type(8))) _Float16 f16x8;
typedef __attribute__((ext_vector_type(4))) float f32x4;

__device__ __forceinline__ u16 f2h(float f) {
  return __half_as_ushort(__float2half(f));
}

__device__ __forceinline__ f32x4 mfma16(f16x8 a, f16x8 b, f32x4 c) {
  return __builtin_amdgcn_mfma_f32_16x16x32_f16(a, b, c, 0, 0, 0);
}

// ---------------- K0: per-(b,c) content stats (ddof=1) ----------------
__global__ __launch_bounds__(256) void k_content_stats(
    const float* __restrict__ x, float* __restrict__ cmean, float* __restrict__ crstd) {
  const int row = blockIdx.x;  // b*512 + c
  const float4* p = (const float4*)(x + (size_t)row * TC);
  float s = 0.f, ss = 0.f;
  for (int i = threadIdx.x; i < TC / 4; i += 256) {
    float4 v = p[i];
    s += v.x + v.y + v.z + v.w;
    ss += v.x * v.x + v.y * v.y + v.z * v.z + v.w * v.w;
  }
#pragma unroll
  for (int d = 1; d < 64; d <<= 1) {
    s += __shfl_xor(s, d);
    ss += __shfl_xor(ss, d);
  }
  __shared__ float rs[4], rss[4];
  if ((threadIdx.x & 63) == 0) {
    rs[threadIdx.x >> 6] = s;
    rss[threadIdx.x >> 6] = ss;
  }
  __syncthreads();
  if (threadIdx.x == 0) {
    float S = rs[0] + rs[1] + rs[2] + rs[3];
    float SS = rss[0] + rss[1] + rss[2] + rss[3];
    float mean = S / (float)TC;
    float var = (SS - S * mean) / (float)(TC - 1);
    cmean[row] = mean;
    crstd[row] = rsqrtf(var + 1e-5f);
  }
}

// ---------------- conv1x1 GEMM: Y[m][n] = sum_k X[k][m] * W[n][k] + bias[n] ----
// BM=64, BN=256, BK=64; 4 waves; wave w owns n-range w*64.
template <bool TRANS_OUT>
__global__ __launch_bounds__(256, 3) void k_conv(
    const float* __restrict__ X, const float* __restrict__ W,
    const float* __restrict__ bias, u16* __restrict__ Y, int M) {
  const int b = blockIdx.z;
  const int m0 = blockIdx.x * 64;
  const int n0 = blockIdx.y * 256;
  const int tid = threadIdx.x;
  const int w = tid >> 6, ln = tid & 63, lg = ln >> 4, l15 = ln & 15;
  __shared__ u16 As[64][72];
  __shared__ u16 Bs[256][72];
  const float* Xb = X + (size_t)b * C_ * M;
  const f32x4 vzero = {0.f, 0.f, 0.f, 0.f};
  f32x4 acc[4][4];
#pragma unroll
  for (int i = 0; i < 4; ++i)
#pragma unroll
    for (int j = 0; j < 4; ++j) acc[i][j] = vzero;

  for (int k0 = 0; k0 < 512; k0 += 64) {
    __syncthreads();
    {  // stage A: X[k0..+64][m0..+64] -> As[m][k] (transpose + cvt)
      const int kk = tid >> 2, c4 = tid & 3;
      const float* src = Xb + (size_t)(k0 + kk) * M + m0 + c4 * 16;
#pragma unroll
      for (int i = 0; i < 4; ++i) {
        float4 v = *(const float4*)(src + i * 4);
        const int mo = c4 * 16 + i * 4;
        As[mo + 0][kk] = f2h(v.x);
        As[mo + 1][kk] = f2h(v.y);
        As[mo + 2][kk] = f2h(v.z);
        As[mo + 3][kk] = f2h(v.w);
      }
    }
    {  // stage B: W[n0..+256][k0..+64] -> Bs[n][k]
      const float* src = W + (size_t)(n0 + tid) * 512 + k0;
#pragma unroll
      for (int i = 0; i < 16; ++i) {
        float4 v = *(const float4*)(src + i * 4);
        ushort4 hq = make_ushort4(f2h(v.x), f2h(v.y), f2h(v.z), f2h(v.w));
        *(ushort4*)&Bs[tid][i * 4] = hq;
      }
    }
    __syncthreads();
#pragma unroll
    for (int ks = 0; ks < 2; ++ks) {
      f16x8 a[4], bb[4];
#pragma unroll
      for (int mt = 0; mt < 4; ++mt)
        a[mt] = *(const f16x8*)&As[mt * 16 + l15][ks * 32 + lg * 8];
#pragma unroll
      for (int nt = 0; nt < 4; ++nt)
        bb[nt] = *(const f16x8*)&Bs[w * 64 + nt * 16 + l15][ks * 32 + lg * 8];
#pragma unroll
      for (int mt = 0; mt < 4; ++mt)
#pragma unroll
        for (int nt = 0; nt < 4; ++nt)
          acc[mt][nt] = mfma16(a[mt], bb[nt], acc[mt][nt]);
    }
  }
  // epilogue: C row = lg*4 + reg (+16*mt), col = l15 (+16*nt +64*w)
#pragma unroll
  for (int nt = 0; nt < 4; ++nt) {
    const int n = n0 + w * 64 + nt * 16 + l15;
    const float bv = bias[n];
#pragma unroll
    for (int mt = 0; mt < 4; ++mt) {
      const int mb = m0 + mt * 16 + lg * 4;
      f32x4 v = acc[mt][nt];
      if (!TRANS_OUT) {
        u16* yp = Y + (size_t)b * M * 512 + (size_t)mb * 512 + n;
        yp[0 * 512] = f2h(v[0] + bv);
        yp[1 * 512] = f2h(v[1] + bv);
        yp[2 * 512] = f2h(v[2] + bv);
        yp[3 * 512] = f2h(v[3] + bv);
      } else {
        ushort4 hq = make_ushort4(f2h(v[0] + bv), f2h(v[1] + bv),
                                  f2h(v[2] + bv), f2h(v[3] + bv));
        *(ushort4*)(Y + (size_t)b * 512 * M + (size_t)n * M + mb) = hq;
      }
    }
  }
}

// ---------------- K5: single-pass flash attention + AdaAttN epilogue ----------------
// block = 512 thr (8 waves), (b, 64 query rows). s-tile = 256, 8 tiles.
// Wave w: QK^T cols w*32..+32 of tile; PV c-slice w*64..+64.
// G/H staged wave-privately (reg-staged, double-buffered 2KB chunks, no barriers);
// only softmax reduce + shared P tile use __syncthreads (3 per tile).
__global__ __launch_bounds__(512, 2) void k_attn(
    const u16* __restrict__ Ft, const u16* __restrict__ Gt,
    const u16* __restrict__ Hm, const float* __restrict__ content,
    const float* __restrict__ cmean, const float* __restrict__ crstd,
    float* __restrict__ out) {
  __shared__ u16 Fq[64 * 512];    // swizzled: granule' = (g&56)|((g^row)&7)
  __shared__ u16 U[8 * 2048];     // per-wave 2-buf G/H chunks [32 rows][4 gran], rotate swz
  __shared__ u16 Ps[64 * 256];    // swizzled like Fq (5-bit granule)
  __shared__ float red[64][8][2]; // per-tile partial (max, sum) per wave
  __shared__ float fin[64][4];    // (m_new, factor, invl, -)

  const int b = blockIdx.y;
  const int t0 = blockIdx.x * 64;
  const int tid = threadIdx.x;
  const int w = tid >> 6, ln = tid & 63, lg = ln >> 4, l15 = ln & 15;

  const u16* Ftb = Ft + ((size_t)b * TC + t0) * C_;
  const u16* Gtb = Gt + (size_t)b * TS * C_;
  const u16* Hb = Hm + (size_t)b * C_ * TS;

  u16* Uw = U + w * 2048;              // wave-private 2 x 1024 u16 buffers
  const int r2 = ln >> 2;              // staging row-part (0..15)
  const int q4 = ln & 3;               // staging linear granule-in-row
  const int jsw = ((ln & 3) + ((ln >> 3) & 3)) & 3;  // staging swizzled granule

  auto loadG = [&](int st_, int kc, uint4* r) {
    const int sb = st_ * 256 + w * 32;
    const u16* p0 = Gtb + (size_t)(sb + r2) * C_ + kc * 32 + q4 * 8;
    r[0] = *(const uint4*)p0;
    r[1] = *(const uint4*)(p0 + 16 * C_);
  };
  auto loadH = [&](int st_, int cc, uint4* r) {
    const int cb = w * 64 + (cc & 1) * 32;
    const int sb = st_ * 256 + (cc >> 1) * 32;
    const u16* p0 = Hb + (size_t)(cb + r2) * TS + sb + q4 * 8;
    r[0] = *(const uint4*)p0;
    r[1] = *(const uint4*)(p0 + 16 * TS);
  };
  auto writeChunk = [&](int buf, const uint4* r) {
    u16* d = Uw + buf * 1024 + (r2 * 4 + jsw) * 8;
    *(uint4*)d = r[0];
    *(uint4*)(d + 512) = r[1];  // second instr: rows +16 -> slot +64 granules
  };
  auto readA = [&](int mt, int kc) -> f16x8 {
    const int row = mt * 16 + l15;
    const int gr = kc * 4 + lg;
    const int sw = (gr & 56) | ((gr ^ row) & 7);
    return *(const f16x8*)&Fq[row * 512 + sw * 8];
  };
  auto readU = [&](int buf, int nt) -> f16x8 {  // G B-frag / H B-frag
    const int sr = nt * 16 + l15;
    const int slot = sr * 4 + ((lg + (sr >> 1)) & 3);
    return *(const f16x8*)&Uw[buf * 1024 + slot * 8];
  };
  auto readPa = [&](int mt, int ksl) -> f16x8 {
    const int row = mt * 16 + l15;
    const int gr = ksl * 4 + lg;
    const int sw = (gr & 24) | ((gr ^ row) & 7);
    return *(const f16x8*)&Ps[row * 256 + sw * 8];
  };

  // ---- prologue ----
  uint4 rG[2][2], rH[2][2];
  loadG(0, 0, rG[0]);
  loadG(0, 1, rG[1]);
  {  // stage Fq (linear global read, swizzled LDS write)
    const int r = tid >> 3, c0 = tid & 7;
    const u16* src = Ftb + (size_t)r * C_;
#pragma unroll
    for (int i = 0; i < 8; ++i) {
      const int j = c0 + 8 * i;
      uint4 v = *(const uint4*)(src + j * 8);
      const int sw = (j & 56) | ((j ^ r) & 7);
      *(uint4*)&Fq[r * 512 + sw * 8] = v;
    }
  }
  writeChunk(0, rG[0]);
  __syncthreads();

  const f32x4 vzero = {0.f, 0.f, 0.f, 0.f};
  f32x4 pvm[4][4], pvs[4][4];
#pragma unroll
  for (int mt = 0; mt < 4; ++mt)
#pragma unroll
    for (int nt = 0; nt < 4; ++nt) {
      pvm[mt][nt] = vzero;
      pvs[mt][nt] = vzero;
    }
  float m_run = -1e30f, l_run = 0.f;  // owned by lanes ln<8 (row = w*8+ln)

  for (int st = 0; st < 8; ++st) {
    // ---- QK^T: 16 k-chunks of 32, wave-private staged, no barriers ----
    f32x4 sacc[4][2];
#pragma unroll
    for (int mt = 0; mt < 4; ++mt) {
      sacc[mt][0] = vzero;
      sacc[mt][1] = vzero;
    }
#pragma unroll
    for (int kc = 0; kc < 16; ++kc) {
      const int buf = kc & 1;
      f16x8 a0 = readA(0, kc), a1 = readA(1, kc), a2 = readA(2, kc), a3 = readA(3, kc);
      f16x8 b0 = readU(buf, 0), b1 = readU(buf, 1);
      sacc[0][0] = mfma16(a0, b0, sacc[0][0]);
      sacc[1][0] = mfma16(a1, b0, sacc[1][0]);
      sacc[2][0] = mfma16(a2, b0, sacc[2][0]);
      sacc[3][0] = mfma16(a3, b0, sacc[3][0]);
      sacc[0][1] = mfma16(a0, b1, sacc[0][1]);
      sacc[1][1] = mfma16(a1, b1, sacc[1][1]);
      sacc[2][1] = mfma16(a2, b1, sacc[2][1]);
      sacc[3][1] = mfma16(a3, b1, sacc[3][1]);
      if (kc < 15) writeChunk(buf ^ 1, rG[(kc + 1) & 1]);
      if (kc < 14) loadG(st, kc + 2, rG[kc & 1]);
      else if (kc == 14) loadH(st, 0, rH[0]);
      else loadH(st, 1, rH[1]);
    }
    writeChunk(0, rH[0]);  // H chunk 0 -> buf0 (overlaps softmax barriers)

    // ---- per-wave partial row stats over this wave's 32 cols ----
#pragma unroll
    for (int mt = 0; mt < 4; ++mt)
#pragma unroll
      for (int rg = 0; rg < 4; ++rg) {
        float v0 = sacc[mt][0][rg], v1 = sacc[mt][1][rg];
        float mx = fmaxf(v0, v1);
        mx = fmaxf(mx, __shfl_xor(mx, 1));
        mx = fmaxf(mx, __shfl_xor(mx, 2));
        mx = fmaxf(mx, __shfl_xor(mx, 4));
        mx = fmaxf(mx, __shfl_xor(mx, 8));
        float sm = __expf(v0 - mx) + __expf(v1 - mx);
        sm += __shfl_xor(sm, 1);
        sm += __shfl_xor(sm, 2);
        sm += __shfl_xor(sm, 4);
        sm += __shfl_xor(sm, 8);
        if (l15 == 0)
          *(float2*)&red[mt * 16 + lg * 4 + rg][w][0] = make_float2(mx, sm);
      }
    __syncthreads();  // [A]

    // ---- online merge (8 lanes/wave, row = w*8+ln) ----
    if (ln < 8) {
      const int row = w * 8 + ln;
      float m_new = m_run;
#pragma unroll
      for (int j = 0; j < 8; ++j) m_new = fmaxf(m_new, red[row][j][0]);
      float l_new = l_run * __expf(m_run - m_new);
#pragma unroll
      for (int j = 0; j < 8; ++j)
        l_new += red[row][j][1] * __expf(red[row][j][0] - m_new);
      fin[row][0] = m_new;
      fin[row][1] = __expf(m_run - m_new);
      if (st == 7) fin[row][2] = 1.f / l_new;
      m_run = m_new;
      l_run = l_new;
    }
    __syncthreads();  // [B]

    // ---- rescale accumulators, write P = exp(s - m) (<=1, fp16) ----
#pragma unroll
    for (int mt = 0; mt < 4; ++mt) {
      float mrow[4];
      f32x4 fac;
#pragma unroll
      for (int rg = 0; rg < 4; ++rg) {
        const int row = mt * 16 + lg * 4 + rg;
        float2 v = *(const float2*)&fin[row][0];
        mrow[rg] = v.x;
        fac[rg] = v.y;
      }
#pragma unroll
      for (int nt = 0; nt < 4; ++nt) {
        pvm[mt][nt] *= fac;
        pvs[mt][nt] *= fac;
      }
#pragma unroll
      for (int nt = 0; nt < 2; ++nt)
#pragma unroll
        for (int rg = 0; rg < 4; ++rg) {
          const int row = mt * 16 + lg * 4 + rg;
          const int s = w * 32 + nt * 16 + l15;
          const int gr = s >> 3;
          const int sw = (gr & 24) | ((gr ^ row) & 7);
          Ps[row * 256 + sw * 8 + (s & 7)] =
              f2h(__expf(sacc[mt][nt][rg] - mrow[rg]));
        }
    }
    __syncthreads();  // [C]

    // ---- PV: 16 sub-chunks (ksl 0..7 x c-half 0..1), wave-private H staging ----
    f16x8 pa0, pa1, pa2, pa3;
#pragma unroll
    for (int ss = 0; ss < 16; ++ss) {
      const int ksl = ss >> 1, h = ss & 1, buf = ss & 1;
      if (h == 0) {
        pa0 = readPa(0, ksl);
        pa1 = readPa(1, ksl);
        pa2 = readPa(2, ksl);
        pa3 = readPa(3, ksl);
      }
      f16x8 hv0 = readU(buf, 0), hv1 = readU(buf, 1);
      f16x8 g0 = hv0 * hv0, g1 = hv1 * hv1;
      const int n0i = h * 2, n1i = h * 2 + 1;
      pvm[0][n0i] = mfma16(pa0, hv0, pvm[0][n0i]);
      pvm[1][n0i] = mfma16(pa1, hv0, pvm[1][n0i]);
      pvm[2][n0i] = mfma16(pa2, hv0, pvm[2][n0i]);
      pvm[3][n0i] = mfma16(pa3, hv0, pvm[3][n0i]);
      pvs[0][n0i] = mfma16(pa0, g0, pvs[0][n0i]);
      pvs[1][n0i] = mfma16(pa1, g0, pvs[1][n0i]);
      pvs[2][n0i] = mfma16(pa2, g0, pvs[2][n0i]);
      pvs[3][n0i] = mfma16(pa3, g0, pvs[3][n0i]);
      pvm[0][n1i] = mfma16(pa0, hv1, pvm[0][n1i]);
      pvm[1][n1i] = mfma16(pa1, hv1, pvm[1][n1i]);
      pvm[2][n1i] = mfma16(pa2, hv1, pvm[2][n1i]);
      pvm[3][n1i] = mfma16(pa3, hv1, pvm[3][n1i]);
      pvs[0][n1i] = mfma16(pa0, g1, pvs[0][n1i]);
      pvs[1][n1i] = mfma16(pa1, g1, pvs[1][n1i]);
      pvs[2][n1i] = mfma16(pa2, g1, pvs[2][n1i]);
      pvs[3][n1i] = mfma16(pa3, g1, pvs[3][n1i]);
      if (ss < 15) writeChunk(buf ^ 1, rH[(ss + 1) & 1]);
      if (ss < 14) loadH(st, ss + 2, rH[ss & 1]);
      else if (ss == 14) loadG((st + 1) & 7, 0, rG[0]);
      else loadG((st + 1) & 7, 1, rG[1]);
    }
    if (st < 7) writeChunk(0, rG[0]);  // next tile's G chunk 0 -> buf0
  }

  // ---- epilogue: out[b][c][t] = std * (content - cm)*cr + mean ----
  f32x4 invq[4];
#pragma unroll
  for (int mt = 0; mt < 4; ++mt)
#pragma unroll
    for (int rg = 0; rg < 4; ++rg)
      invq[mt][rg] = fin[mt * 16 + lg * 4 + rg][2];
#pragma unroll
  for (int nt = 0; nt < 4; ++nt) {
    const int c = w * 64 + nt * 16 + l15;
    const size_t row = (size_t)b * C_ + c;
    const float cm = cmean[row];
    const float cr = crstd[row];
    const float* cp = content + row * TC + t0;
    float* op = out + row * TC + t0;
#pragma unroll
    for (int mt = 0; mt < 4; ++mt) {
      const int q0 = mt * 16 + lg * 4;
      const float4 x = *(const float4*)(cp + q0);
      const f32x4 mu = pvm[mt][nt] * invq[mt];
      const f32x4 se = pvs[mt][nt] * invq[mt];
      float4 y;
      y.x = sqrtf(fmaxf(se[0] - mu[0] * mu[0], 0.f)) * ((x.x - cm) * cr) + mu[0];
      y.y = sqrtf(fmaxf(se[1] - mu[1] * mu[1], 0.f)) * ((x.y - cm) * cr) + mu[1];
      y.z = sqrtf(fmaxf(se[2] - mu[2] * mu[2], 0.f)) * ((x.z - cm) * cr) + mu[2];
      y.w = sqrtf(fmaxf(se[3] - mu[3] * mu[3], 0.f)) * ((x.w - cm) * cr) + mu[3];
      *(float4*)(op + q0) = y;
    }
  }
}

extern "C" void kernel_launch(void* const* d_in, const int* in_sizes, int n_in,
                              void* d_out, int out_size, void* d_ws, size_t ws_size,
                              hipStream_t stream) {
  (void)in_sizes;
  (void)n_in;
  (void)out_size;
  (void)ws_size;  // needs ~96 MB
  const float* content = (const float*)d_in[0];
  const float* style = (const float*)d_in[1];
  const float* content_key = (const float*)d_in[2];
  const float* style_key = (const float*)d_in[3];
  const float* Wf = (const float*)d_in[4];
  const float* bf = (const float*)d_in[5];
  const float* Wg = (const float*)d_in[6];
  const float* bg = (const float*)d_in[7];
  const float* Wh = (const float*)d_in[8];
  const float* bh = (const float*)d_in[9];
  float* out = (float*)d_out;

  char* ws = (char*)d_ws;
  u16* Ft = (u16*)(ws);
  u16* Gt = (u16*)(ws + 67108864);
  u16* Hm = (u16*)(ws + 83886080);
  float* cmean = (float*)(ws + 100663296);
  float* crstd = (float*)(ws + 100663296 + 16384);

  k_content_stats<<<dim3(B_ * C_), dim3(256), 0, stream>>>(content, cmean, crstd);
  // Ft[b][t][c] = conv(Wf, content_key)
  k_conv<false><<<dim3(TC / 64, 2, B_), dim3(256), 0, stream>>>(content_key, Wf, bf, Ft, TC);
  // Gt[b][s][c] = conv(Wg, style_key)
  k_conv<false><<<dim3(TS / 64, 2, B_), dim3(256), 0, stream>>>(style_key, Wg, bg, Gt, TS);
  // H[b][c][s] = conv(Wh, style)  (transposed store)
  k_conv<true><<<dim3(TS / 64, 2, B_), dim3(256), 0, stream>>>(style, Wh, bh, Hm, TS);

  k_attn<<<dim3(TC / 64, B_), dim3(512), 0, stream>>>(Ft, Gt, Hm, content, cmean, crstd, out);
}

// Round 3
// 1064.674 us; speedup vs baseline: 1.5065x; 1.5065x over previous
//
#include <hip/hip_runtime.h>
#include <hip/hip_fp16.h>

// AdaAttN fused pipeline, fp16 MFMA path, single-pass flash attention.
// B=8, C=512, Tc=8192, Ts=2048.
//
// ws layout (bytes):
//   Ft  [8][8192][512] fp16 :      0 .. 67,108,864
//   Gt  [8][2048][512] fp16 : 67,108,864 .. 83,886,080
//   H   [8][512][2048] fp16 : 83,886,080 .. 100,663,296
//   cmean [4096] f32        : 100,663,296
//   crstd [4096] f32        : 100,679,680

#define B_ 8
#define C_ 512
#define TC 8192
#define TS 2048

typedef unsigned short u16;
typedef __attribute__((ext_vector_type(8))) _Float16 f16x8;
typedef __attribute__((ext_vector_type(4))) float f32x4;

__device__ __forceinline__ u16 f2h(float f) {
  return __half_as_ushort(__float2half(f));
}

__device__ __forceinline__ f32x4 mfma16(f16x8 a, f16x8 b, f32x4 c) {
  return __builtin_amdgcn_mfma_f32_16x16x32_f16(a, b, c, 0, 0, 0);
}

// async global->LDS, 16B per lane; LDS dest = wave-uniform base + lane*16
__device__ __forceinline__ void stage16(const u16* g, u16* l) {
  __builtin_amdgcn_global_load_lds(
      (__attribute__((address_space(1))) void*)(const void*)g,
      (__attribute__((address_space(3))) void*)l, 16, 0, 0);
}

// raw barrier: flush LDS ops, no vmcnt drain (keeps staging loads in flight)
#define BARSYNC()                                         \
  do {                                                    \
    asm volatile("s_waitcnt lgkmcnt(0)" ::: "memory");    \
    __builtin_amdgcn_s_barrier();                         \
    __builtin_amdgcn_sched_barrier(0);                    \
  } while (0)

// ---------------- K0: per-(b,c) content stats (ddof=1) ----------------
__global__ __launch_bounds__(256) void k_content_stats(
    const float* __restrict__ x, float* __restrict__ cmean, float* __restrict__ crstd) {
  const int row = blockIdx.x;  // b*512 + c
  const float4* p = (const float4*)(x + (size_t)row * TC);
  float s = 0.f, ss = 0.f;
  for (int i = threadIdx.x; i < TC / 4; i += 256) {
    float4 v = p[i];
    s += v.x + v.y + v.z + v.w;
    ss += v.x * v.x + v.y * v.y + v.z * v.z + v.w * v.w;
  }
#pragma unroll
  for (int d = 1; d < 64; d <<= 1) {
    s += __shfl_xor(s, d);
    ss += __shfl_xor(ss, d);
  }
  __shared__ float rs[4], rss[4];
  if ((threadIdx.x & 63) == 0) {
    rs[threadIdx.x >> 6] = s;
    rss[threadIdx.x >> 6] = ss;
  }
  __syncthreads();
  if (threadIdx.x == 0) {
    float S = rs[0] + rs[1] + rs[2] + rs[3];
    float SS = rss[0] + rss[1] + rss[2] + rss[3];
    float mean = S / (float)TC;
    float var = (SS - S * mean) / (float)(TC - 1);
    cmean[row] = mean;
    crstd[row] = rsqrtf(var + 1e-5f);
  }
}

// ---------------- conv1x1 GEMM (unchanged, verified) ----------------
template <bool TRANS_OUT>
__global__ __launch_bounds__(256, 3) void k_conv(
    const float* __restrict__ X, const float* __restrict__ W,
    const float* __restrict__ bias, u16* __restrict__ Y, int M) {
  const int b = blockIdx.z;
  const int m0 = blockIdx.x * 64;
  const int n0 = blockIdx.y * 256;
  const int tid = threadIdx.x;
  const int w = tid >> 6, ln = tid & 63, lg = ln >> 4, l15 = ln & 15;
  __shared__ u16 As[64][72];
  __shared__ u16 Bs[256][72];
  const float* Xb = X + (size_t)b * C_ * M;
  const f32x4 vzero = {0.f, 0.f, 0.f, 0.f};
  f32x4 acc[4][4];
#pragma unroll
  for (int i = 0; i < 4; ++i)
#pragma unroll
    for (int j = 0; j < 4; ++j) acc[i][j] = vzero;

  for (int k0 = 0; k0 < 512; k0 += 64) {
    __syncthreads();
    {  // stage A (transpose + cvt)
      const int kk = tid >> 2, c4 = tid & 3;
      const float* src = Xb + (size_t)(k0 + kk) * M + m0 + c4 * 16;
#pragma unroll
      for (int i = 0; i < 4; ++i) {
        float4 v = *(const float4*)(src + i * 4);
        const int mo = c4 * 16 + i * 4;
        As[mo + 0][kk] = f2h(v.x);
        As[mo + 1][kk] = f2h(v.y);
        As[mo + 2][kk] = f2h(v.z);
        As[mo + 3][kk] = f2h(v.w);
      }
    }
    {  // stage B
      const float* src = W + (size_t)(n0 + tid) * 512 + k0;
#pragma unroll
      for (int i = 0; i < 16; ++i) {
        float4 v = *(const float4*)(src + i * 4);
        ushort4 hq = make_ushort4(f2h(v.x), f2h(v.y), f2h(v.z), f2h(v.w));
        *(ushort4*)&Bs[tid][i * 4] = hq;
      }
    }
    __syncthreads();
#pragma unroll
    for (int ks = 0; ks < 2; ++ks) {
      f16x8 a[4], bb[4];
#pragma unroll
      for (int mt = 0; mt < 4; ++mt)
        a[mt] = *(const f16x8*)&As[mt * 16 + l15][ks * 32 + lg * 8];
#pragma unroll
      for (int nt = 0; nt < 4; ++nt)
        bb[nt] = *(const f16x8*)&Bs[w * 64 + nt * 16 + l15][ks * 32 + lg * 8];
#pragma unroll
      for (int mt = 0; mt < 4; ++mt)
#pragma unroll
        for (int nt = 0; nt < 4; ++nt)
          acc[mt][nt] = mfma16(a[mt], bb[nt], acc[mt][nt]);
    }
  }
#pragma unroll
  for (int nt = 0; nt < 4; ++nt) {
    const int n = n0 + w * 64 + nt * 16 + l15;
    const float bv = bias[n];
#pragma unroll
    for (int mt = 0; mt < 4; ++mt) {
      const int mb = m0 + mt * 16 + lg * 4;
      f32x4 v = acc[mt][nt];
      if (!TRANS_OUT) {
        u16* yp = Y + (size_t)b * M * 512 + (size_t)mb * 512 + n;
        yp[0 * 512] = f2h(v[0] + bv);
        yp[1 * 512] = f2h(v[1] + bv);
        yp[2 * 512] = f2h(v[2] + bv);
        yp[3 * 512] = f2h(v[3] + bv);
      } else {
        ushort4 hq = make_ushort4(f2h(v[0] + bv), f2h(v[1] + bv),
                                  f2h(v[2] + bv), f2h(v[3] + bv));
        *(ushort4*)(Y + (size_t)b * 512 * M + (size_t)n * M + mb) = hq;
      }
    }
  }
}

// ---------------- K5: flash attention, DMA-staged, barrier-light ----------------
// 512 thr (8 waves) per block, 64 q rows, s-tile 128 (16 tiles).
// QK: wave w owns s-cols w*16..+16 (G rows wave-private).
// PV: wave w owns c rows {ch*256 + w*32..+32} for ch in {0,1} (H rows wave-private).
// Staging: global_load_lds w16, source pre-swizzled; ledger = 2 loads/phase,
// wait vmcnt(2) at phase top. Barriers only around softmax (3/tile).
__global__ __launch_bounds__(512, 2) void k_attn(
    const u16* __restrict__ Ft, const u16* __restrict__ Gt,
    const u16* __restrict__ Hm, const float* __restrict__ content,
    const float* __restrict__ cmean, const float* __restrict__ crstd,
    float* __restrict__ out) {
  __shared__ u16 Fq[64 * 512];       // swizzled granule: (g&56)|((g^row)&7)
  __shared__ u16 UG[2][128 * 64];    // G chunk [128 s][64 c], granule g^(row&7)
  __shared__ u16 UH[2][256 * 32];    // H chunk [256 c][32 s], g^(row&3)^((row>>2)&3)
  __shared__ u16 Ps[64 * 128];       // swizzled granule: (g&8)|((g^row)&7)
  __shared__ float red[64][8][2];
  __shared__ float fin[64][4];

  const int bid = blockIdx.x;
  const int swz = (bid & 7) * 128 + (bid >> 3);  // XCD-contiguous (1024%8==0)
  const int b = swz >> 7;
  const int t0 = (swz & 127) * 64;
  const int tid = threadIdx.x;
  const int w = tid >> 6, ln = tid & 63, lg = ln >> 4, l15 = ln & 15;

  const u16* Ftb = Ft + ((size_t)b * TC + t0) * C_;
  const u16* Gtb = Gt + (size_t)b * TS * C_;
  const u16* Hb = Hm + (size_t)b * C_ * TS;

  // ---- Fq stage: linear global read, swizzled LDS write (verified r2) ----
  {
    const int r = tid >> 3, c0 = tid & 7;
    const u16* src = Ftb + (size_t)r * C_;
#pragma unroll
    for (int i = 0; i < 8; ++i) {
      const int j = c0 + 8 * i;
      uint4 v = *(const uint4*)(src + j * 8);
      const int sw = (j & 56) | ((j ^ r) & 7);
      *(uint4*)&Fq[r * 512 + sw * 8] = v;
    }
  }
  __syncthreads();  // full drain once; ledger starts clean

  auto stageG = [&](int st_, int kc, int bf) {
#pragma unroll
    for (int i = 0; i < 2; ++i) {
      const int row = w * 16 + i * 8 + (ln >> 3);
      const int g = (ln & 7) ^ ((ln >> 3) & 7);
      stage16(Gtb + (size_t)(st_ * 128 + row) * 512 + kc * 64 + g * 8,
              &UG[bf][(w * 16 + i * 8) * 64]);
    }
  };
  auto stageH = [&](int st_, int hc, int bf) {
    const int ch = hc >> 2, ksl = hc & 3;
#pragma unroll
    for (int i = 0; i < 2; ++i) {
      const int row = w * 32 + i * 16 + (ln >> 2);
      const int g = (ln & 3) ^ ((ln >> 2) & 3) ^ ((ln >> 4) & 3);
      stage16(Hb + (size_t)(ch * 256 + row) * TS + st_ * 128 + ksl * 32 + g * 8,
              &UH[bf][(w * 32 + i * 16) * 32]);
    }
  };
  auto readA = [&](int mt, int kq) -> f16x8 {  // kq = kc*2+ks in 0..15
    const int row = mt * 16 + l15;
    const int g = kq * 4 + lg;
    const int sw = (g & 56) | ((g ^ row) & 7);
    return *(const f16x8*)&Fq[row * 512 + sw * 8];
  };
  auto readG = [&](int bf, int ks) -> f16x8 {
    const int row = w * 16 + l15;
    const int sw = (ks * 4 + lg) ^ (row & 7);
    return *(const f16x8*)&UG[bf][row * 64 + sw * 8];
  };
  auto readH = [&](int bf, int nt) -> f16x8 {
    const int row = w * 32 + nt * 16 + l15;
    const int sw = lg ^ (row & 3) ^ ((row >> 2) & 3);
    return *(const f16x8*)&UH[bf][row * 32 + sw * 8];
  };
  auto readPa = [&](int mt, int ksl) -> f16x8 {
    const int row = mt * 16 + l15;
    const int g = ksl * 4 + lg;
    const int sw = (g & 8) | ((g ^ row) & 7);
    return *(const f16x8*)&Ps[row * 128 + sw * 8];
  };

  // prologue stages: tile 0, G chunks 0,1  (4 loads in flight)
  stageG(0, 0, 0);
  stageG(0, 1, 1);

  const f32x4 vzero = {0.f, 0.f, 0.f, 0.f};
  f32x4 pvm[4][2][2], pvs[4][2][2];
#pragma unroll
  for (int mt = 0; mt < 4; ++mt)
#pragma unroll
    for (int ch = 0; ch < 2; ++ch)
#pragma unroll
      for (int nt = 0; nt < 2; ++nt) {
        pvm[mt][ch][nt] = vzero;
        pvs[mt][ch][nt] = vzero;
      }
  float m_run = -1e30f, l_run = 0.f;  // live in lanes ln<8 (row = w*8+ln)

  for (int st = 0; st < 16; ++st) {
    const int stn = (st + 1) & 15;
    f32x4 sacc[4] = {vzero, vzero, vzero, vzero};

    // ---- QK: 8 chunks of K=64, no barriers (wave-private G) ----
#pragma unroll
    for (int kc = 0; kc < 8; ++kc) {
      asm volatile("s_waitcnt vmcnt(2)" ::: "memory");
      const int bf = kc & 1;
      __builtin_amdgcn_s_setprio(1);
#pragma unroll
      for (int ks = 0; ks < 2; ++ks) {
        f16x8 bb = readG(bf, ks);
        f16x8 a0 = readA(0, kc * 2 + ks), a1 = readA(1, kc * 2 + ks);
        f16x8 a2 = readA(2, kc * 2 + ks), a3 = readA(3, kc * 2 + ks);
        sacc[0] = mfma16(a0, bb, sacc[0]);
        sacc[1] = mfma16(a1, bb, sacc[1]);
        sacc[2] = mfma16(a2, bb, sacc[2]);
        sacc[3] = mfma16(a3, bb, sacc[3]);
      }
      __builtin_amdgcn_s_setprio(0);
      __builtin_amdgcn_sched_barrier(0);
      if (kc < 6) stageG(st, kc + 2, bf);
      else stageH(st, kc - 6, bf);  // kc=6 -> H0 buf0, kc=7 -> H1 buf1
    }

    // ---- softmax (3 barriers) ----
#pragma unroll
    for (int mt = 0; mt < 4; ++mt)
#pragma unroll
      for (int rg = 0; rg < 4; ++rg) {
        float v = sacc[mt][rg];
        float mx = v;
        mx = fmaxf(mx, __shfl_xor(mx, 1));
        mx = fmaxf(mx, __shfl_xor(mx, 2));
        mx = fmaxf(mx, __shfl_xor(mx, 4));
        mx = fmaxf(mx, __shfl_xor(mx, 8));
        float sm = __expf(v - mx);
        sm += __shfl_xor(sm, 1);
        sm += __shfl_xor(sm, 2);
        sm += __shfl_xor(sm, 4);
        sm += __shfl_xor(sm, 8);
        if (l15 == 0)
          *(float2*)&red[mt * 16 + lg * 4 + rg][w][0] = make_float2(mx, sm);
      }
    BARSYNC();  // [A]
    if (ln < 8) {
      const int row = w * 8 + ln;
      float m_new = m_run;
#pragma unroll
      for (int j = 0; j < 8; ++j) m_new = fmaxf(m_new, red[row][j][0]);
      float l_new = l_run * __expf(m_run - m_new);
#pragma unroll
      for (int j = 0; j < 8; ++j)
        l_new += red[row][j][1] * __expf(red[row][j][0] - m_new);
      fin[row][0] = m_new;
      fin[row][1] = __expf(m_run - m_new);
      if (st == 15) fin[row][2] = 1.f / l_new;
      m_run = m_new;
      l_run = l_new;
    }
    BARSYNC();  // [B]
#pragma unroll
    for (int mt = 0; mt < 4; ++mt) {
      float mrow[4];
      f32x4 fac;
#pragma unroll
      for (int rg = 0; rg < 4; ++rg) {
        float2 v = *(const float2*)&fin[mt * 16 + lg * 4 + rg][0];
        mrow[rg] = v.x;
        fac[rg] = v.y;
      }
#pragma unroll
      for (int ch = 0; ch < 2; ++ch)
#pragma unroll
        for (int nt = 0; nt < 2; ++nt) {
          pvm[mt][ch][nt] *= fac;
          pvs[mt][ch][nt] *= fac;
        }
#pragma unroll
      for (int rg = 0; rg < 4; ++rg) {
        const int row = mt * 16 + lg * 4 + rg;
        const int gw = w * 2 + (l15 >> 3);
        const int sw = (gw & 8) | ((gw ^ row) & 7);
        Ps[row * 128 + sw * 8 + (l15 & 7)] =
            f2h(__expf(sacc[mt][rg] - mrow[rg]));
      }
    }
    BARSYNC();  // [C] — Ps stable for whole PV phase

    // ---- PV: 8 chunks (ch-half x ksl), no barriers (wave-private H) ----
#pragma unroll
    for (int hc = 0; hc < 8; ++hc) {
      asm volatile("s_waitcnt vmcnt(2)" ::: "memory");
      const int bf = hc & 1;
      const int ch = hc >> 2, ksl = hc & 3;
      f16x8 p0 = readPa(0, ksl), p1 = readPa(1, ksl);
      f16x8 p2 = readPa(2, ksl), p3 = readPa(3, ksl);
      f16x8 h0 = readH(bf, 0), h1 = readH(bf, 1);
      f16x8 q0 = h0 * h0, q1 = h1 * h1;
      __builtin_amdgcn_s_setprio(1);
      pvm[0][ch][0] = mfma16(p0, h0, pvm[0][ch][0]);
      pvm[1][ch][0] = mfma16(p1, h0, pvm[1][ch][0]);
      pvm[2][ch][0] = mfma16(p2, h0, pvm[2][ch][0]);
      pvm[3][ch][0] = mfma16(p3, h0, pvm[3][ch][0]);
      pvs[0][ch][0] = mfma16(p0, q0, pvs[0][ch][0]);
      pvs[1][ch][0] = mfma16(p1, q0, pvs[1][ch][0]);
      pvs[2][ch][0] = mfma16(p2, q0, pvs[2][ch][0]);
      pvs[3][ch][0] = mfma16(p3, q0, pvs[3][ch][0]);
      pvm[0][ch][1] = mfma16(p0, h1, pvm[0][ch][1]);
      pvm[1][ch][1] = mfma16(p1, h1, pvm[1][ch][1]);
      pvm[2][ch][1] = mfma16(p2, h1, pvm[2][ch][1]);
      pvm[3][ch][1] = mfma16(p3, h1, pvm[3][ch][1]);
      pvs[0][ch][1] = mfma16(p0, q1, pvs[0][ch][1]);
      pvs[1][ch][1] = mfma16(p1, q1, pvs[1][ch][1]);
      pvs[2][ch][1] = mfma16(p2, q1, pvs[2][ch][1]);
      pvs[3][ch][1] = mfma16(p3, q1, pvs[3][ch][1]);
      __builtin_amdgcn_s_setprio(0);
      __builtin_amdgcn_sched_barrier(0);
      if (hc < 6) stageH(st, hc + 2, bf);
      else stageG(stn, hc - 6, bf);  // prefetch next tile's G
    }
  }
  asm volatile("s_waitcnt vmcnt(0)" ::: "memory");

  // ---- epilogue ----
  f32x4 invq[4];
#pragma unroll
  for (int mt = 0; mt < 4; ++mt)
#pragma unroll
    for (int rg = 0; rg < 4; ++rg)
      invq[mt][rg] = fin[mt * 16 + lg * 4 + rg][2];
#pragma unroll
  for (int ch = 0; ch < 2; ++ch)
#pragma unroll
    for (int nt = 0; nt < 2; ++nt) {
      const int c = ch * 256 + w * 32 + nt * 16 + l15;
      const size_t row = (size_t)b * C_ + c;
      const float cm = cmean[row];
      const float cr = crstd[row];
      const float* cp = content + row * TC + t0;
      float* op = out + row * TC + t0;
#pragma unroll
      for (int mt = 0; mt < 4; ++mt) {
        const int q0 = mt * 16 + lg * 4;
        const float4 x = *(const float4*)(cp + q0);
        const f32x4 mu = pvm[mt][ch][nt] * invq[mt];
        const f32x4 se = pvs[mt][ch][nt] * invq[mt];
        float4 y;
        y.x = sqrtf(fmaxf(se[0] - mu[0] * mu[0], 0.f)) * ((x.x - cm) * cr) + mu[0];
        y.y = sqrtf(fmaxf(se[1] - mu[1] * mu[1], 0.f)) * ((x.y - cm) * cr) + mu[1];
        y.z = sqrtf(fmaxf(se[2] - mu[2] * mu[2], 0.f)) * ((x.z - cm) * cr) + mu[2];
        y.w = sqrtf(fmaxf(se[3] - mu[3] * mu[3], 0.f)) * ((x.w - cm) * cr) + mu[3];
        *(float4*)(op + q0) = y;
      }
    }
}

extern "C" void kernel_launch(void* const* d_in, const int* in_sizes, int n_in,
                              void* d_out, int out_size, void* d_ws, size_t ws_size,
                              hipStream_t stream) {
  (void)in_sizes;
  (void)n_in;
  (void)out_size;
  (void)ws_size;  // needs ~96 MB
  const float* content = (const float*)d_in[0];
  const float* style = (const float*)d_in[1];
  const float* content_key = (const float*)d_in[2];
  const float* style_key = (const float*)d_in[3];
  const float* Wf = (const float*)d_in[4];
  const float* bf = (const float*)d_in[5];
  const float* Wg = (const float*)d_in[6];
  const float* bg = (const float*)d_in[7];
  const float* Wh = (const float*)d_in[8];
  const float* bh = (const float*)d_in[9];
  float* out = (float*)d_out;

  char* ws = (char*)d_ws;
  u16* Ft = (u16*)(ws);
  u16* Gt = (u16*)(ws + 67108864);
  u16* Hm = (u16*)(ws + 83886080);
  float* cmean = (float*)(ws + 100663296);
  float* crstd = (float*)(ws + 100663296 + 16384);

  k_content_stats<<<dim3(B_ * C_), dim3(256), 0, stream>>>(content, cmean, crstd);
  k_conv<false><<<dim3(TC / 64, 2, B_), dim3(256), 0, stream>>>(content_key, Wf, bf, Ft, TC);
  k_conv<false><<<dim3(TS / 64, 2, B_), dim3(256), 0, stream>>>(style_key, Wg, bg, Gt, TS);
  k_conv<true><<<dim3(TS / 64, 2, B_), dim3(256), 0, stream>>>(style, Wh, bh, Hm, TS);

  k_attn<<<dim3(1024), dim3(512), 0, stream>>>(Ft, Gt, Hm, content, cmean, crstd, out);
}

// Round 4
// 908.811 us; speedup vs baseline: 1.7648x; 1.1715x over previous
//
#include <hip/hip_runtime.h>
#include <hip/hip_fp16.h>

// AdaAttN fused pipeline, fp16 MFMA path, single-pass flash attention.
// B=8, C=512, Tc=8192, Ts=2048.
//
// ws layout (bytes):
//   Ft  [8][8192][512] fp16 :      0 .. 67,108,864
//   Gt  [8][2048][512] fp16 : 67,108,864 .. 83,886,080
//   H   [8][512][2048] fp16 : 83,886,080 .. 100,663,296
//   cmean [4096] f32        : 100,663,296
//   crstd [4096] f32        : 100,679,680

#define B_ 8
#define C_ 512
#define TC 8192
#define TS 2048

typedef unsigned short u16;
typedef __attribute__((ext_vector_type(8))) _Float16 f16x8;
typedef __attribute__((ext_vector_type(4))) float f32x4;

__device__ __forceinline__ u16 f2h(float f) {
  return __half_as_ushort(__float2half(f));
}

__device__ __forceinline__ f32x4 mfma16(f16x8 a, f16x8 b, f32x4 c) {
  return __builtin_amdgcn_mfma_f32_16x16x32_f16(a, b, c, 0, 0, 0);
}

// async global->LDS, 16B per lane; LDS dest = wave-uniform base + lane*16
__device__ __forceinline__ void stage16(const u16* g, u16* l) {
  __builtin_amdgcn_global_load_lds(
      (__attribute__((address_space(1))) void*)(const void*)g,
      (__attribute__((address_space(3))) void*)l, 16, 0, 0);
}

// raw barrier: flush LDS ops, no vmcnt drain (keeps staging loads in flight)
#define BARSYNC()                                         \
  do {                                                    \
    asm volatile("s_waitcnt lgkmcnt(0)" ::: "memory");    \
    __builtin_amdgcn_s_barrier();                         \
    __builtin_amdgcn_sched_barrier(0);                    \
  } while (0)

// ---------------- K0: per-(b,c) content stats (ddof=1) ----------------
__global__ __launch_bounds__(256) void k_content_stats(
    const float* __restrict__ x, float* __restrict__ cmean, float* __restrict__ crstd) {
  const int row = blockIdx.x;  // b*512 + c
  const float4* p = (const float4*)(x + (size_t)row * TC);
  float s = 0.f, ss = 0.f;
  for (int i = threadIdx.x; i < TC / 4; i += 256) {
    float4 v = p[i];
    s += v.x + v.y + v.z + v.w;
    ss += v.x * v.x + v.y * v.y + v.z * v.z + v.w * v.w;
  }
#pragma unroll
  for (int d = 1; d < 64; d <<= 1) {
    s += __shfl_xor(s, d);
    ss += __shfl_xor(ss, d);
  }
  __shared__ float rs[4], rss[4];
  if ((threadIdx.x & 63) == 0) {
    rs[threadIdx.x >> 6] = s;
    rss[threadIdx.x >> 6] = ss;
  }
  __syncthreads();
  if (threadIdx.x == 0) {
    float S = rs[0] + rs[1] + rs[2] + rs[3];
    float SS = rss[0] + rss[1] + rss[2] + rss[3];
    float mean = S / (float)TC;
    float var = (SS - S * mean) / (float)(TC - 1);
    cmean[row] = mean;
    crstd[row] = rsqrtf(var + 1e-5f);
  }
}

// ---------------- conv1x1 GEMM (unchanged, verified) ----------------
template <bool TRANS_OUT>
__global__ __launch_bounds__(256, 3) void k_conv(
    const float* __restrict__ X, const float* __restrict__ W,
    const float* __restrict__ bias, u16* __restrict__ Y, int M) {
  const int b = blockIdx.z;
  const int m0 = blockIdx.x * 64;
  const int n0 = blockIdx.y * 256;
  const int tid = threadIdx.x;
  const int w = tid >> 6, ln = tid & 63, lg = ln >> 4, l15 = ln & 15;
  __shared__ u16 As[64][72];
  __shared__ u16 Bs[256][72];
  const float* Xb = X + (size_t)b * C_ * M;
  const f32x4 vzero = {0.f, 0.f, 0.f, 0.f};
  f32x4 acc[4][4];
#pragma unroll
  for (int i = 0; i < 4; ++i)
#pragma unroll
    for (int j = 0; j < 4; ++j) acc[i][j] = vzero;

  for (int k0 = 0; k0 < 512; k0 += 64) {
    __syncthreads();
    {  // stage A (transpose + cvt)
      const int kk = tid >> 2, c4 = tid & 3;
      const float* src = Xb + (size_t)(k0 + kk) * M + m0 + c4 * 16;
#pragma unroll
      for (int i = 0; i < 4; ++i) {
        float4 v = *(const float4*)(src + i * 4);
        const int mo = c4 * 16 + i * 4;
        As[mo + 0][kk] = f2h(v.x);
        As[mo + 1][kk] = f2h(v.y);
        As[mo + 2][kk] = f2h(v.z);
        As[mo + 3][kk] = f2h(v.w);
      }
    }
    {  // stage B
      const float* src = W + (size_t)(n0 + tid) * 512 + k0;
#pragma unroll
      for (int i = 0; i < 16; ++i) {
        float4 v = *(const float4*)(src + i * 4);
        ushort4 hq = make_ushort4(f2h(v.x), f2h(v.y), f2h(v.z), f2h(v.w));
        *(ushort4*)&Bs[tid][i * 4] = hq;
      }
    }
    __syncthreads();
#pragma unroll
    for (int ks = 0; ks < 2; ++ks) {
      f16x8 a[4], bb[4];
#pragma unroll
      for (int mt = 0; mt < 4; ++mt)
        a[mt] = *(const f16x8*)&As[mt * 16 + l15][ks * 32 + lg * 8];
#pragma unroll
      for (int nt = 0; nt < 4; ++nt)
        bb[nt] = *(const f16x8*)&Bs[w * 64 + nt * 16 + l15][ks * 32 + lg * 8];
#pragma unroll
      for (int mt = 0; mt < 4; ++mt)
#pragma unroll
        for (int nt = 0; nt < 4; ++nt)
          acc[mt][nt] = mfma16(a[mt], bb[nt], acc[mt][nt]);
    }
  }
#pragma unroll
  for (int nt = 0; nt < 4; ++nt) {
    const int n = n0 + w * 64 + nt * 16 + l15;
    const float bv = bias[n];
#pragma unroll
    for (int mt = 0; mt < 4; ++mt) {
      const int mb = m0 + mt * 16 + lg * 4;
      f32x4 v = acc[mt][nt];
      if (!TRANS_OUT) {
        u16* yp = Y + (size_t)b * M * 512 + (size_t)mb * 512 + n;
        yp[0 * 512] = f2h(v[0] + bv);
        yp[1 * 512] = f2h(v[1] + bv);
        yp[2 * 512] = f2h(v[2] + bv);
        yp[3 * 512] = f2h(v[3] + bv);
      } else {
        ushort4 hq = make_ushort4(f2h(v[0] + bv), f2h(v[1] + bv),
                                  f2h(v[2] + bv), f2h(v[3] + bv));
        *(ushort4*)(Y + (size_t)b * 512 * M + (size_t)n * M + mb) = hq;
      }
    }
  }
}

// ---------------- K5: flash attention, swapped-QK, defer-max ----------------
// 512 thr (8 waves), 64 q rows, s-tile 128 (16 tiles).
// QK (swapped): out[s][t]; wave w owns s-rows w*16..+16 (A=G wave-private),
//   all 64 t as 4 B-tiles (B=F). Lane: s = w*16+lg*4+rg (regs), t = tt*16+l15.
//   -> row-softmax over s is in-register + 2 shfl.
// PV: unchanged; wave w owns c rows {ch*256 + w*32..+32}.
// 2 barriers/tile. Rescale skipped unless row-max grew > 2^11 (defer-max).
__global__ __launch_bounds__(512, 2) void k_attn(
    const u16* __restrict__ Ft, const u16* __restrict__ Gt,
    const u16* __restrict__ Hm, const float* __restrict__ content,
    const float* __restrict__ cmean, const float* __restrict__ crstd,
    float* __restrict__ out) {
  __shared__ u16 Fq[64 * 512];     // swizzled granule: (g&56)|((g^row)&7)
  __shared__ u16 UG[2][128 * 64];  // G chunk [128 s][64 c], granule g^(row&7)
  __shared__ u16 UH[2][256 * 32];  // H chunk [256 c][32 s]
  __shared__ u16 Ps[64 * 128];     // [t][s], granule16: (g&8)|((g^t)&7)
  __shared__ float red[8][64][2];  // [wave][t-row]: (max2, sum)
  __shared__ float fin_fac[64];    // rescale factor per t-row
  __shared__ float fin_invl[64];   // 1/l at last tile
  __shared__ float flagv[2];       // per-parity "any row rescaled" flag

  const int bid = blockIdx.x;
  const int swz = (bid & 7) * 128 + (bid >> 3);  // XCD-contiguous (1024%8==0)
  const int b = swz >> 7;
  const int t0 = (swz & 127) * 64;
  const int tid = threadIdx.x;
  const int w = tid >> 6, ln = tid & 63, lg = ln >> 4, l15 = ln & 15;

  const u16* Ftb = Ft + ((size_t)b * TC + t0) * C_;
  const u16* Gtb = Gt + (size_t)b * TS * C_;
  const u16* Hb = Hm + (size_t)b * C_ * TS;

  // ---- Fq stage: linear global read, swizzled LDS write ----
  {
    const int r = tid >> 3, c0 = tid & 7;
    const u16* src = Ftb + (size_t)r * C_;
#pragma unroll
    for (int i = 0; i < 8; ++i) {
      const int j = c0 + 8 * i;
      uint4 v = *(const uint4*)(src + j * 8);
      const int sw = (j & 56) | ((j ^ r) & 7);
      *(uint4*)&Fq[r * 512 + sw * 8] = v;
    }
  }
  if (tid < 2) flagv[tid] = 0.f;
  __syncthreads();  // full drain once; ledger starts clean

  auto stageG = [&](int st_, int kc, int bf) {
#pragma unroll
    for (int i = 0; i < 2; ++i) {
      const int row = w * 16 + i * 8 + (ln >> 3);
      const int g = (ln & 7) ^ ((ln >> 3) & 7);
      stage16(Gtb + (size_t)(st_ * 128 + row) * 512 + kc * 64 + g * 8,
              &UG[bf][(w * 16 + i * 8) * 64]);
    }
  };
  auto stageH = [&](int st_, int hc, int bf) {
    const int ch = hc >> 2, ksl = hc & 3;
#pragma unroll
    for (int i = 0; i < 2; ++i) {
      const int row = w * 32 + i * 16 + (ln >> 2);
      const int g = (ln & 3) ^ ((ln >> 2) & 3) ^ ((ln >> 4) & 3);
      stage16(Hb + (size_t)(ch * 256 + row) * TS + st_ * 128 + ksl * 32 + g * 8,
              &UH[bf][(w * 32 + i * 16) * 32]);
    }
  };
  auto readF = [&](int tt, int kq) -> f16x8 {  // B operand: F t-tile
    const int row = tt * 16 + l15;
    const int g = kq * 4 + lg;
    const int sw = (g & 56) | ((g ^ row) & 7);
    return *(const f16x8*)&Fq[row * 512 + sw * 8];
  };
  auto readG = [&](int bf, int ks) -> f16x8 {  // A operand: G s-rows
    const int row = w * 16 + l15;
    const int sw = (ks * 4 + lg) ^ (row & 7);
    return *(const f16x8*)&UG[bf][row * 64 + sw * 8];
  };
  auto readH = [&](int bf, int nt) -> f16x8 {
    const int row = w * 32 + nt * 16 + l15;
    const int sw = lg ^ (row & 3) ^ ((row >> 2) & 3);
    return *(const f16x8*)&UH[bf][row * 32 + sw * 8];
  };
  auto readPa = [&](int mt, int ksl) -> f16x8 {
    const int row = mt * 16 + l15;
    const int g = ksl * 4 + lg;
    const int sw = (g & 8) | ((g ^ row) & 7);
    return *(const f16x8*)&Ps[row * 128 + sw * 8];
  };

  // prologue stages: tile 0, G chunks 0,1
  stageG(0, 0, 0);
  stageG(0, 1, 1);

  const f32x4 vzero = {0.f, 0.f, 0.f, 0.f};
  f32x4 pvm[4][2][2], pvs[4][2][2];
#pragma unroll
  for (int mt = 0; mt < 4; ++mt)
#pragma unroll
    for (int ch = 0; ch < 2; ++ch)
#pragma unroll
      for (int nt = 0; nt < 2; ++nt) {
        pvm[mt][ch][nt] = vzero;
        pvs[mt][ch][nt] = vzero;
      }
  // per-lane online state for its 4 rows t = tt*16 + l15 (base-2 units)
  float m_run[4] = {-1e30f, -1e30f, -1e30f, -1e30f};
  float l_run[4] = {0.f, 0.f, 0.f, 0.f};
  const float LOG2E = 1.44269504f;

  for (int st = 0; st < 16; ++st) {
    const int stn = (st + 1) & 15;
    f32x4 sacc[4] = {vzero, vzero, vzero, vzero};

    // ---- QK swapped: out rows = s (regs), cols = t (l15); no barriers ----
#pragma unroll
    for (int kc = 0; kc < 8; ++kc) {
      asm volatile("s_waitcnt vmcnt(2)" ::: "memory");
      const int bf = kc & 1;
      __builtin_amdgcn_s_setprio(1);
#pragma unroll
      for (int ks = 0; ks < 2; ++ks) {
        f16x8 gv = readG(bf, ks);
        f16x8 f0 = readF(0, kc * 2 + ks), f1 = readF(1, kc * 2 + ks);
        f16x8 f2 = readF(2, kc * 2 + ks), f3 = readF(3, kc * 2 + ks);
        sacc[0] = mfma16(gv, f0, sacc[0]);
        sacc[1] = mfma16(gv, f1, sacc[1]);
        sacc[2] = mfma16(gv, f2, sacc[2]);
        sacc[3] = mfma16(gv, f3, sacc[3]);
      }
      __builtin_amdgcn_s_setprio(0);
      __builtin_amdgcn_sched_barrier(0);
      if (kc < 6) stageG(st, kc + 2, bf);
      else stageH(st, kc - 6, bf);  // kc=6 -> H0 buf0, kc=7 -> H1 buf1
    }

    // ---- per-wave partial stats (in-reg over s + 2 shfl over lg) ----
    float mx4[4];
#pragma unroll
    for (int tt = 0; tt < 4; ++tt) {
      f32x4 v = sacc[tt] * LOG2E;
      float mx = fmaxf(fmaxf(v[0], v[1]), fmaxf(v[2], v[3]));
      mx = fmaxf(mx, __shfl_xor(mx, 16));
      mx = fmaxf(mx, __shfl_xor(mx, 32));
      f32x4 pe;
      pe[0] = exp2f(v[0] - mx);
      pe[1] = exp2f(v[1] - mx);
      pe[2] = exp2f(v[2] - mx);
      pe[3] = exp2f(v[3] - mx);
      float sm = pe[0] + pe[1] + pe[2] + pe[3];
      sm += __shfl_xor(sm, 16);
      sm += __shfl_xor(sm, 32);
      sacc[tt] = pe;  // keep exp(v - mx) for P-write
      mx4[tt] = mx;
      if (lg == 0)
        *(float2*)&red[w][tt * 16 + l15][0] = make_float2(mx, sm);
    }
    BARSYNC();  // [A]

    // ---- per-lane redundant merge for rows t = tt*16 + l15 ----
    {
      float fac_p[4];
      bool changed = false;
#pragma unroll
      for (int tt = 0; tt < 4; ++tt) {
        const int row = tt * 16 + l15;
        float pm[8], psum[8];
        float mc = m_run[tt];
#pragma unroll
        for (int j = 0; j < 8; ++j) {
          float2 r = *(const float2*)&red[j][row][0];
          pm[j] = r.x;
          psum[j] = r.y;
          mc = fmaxf(mc, pm[j]);
        }
        const float m_new = (mc - m_run[tt] <= 11.0f) ? m_run[tt] : mc;  // defer-max
        float l_new = l_run[tt] * exp2f(m_run[tt] - m_new);
#pragma unroll
        for (int j = 0; j < 8; ++j) l_new += psum[j] * exp2f(pm[j] - m_new);
        fac_p[tt] = exp2f(mx4[tt] - m_new);
        if (m_new != m_run[tt]) changed = true;
        if (w == 0 && lg == 0) {
          fin_fac[row] = exp2f(m_run[tt] - m_new);
          if (st == 15) fin_invl[row] = 1.0f / l_new;
        }
        m_run[tt] = m_new;
        l_run[tt] = l_new;
      }
      if (w == 0 && changed) flagv[st & 1] = 1.0f;

      // ---- P-write: packed b64, swizzled [t][s] layout ----
#pragma unroll
      for (int tt = 0; tt < 4; ++tt) {
        const int row = tt * 16 + l15;
        const int g16 = w * 2 + (lg >> 1);
        const int sw16 = (g16 & 8) | ((g16 ^ row) & 7);
        const f32x4 pe = sacc[tt];
        const float fp = fac_p[tt];
        ushort4 pk = make_ushort4(f2h(pe[0] * fp), f2h(pe[1] * fp),
                                  f2h(pe[2] * fp), f2h(pe[3] * fp));
        *(ushort4*)&Ps[row * 128 + sw16 * 8 + (lg & 1) * 4] = pk;
      }
    }
    BARSYNC();  // [C] — Ps + fin stable for PV phase

    // ---- rescale (uniform skip via defer-max flag) ----
    {
      const float fl = flagv[st & 1];
      if (fl != 0.f) {
#pragma unroll
        for (int mt = 0; mt < 4; ++mt) {
          const f32x4 fac = *(const f32x4*)&fin_fac[mt * 16 + lg * 4];
#pragma unroll
          for (int ch = 0; ch < 2; ++ch)
#pragma unroll
            for (int nt = 0; nt < 2; ++nt) {
              pvm[mt][ch][nt] *= fac;
              pvs[mt][ch][nt] *= fac;
            }
        }
      }
      if (tid == 0) flagv[(st + 1) & 1] = 0.f;
    }

    // ---- PV: 8 chunks, no barriers (wave-private H) ----
#pragma unroll
    for (int hc = 0; hc < 8; ++hc) {
      asm volatile("s_waitcnt vmcnt(2)" ::: "memory");
      const int bf = hc & 1;
      const int ch = hc >> 2, ksl = hc & 3;
      f16x8 p0 = readPa(0, ksl), p1 = readPa(1, ksl);
      f16x8 p2 = readPa(2, ksl), p3 = readPa(3, ksl);
      f16x8 h0 = readH(bf, 0), h1 = readH(bf, 1);
      f16x8 q0 = h0 * h0, q1 = h1 * h1;
      __builtin_amdgcn_s_setprio(1);
      pvm[0][ch][0] = mfma16(p0, h0, pvm[0][ch][0]);
      pvm[1][ch][0] = mfma16(p1, h0, pvm[1][ch][0]);
      pvm[2][ch][0] = mfma16(p2, h0, pvm[2][ch][0]);
      pvm[3][ch][0] = mfma16(p3, h0, pvm[3][ch][0]);
      pvs[0][ch][0] = mfma16(p0, q0, pvs[0][ch][0]);
      pvs[1][ch][0] = mfma16(p1, q0, pvs[1][ch][0]);
      pvs[2][ch][0] = mfma16(p2, q0, pvs[2][ch][0]);
      pvs[3][ch][0] = mfma16(p3, q0, pvs[3][ch][0]);
      pvm[0][ch][1] = mfma16(p0, h1, pvm[0][ch][1]);
      pvm[1][ch][1] = mfma16(p1, h1, pvm[1][ch][1]);
      pvm[2][ch][1] = mfma16(p2, h1, pvm[2][ch][1]);
      pvm[3][ch][1] = mfma16(p3, h1, pvm[3][ch][1]);
      pvs[0][ch][1] = mfma16(p0, q1, pvs[0][ch][1]);
      pvs[1][ch][1] = mfma16(p1, q1, pvs[1][ch][1]);
      pvs[2][ch][1] = mfma16(p2, q1, pvs[2][ch][1]);
      pvs[3][ch][1] = mfma16(p3, q1, pvs[3][ch][1]);
      __builtin_amdgcn_s_setprio(0);
      __builtin_amdgcn_sched_barrier(0);
      if (hc < 6) stageH(st, hc + 2, bf);
      else stageG(stn, hc - 6, bf);  // prefetch next tile's G
    }
  }
  asm volatile("s_waitcnt vmcnt(0)" ::: "memory");

  // ---- epilogue: out[b][c][t] = std * (content - cm)*cr + mean ----
  f32x4 invq[4];
#pragma unroll
  for (int mt = 0; mt < 4; ++mt)
    invq[mt] = *(const f32x4*)&fin_invl[mt * 16 + lg * 4];
#pragma unroll
  for (int ch = 0; ch < 2; ++ch)
#pragma unroll
    for (int nt = 0; nt < 2; ++nt) {
      const int c = ch * 256 + w * 32 + nt * 16 + l15;
      const size_t row = (size_t)b * C_ + c;
      const float cm = cmean[row];
      const float cr = crstd[row];
      const float* cp = content + row * TC + t0;
      float* op = out + row * TC + t0;
#pragma unroll
      for (int mt = 0; mt < 4; ++mt) {
        const int q0 = mt * 16 + lg * 4;
        const float4 x = *(const float4*)(cp + q0);
        const f32x4 mu = pvm[mt][ch][nt] * invq[mt];
        const f32x4 se = pvs[mt][ch][nt] * invq[mt];
        float4 y;
        y.x = sqrtf(fmaxf(se[0] - mu[0] * mu[0], 0.f)) * ((x.x - cm) * cr) + mu[0];
        y.y = sqrtf(fmaxf(se[1] - mu[1] * mu[1], 0.f)) * ((x.y - cm) * cr) + mu[1];
        y.z = sqrtf(fmaxf(se[2] - mu[2] * mu[2], 0.f)) * ((x.z - cm) * cr) + mu[2];
        y.w = sqrtf(fmaxf(se[3] - mu[3] * mu[3], 0.f)) * ((x.w - cm) * cr) + mu[3];
        *(float4*)(op + q0) = y;
      }
    }
}

extern "C" void kernel_launch(void* const* d_in, const int* in_sizes, int n_in,
                              void* d_out, int out_size, void* d_ws, size_t ws_size,
                              hipStream_t stream) {
  (void)in_sizes;
  (void)n_in;
  (void)out_size;
  (void)ws_size;  // needs ~96 MB
  const float* content = (const float*)d_in[0];
  const float* style = (const float*)d_in[1];
  const float* content_key = (const float*)d_in[2];
  const float* style_key = (const float*)d_in[3];
  const float* Wf = (const float*)d_in[4];
  const float* bf = (const float*)d_in[5];
  const float* Wg = (const float*)d_in[6];
  const float* bg = (const float*)d_in[7];
  const float* Wh = (const float*)d_in[8];
  const float* bh = (const float*)d_in[9];
  float* out = (float*)d_out;

  char* ws = (char*)d_ws;
  u16* Ft = (u16*)(ws);
  u16* Gt = (u16*)(ws + 67108864);
  u16* Hm = (u16*)(ws + 83886080);
  float* cmean = (float*)(ws + 100663296);
  float* crstd = (float*)(ws + 100663296 + 16384);

  k_content_stats<<<dim3(B_ * C_), dim3(256), 0, stream>>>(content, cmean, crstd);
  k_conv<false><<<dim3(TC / 64, 2, B_), dim3(256), 0, stream>>>(content_key, Wf, bf, Ft, TC);
  k_conv<false><<<dim3(TS / 64, 2, B_), dim3(256), 0, stream>>>(style_key, Wg, bg, Gt, TS);
  k_conv<true><<<dim3(TS / 64, 2, B_), dim3(256), 0, stream>>>(style, Wh, bh, Hm, TS);

  k_attn<<<dim3(1024), dim3(512), 0, stream>>>(Ft, Gt, Hm, content, cmean, crstd, out);
}

// Round 5
// 815.519 us; speedup vs baseline: 1.9667x; 1.1144x over previous
//
#include <hip/hip_runtime.h>
#include <hip/hip_fp16.h>

// AdaAttN fused pipeline, fp16 MFMA path, single-pass flash attention.
// B=8, C=512, Tc=8192, Ts=2048.
//
// ws layout (bytes):
//   Ft  [8][8192][512] fp16 :      0 .. 67,108,864
//   Gt  [8][2048][512] fp16 : 67,108,864 .. 83,886,080
//   H   [8][512][2048] fp16 : 83,886,080 .. 100,663,296
//   cmean [4096] f32        : 100,663,296
//   crstd [4096] f32        : 100,679,680

#define B_ 8
#define C_ 512
#define TC 8192
#define TS 2048

typedef unsigned short u16;
typedef __attribute__((ext_vector_type(8))) _Float16 f16x8;
typedef __attribute__((ext_vector_type(4))) float f32x4;

__device__ __forceinline__ u16 f2h(float f) {
  return __half_as_ushort(__float2half(f));
}

__device__ __forceinline__ f32x4 mfma16(f16x8 a, f16x8 b, f32x4 c) {
  return __builtin_amdgcn_mfma_f32_16x16x32_f16(a, b, c, 0, 0, 0);
}

// async global->LDS, 16B per lane; LDS dest = wave-uniform base + lane*16
__device__ __forceinline__ void stage16(const u16* g, u16* l) {
  __builtin_amdgcn_global_load_lds(
      (__attribute__((address_space(1))) void*)(const void*)g,
      (__attribute__((address_space(3))) void*)l, 16, 0, 0);
}

// raw barrier: flush LDS ops, no vmcnt drain (keeps staging loads in flight)
#define BARSYNC()                                         \
  do {                                                    \
    asm volatile("s_waitcnt lgkmcnt(0)" ::: "memory");    \
    __builtin_amdgcn_s_barrier();                         \
    __builtin_amdgcn_sched_barrier(0);                    \
  } while (0)

// ---------------- K0: per-(b,c) content stats (ddof=1) ----------------
__global__ __launch_bounds__(256) void k_content_stats(
    const float* __restrict__ x, float* __restrict__ cmean, float* __restrict__ crstd) {
  const int row = blockIdx.x;  // b*512 + c
  const float4* p = (const float4*)(x + (size_t)row * TC);
  float s = 0.f, ss = 0.f;
  for (int i = threadIdx.x; i < TC / 4; i += 256) {
    float4 v = p[i];
    s += v.x + v.y + v.z + v.w;
    ss += v.x * v.x + v.y * v.y + v.z * v.z + v.w * v.w;
  }
#pragma unroll
  for (int d = 1; d < 64; d <<= 1) {
    s += __shfl_xor(s, d);
    ss += __shfl_xor(ss, d);
  }
  __shared__ float rs[4], rss[4];
  if ((threadIdx.x & 63) == 0) {
    rs[threadIdx.x >> 6] = s;
    rss[threadIdx.x >> 6] = ss;
  }
  __syncthreads();
  if (threadIdx.x == 0) {
    float S = rs[0] + rs[1] + rs[2] + rs[3];
    float SS = rss[0] + rss[1] + rss[2] + rss[3];
    float mean = S / (float)TC;
    float var = (SS - S * mean) / (float)(TC - 1);
    cmean[row] = mean;
    crstd[row] = rsqrtf(var + 1e-5f);
  }
}

// ---------------- conv1x1 GEMM (unchanged, verified) ----------------
template <bool TRANS_OUT>
__global__ __launch_bounds__(256, 3) void k_conv(
    const float* __restrict__ X, const float* __restrict__ W,
    const float* __restrict__ bias, u16* __restrict__ Y, int M) {
  const int b = blockIdx.z;
  const int m0 = blockIdx.x * 64;
  const int n0 = blockIdx.y * 256;
  const int tid = threadIdx.x;
  const int w = tid >> 6, ln = tid & 63, lg = ln >> 4, l15 = ln & 15;
  __shared__ u16 As[64][72];
  __shared__ u16 Bs[256][72];
  const float* Xb = X + (size_t)b * C_ * M;
  const f32x4 vzero = {0.f, 0.f, 0.f, 0.f};
  f32x4 acc[4][4];
#pragma unroll
  for (int i = 0; i < 4; ++i)
#pragma unroll
    for (int j = 0; j < 4; ++j) acc[i][j] = vzero;

  for (int k0 = 0; k0 < 512; k0 += 64) {
    __syncthreads();
    {  // stage A (transpose + cvt)
      const int kk = tid >> 2, c4 = tid & 3;
      const float* src = Xb + (size_t)(k0 + kk) * M + m0 + c4 * 16;
#pragma unroll
      for (int i = 0; i < 4; ++i) {
        float4 v = *(const float4*)(src + i * 4);
        const int mo = c4 * 16 + i * 4;
        As[mo + 0][kk] = f2h(v.x);
        As[mo + 1][kk] = f2h(v.y);
        As[mo + 2][kk] = f2h(v.z);
        As[mo + 3][kk] = f2h(v.w);
      }
    }
    {  // stage B
      const float* src = W + (size_t)(n0 + tid) * 512 + k0;
#pragma unroll
      for (int i = 0; i < 16; ++i) {
        float4 v = *(const float4*)(src + i * 4);
        ushort4 hq = make_ushort4(f2h(v.x), f2h(v.y), f2h(v.z), f2h(v.w));
        *(ushort4*)&Bs[tid][i * 4] = hq;
      }
    }
    __syncthreads();
#pragma unroll
    for (int ks = 0; ks < 2; ++ks) {
      f16x8 a[4], bb[4];
#pragma unroll
      for (int mt = 0; mt < 4; ++mt)
        a[mt] = *(const f16x8*)&As[mt * 16 + l15][ks * 32 + lg * 8];
#pragma unroll
      for (int nt = 0; nt < 4; ++nt)
        bb[nt] = *(const f16x8*)&Bs[w * 64 + nt * 16 + l15][ks * 32 + lg * 8];
#pragma unroll
      for (int mt = 0; mt < 4; ++mt)
#pragma unroll
        for (int nt = 0; nt < 4; ++nt)
          acc[mt][nt] = mfma16(a[mt], bb[nt], acc[mt][nt]);
    }
  }
#pragma unroll
  for (int nt = 0; nt < 4; ++nt) {
    const int n = n0 + w * 64 + nt * 16 + l15;
    const float bv = bias[n];
#pragma unroll
    for (int mt = 0; mt < 4; ++mt) {
      const int mb = m0 + mt * 16 + lg * 4;
      f32x4 v = acc[mt][nt];
      if (!TRANS_OUT) {
        u16* yp = Y + (size_t)b * M * 512 + (size_t)mb * 512 + n;
        yp[0 * 512] = f2h(v[0] + bv);
        yp[1 * 512] = f2h(v[1] + bv);
        yp[2 * 512] = f2h(v[2] + bv);
        yp[3 * 512] = f2h(v[3] + bv);
      } else {
        ushort4 hq = make_ushort4(f2h(v[0] + bv), f2h(v[1] + bv),
                                  f2h(v[2] + bv), f2h(v[3] + bv));
        *(ushort4*)(Y + (size_t)b * 512 * M + (size_t)n * M + mb) = hq;
      }
    }
  }
}

// ---------------- K5: flash attention, s_tile=256, F-frag reuse ----------------
// 512 thr (8 waves), 64 q rows, s-tile 256 (8 tiles), processed as 2 s-halves.
// QK (swapped): wave w owns s-rows w*16..+16 of EACH s-half; F-fragments read
//   once per kc and reused across both halves (halves F LDS traffic).
// PV: ksl-outer, ch-inner; P-frags held in regs across both c-halves.
// Ledger: every step stages one chunk (2 x global_load_lds), waits vmcnt(2).
__global__ __launch_bounds__(512, 2) void k_attn(
    const u16* __restrict__ Ft, const u16* __restrict__ Gt,
    const u16* __restrict__ Hm, const float* __restrict__ content,
    const float* __restrict__ cmean, const float* __restrict__ crstd,
    float* __restrict__ out) {
  __shared__ u16 Fq[64 * 512];     // swizzled granule: (g&56)|((g^row)&7)
  __shared__ u16 UG[2][128 * 64];  // G chunk [128 s][64 c], granule g^(row&7)
  __shared__ u16 UH[2][256 * 32];  // H chunk [256 c][32 s]
  __shared__ u16 Ps[64 * 128];     // [t][s-local], one s-half at a time
  __shared__ float red[64][20];    // [t-row][wave*2]: (max2, sum), stride 80B
  __shared__ float fin_fac[64];    // rescale factor per t-row
  __shared__ float fin_invl[64];   // 1/l at last tile
  __shared__ float flagv[2];       // per-parity "any row rescaled" flag

  const int bid = blockIdx.x;
  const int swz = (bid & 7) * 128 + (bid >> 3);  // XCD-contiguous (1024%8==0)
  const int b = swz >> 7;
  const int t0 = (swz & 127) * 64;
  const int tid = threadIdx.x;
  const int w = tid >> 6, ln = tid & 63, lg = ln >> 4, l15 = ln & 15;

  const u16* Ftb = Ft + ((size_t)b * TC + t0) * C_;
  const u16* Gtb = Gt + (size_t)b * TS * C_;
  const u16* Hb = Hm + (size_t)b * C_ * TS;

  // ---- Fq stage: linear global read, swizzled LDS write ----
  {
    const int r = tid >> 3, c0 = tid & 7;
    const u16* src = Ftb + (size_t)r * C_;
#pragma unroll
    for (int i = 0; i < 8; ++i) {
      const int j = c0 + 8 * i;
      uint4 v = *(const uint4*)(src + j * 8);
      const int sw = (j & 56) | ((j ^ r) & 7);
      *(uint4*)&Fq[r * 512 + sw * 8] = v;
    }
  }
  if (tid < 2) flagv[tid] = 0.f;
  __syncthreads();  // full drain once; ledger starts clean

  // G chunk q = kc*2+sh covers s = st*256 + sh*128 .. +128, k = kc*64 .. +64
  auto stageG = [&](int st_, int kc, int sh, int bf) {
#pragma unroll
    for (int i = 0; i < 2; ++i) {
      const int row = w * 16 + i * 8 + (ln >> 3);
      const int g = (ln & 7) ^ ((ln >> 3) & 7);
      stage16(Gtb + (size_t)(st_ * 256 + sh * 128 + row) * 512 + kc * 64 + g * 8,
              &UG[bf][(w * 16 + i * 8) * 64]);
    }
  };
  // H chunk hc (0..15): c = (hc&1)*256 .. +256, s = st*256 + (hc>>1)*32 .. +32
  auto stageH = [&](int st_, int hc, int bf) {
    const int ch = hc & 1, kslg = hc >> 1;
#pragma unroll
    for (int i = 0; i < 2; ++i) {
      const int row = w * 32 + i * 16 + (ln >> 2);
      const int g = (ln & 3) ^ ((ln >> 2) & 3) ^ ((ln >> 4) & 3);
      stage16(Hb + (size_t)(ch * 256 + row) * TS + st_ * 256 + kslg * 32 + g * 8,
              &UH[bf][(w * 32 + i * 16) * 32]);
    }
  };
  auto readF = [&](int tt, int kq) -> f16x8 {  // B operand: F t-tile
    const int row = tt * 16 + l15;
    const int g = kq * 4 + lg;
    const int sw = (g & 56) | ((g ^ row) & 7);
    return *(const f16x8*)&Fq[row * 512 + sw * 8];
  };
  auto readG = [&](int bf, int ks) -> f16x8 {  // A operand: G s-rows
    const int row = w * 16 + l15;
    const int sw = (ks * 4 + lg) ^ (row & 7);
    return *(const f16x8*)&UG[bf][row * 64 + sw * 8];
  };
  auto readH = [&](int bf, int nt) -> f16x8 {
    const int row = w * 32 + nt * 16 + l15;
    const int sw = lg ^ (row & 3) ^ ((row >> 2) & 3);
    return *(const f16x8*)&UH[bf][row * 32 + sw * 8];
  };
  auto readPa = [&](int mt, int ksl) -> f16x8 {
    const int row = mt * 16 + l15;
    const int g = ksl * 4 + lg;
    const int sw = (g & 8) | ((g ^ row) & 7);
    return *(const f16x8*)&Ps[row * 128 + sw * 8];
  };

  // prologue stages: tile 0, G chunks q=0 (kc0,sh0) -> buf0, q=1 (kc0,sh1) -> buf1
  stageG(0, 0, 0, 0);
  stageG(0, 0, 1, 1);

  const f32x4 vzero = {0.f, 0.f, 0.f, 0.f};
  f32x4 pvm[4][2][2], pvs[4][2][2];
#pragma unroll
  for (int mt = 0; mt < 4; ++mt)
#pragma unroll
    for (int ch = 0; ch < 2; ++ch)
#pragma unroll
      for (int nt = 0; nt < 2; ++nt) {
        pvm[mt][ch][nt] = vzero;
        pvs[mt][ch][nt] = vzero;
      }
  // per-lane online state for its 4 t-rows (tt*16 + l15), base-2 units
  float m_run[4] = {-1e30f, -1e30f, -1e30f, -1e30f};
  float l_run[4] = {0.f, 0.f, 0.f, 0.f};
  const float LOG2E = 1.44269504f;

  for (int st = 0; st < 8; ++st) {
    const int stn = (st + 1) & 7;
    f32x4 sacc[2][4];  // [sh][tt]
#pragma unroll
    for (int sh = 0; sh < 2; ++sh)
#pragma unroll
      for (int tt = 0; tt < 4; ++tt) sacc[sh][tt] = vzero;

    // ---- QK: 16 steps (kc x sh); F-frags read at sh==0, reused at sh==1 ----
#pragma unroll
    for (int kc = 0; kc < 8; ++kc) {
      f16x8 fA[2][4];
#pragma unroll
      for (int sh = 0; sh < 2; ++sh) {
        const int q = kc * 2 + sh;
        asm volatile("s_waitcnt vmcnt(2)" ::: "memory");
        const int bf = q & 1;
        if (sh == 0) {
#pragma unroll
          for (int ks = 0; ks < 2; ++ks)
#pragma unroll
            for (int tt = 0; tt < 4; ++tt) fA[ks][tt] = readF(tt, kc * 2 + ks);
        }
        __builtin_amdgcn_s_setprio(1);
#pragma unroll
        for (int ks = 0; ks < 2; ++ks) {
          f16x8 gv = readG(bf, ks);
          sacc[sh][0] = mfma16(gv, fA[ks][0], sacc[sh][0]);
          sacc[sh][1] = mfma16(gv, fA[ks][1], sacc[sh][1]);
          sacc[sh][2] = mfma16(gv, fA[ks][2], sacc[sh][2]);
          sacc[sh][3] = mfma16(gv, fA[ks][3], sacc[sh][3]);
        }
        __builtin_amdgcn_s_setprio(0);
        __builtin_amdgcn_sched_barrier(0);
        const int qn = q + 2;
        if (qn < 16) stageG(st, qn >> 1, qn & 1, bf);
        else stageH(st, qn - 16, bf);  // qn=16,17 -> H chunks 0,1
      }
    }

    // ---- per-wave partial stats over this wave's 32 s (2 sh x 4 rg + lg) ----
    float mx4[4];
#pragma unroll
    for (int tt = 0; tt < 4; ++tt) {
      f32x4 v0 = sacc[0][tt] * LOG2E;
      f32x4 v1 = sacc[1][tt] * LOG2E;
      float mx = fmaxf(fmaxf(fmaxf(v0[0], v0[1]), fmaxf(v0[2], v0[3])),
                       fmaxf(fmaxf(v1[0], v1[1]), fmaxf(v1[2], v1[3])));
      mx = fmaxf(mx, __shfl_xor(mx, 16));
      mx = fmaxf(mx, __shfl_xor(mx, 32));
      f32x4 p0, p1;
#pragma unroll
      for (int rg = 0; rg < 4; ++rg) {
        p0[rg] = exp2f(v0[rg] - mx);
        p1[rg] = exp2f(v1[rg] - mx);
      }
      float sm = p0[0] + p0[1] + p0[2] + p0[3] + p1[0] + p1[1] + p1[2] + p1[3];
      sm += __shfl_xor(sm, 16);
      sm += __shfl_xor(sm, 32);
      sacc[0][tt] = p0;
      sacc[1][tt] = p1;
      mx4[tt] = mx;
      if (lg == 0)
        *(float2*)&red[tt * 16 + l15][w * 2] = make_float2(mx, sm);
    }
    BARSYNC();  // [A]

    // ---- per-lane redundant merge for rows t = tt*16 + l15 ----
    float fac_p[4];
    {
      bool changed = false;
#pragma unroll
      for (int tt = 0; tt < 4; ++tt) {
        const int row = tt * 16 + l15;
        float4 r0 = *(const float4*)&red[row][0];
        float4 r1 = *(const float4*)&red[row][4];
        float4 r2 = *(const float4*)&red[row][8];
        float4 r3 = *(const float4*)&red[row][12];
        float mc = fmaxf(m_run[tt],
                   fmaxf(fmaxf(fmaxf(r0.x, r0.z), fmaxf(r1.x, r1.z)),
                         fmaxf(fmaxf(r2.x, r2.z), fmaxf(r3.x, r3.z))));
        const float m_new = (mc - m_run[tt] <= 11.0f) ? m_run[tt] : mc;
        float l_new = l_run[tt] * exp2f(m_run[tt] - m_new);
        l_new += r0.y * exp2f(r0.x - m_new) + r0.w * exp2f(r0.z - m_new);
        l_new += r1.y * exp2f(r1.x - m_new) + r1.w * exp2f(r1.z - m_new);
        l_new += r2.y * exp2f(r2.x - m_new) + r2.w * exp2f(r2.z - m_new);
        l_new += r3.y * exp2f(r3.x - m_new) + r3.w * exp2f(r3.z - m_new);
        fac_p[tt] = exp2f(mx4[tt] - m_new);
        if (m_new != m_run[tt]) changed = true;
        if (w == 0 && lg == 0) {
          fin_fac[row] = exp2f(m_run[tt] - m_new);
          if (st == 7) fin_invl[row] = 1.0f / l_new;
        }
        m_run[tt] = m_new;
        l_run[tt] = l_new;
      }
      if (w == 0 && changed) flagv[st & 1] = 1.0f;
    }
    // ---- P-write sh0: packed b64, swizzled [t][s-local] ----
#pragma unroll
    for (int tt = 0; tt < 4; ++tt) {
      const int row = tt * 16 + l15;
      const int g16 = w * 2 + (lg >> 1);
      const int sw16 = (g16 & 8) | ((g16 ^ row) & 7);
      const f32x4 pe = sacc[0][tt];
      const float fp = fac_p[tt];
      ushort4 pk = make_ushort4(f2h(pe[0] * fp), f2h(pe[1] * fp),
                                f2h(pe[2] * fp), f2h(pe[3] * fp));
      *(ushort4*)&Ps[row * 128 + sw16 * 8 + (lg & 1) * 4] = pk;
    }
    BARSYNC();  // [B] — Ps(sh0) + fin stable

    // ---- rescale (uniform skip via defer-max flag) ----
    {
      const float fl = flagv[st & 1];
      if (fl != 0.f) {
#pragma unroll
        for (int mt = 0; mt < 4; ++mt) {
          const f32x4 fac = *(const f32x4*)&fin_fac[mt * 16 + lg * 4];
#pragma unroll
          for (int ch = 0; ch < 2; ++ch)
#pragma unroll
            for (int nt = 0; nt < 2; ++nt) {
              pvm[mt][ch][nt] *= fac;
              pvs[mt][ch][nt] *= fac;
            }
        }
      }
      if (tid == 0) flagv[(st + 1) & 1] = 0.f;
    }

    // ---- PV: 2 halves x 8 steps; P-frags held across ch ----
#pragma unroll
    for (int half = 0; half < 2; ++half) {
      if (half == 1) {
        BARSYNC();  // [C] — half0 done reading Ps
#pragma unroll
        for (int tt = 0; tt < 4; ++tt) {
          const int row = tt * 16 + l15;
          const int g16 = w * 2 + (lg >> 1);
          const int sw16 = (g16 & 8) | ((g16 ^ row) & 7);
          const f32x4 pe = sacc[1][tt];
          const float fp = fac_p[tt];
          ushort4 pk = make_ushort4(f2h(pe[0] * fp), f2h(pe[1] * fp),
                                    f2h(pe[2] * fp), f2h(pe[3] * fp));
          *(ushort4*)&Ps[row * 128 + sw16 * 8 + (lg & 1) * 4] = pk;
        }
        BARSYNC();  // [D] — Ps(sh1) stable
      }
      f16x8 pf0, pf1, pf2, pf3;
#pragma unroll
      for (int pp = 0; pp < 8; ++pp) {
        const int P_ = half * 8 + pp;
        asm volatile("s_waitcnt vmcnt(2)" ::: "memory");
        const int bf = P_ & 1;
        const int ch = pp & 1, ksl = pp >> 1;
        if (ch == 0) {
          pf0 = readPa(0, ksl);
          pf1 = readPa(1, ksl);
          pf2 = readPa(2, ksl);
          pf3 = readPa(3, ksl);
        }
        f16x8 h0 = readH(bf, 0), h1 = readH(bf, 1);
        f16x8 q0 = h0 * h0, q1 = h1 * h1;
        __builtin_amdgcn_s_setprio(1);
        pvm[0][ch][0] = mfma16(pf0, h0, pvm[0][ch][0]);
        pvm[1][ch][0] = mfma16(pf1, h0, pvm[1][ch][0]);
        pvm[2][ch][0] = mfma16(pf2, h0, pvm[2][ch][0]);
        pvm[3][ch][0] = mfma16(pf3, h0, pvm[3][ch][0]);
        pvs[0][ch][0] = mfma16(pf0, q0, pvs[0][ch][0]);
        pvs[1][ch][0] = mfma16(pf1, q0, pvs[1][ch][0]);
        pvs[2][ch][0] = mfma16(pf2, q0, pvs[2][ch][0]);
        pvs[3][ch][0] = mfma16(pf3, q0, pvs[3][ch][0]);
        pvm[0][ch][1] = mfma16(pf0, h1, pvm[0][ch][1]);
        pvm[1][ch][1] = mfma16(pf1, h1, pvm[1][ch][1]);
        pvm[2][ch][1] = mfma16(pf2, h1, pvm[2][ch][1]);
        pvm[3][ch][1] = mfma16(pf3, h1, pvm[3][ch][1]);
        pvs[0][ch][1] = mfma16(pf0, q1, pvs[0][ch][1]);
        pvs[1][ch][1] = mfma16(pf1, q1, pvs[1][ch][1]);
        pvs[2][ch][1] = mfma16(pf2, q1, pvs[2][ch][1]);
        pvs[3][ch][1] = mfma16(pf3, q1, pvs[3][ch][1]);
        __builtin_amdgcn_s_setprio(0);
        __builtin_amdgcn_sched_barrier(0);
        const int pn = P_ + 2;
        if (pn < 16) stageH(st, pn, bf);
        else stageG(stn, 0, pn - 16, bf);  // next tile G chunks q=0,1
      }
    }
  }
  asm volatile("s_waitcnt vmcnt(0)" ::: "memory");

  // ---- epilogue: out[b][c][t] = std * (content - cm)*cr + mean ----
  f32x4 invq[4];
#pragma unroll
  for (int mt = 0; mt < 4; ++mt)
    invq[mt] = *(const f32x4*)&fin_invl[mt * 16 + lg * 4];
#pragma unroll
  for (int ch = 0; ch < 2; ++ch)
#pragma unroll
    for (int nt = 0; nt < 2; ++nt) {
      const int c = ch * 256 + w * 32 + nt * 16 + l15;
      const size_t row = (size_t)b * C_ + c;
      const float cm = cmean[row];
      const float cr = crstd[row];
      const float* cp = content + row * TC + t0;
      float* op = out + row * TC + t0;
#pragma unroll
      for (int mt = 0; mt < 4; ++mt) {
        const int q0 = mt * 16 + lg * 4;
        const float4 x = *(const float4*)(cp + q0);
        const f32x4 mu = pvm[mt][ch][nt] * invq[mt];
        const f32x4 se = pvs[mt][ch][nt] * invq[mt];
        float4 y;
        y.x = sqrtf(fmaxf(se[0] - mu[0] * mu[0], 0.f)) * ((x.x - cm) * cr) + mu[0];
        y.y = sqrtf(fmaxf(se[1] - mu[1] * mu[1], 0.f)) * ((x.y - cm) * cr) + mu[1];
        y.z = sqrtf(fmaxf(se[2] - mu[2] * mu[2], 0.f)) * ((x.z - cm) * cr) + mu[2];
        y.w = sqrtf(fmaxf(se[3] - mu[3] * mu[3], 0.f)) * ((x.w - cm) * cr) + mu[3];
        *(float4*)(op + q0) = y;
      }
    }
}

extern "C" void kernel_launch(void* const* d_in, const int* in_sizes, int n_in,
                              void* d_out, int out_size, void* d_ws, size_t ws_size,
                              hipStream_t stream) {
  (void)in_sizes;
  (void)n_in;
  (void)out_size;
  (void)ws_size;  // needs ~96 MB
  const float* content = (const float*)d_in[0];
  const float* style = (const float*)d_in[1];
  const float* content_key = (const float*)d_in[2];
  const float* style_key = (const float*)d_in[3];
  const float* Wf = (const float*)d_in[4];
  const float* bf = (const float*)d_in[5];
  const float* Wg = (const float*)d_in[6];
  const float* bg = (const float*)d_in[7];
  const float* Wh = (const float*)d_in[8];
  const float* bh = (const float*)d_in[9];
  float* out = (float*)d_out;

  char* ws = (char*)d_ws;
  u16* Ft = (u16*)(ws);
  u16* Gt = (u16*)(ws + 67108864);
  u16* Hm = (u16*)(ws + 83886080);
  float* cmean = (float*)(ws + 100663296);
  float* crstd = (float*)(ws + 100663296 + 16384);

  k_content_stats<<<dim3(B_ * C_), dim3(256), 0, stream>>>(content, cmean, crstd);
  k_conv<false><<<dim3(TC / 64, 2, B_), dim3(256), 0, stream>>>(content_key, Wf, bf, Ft, TC);
  k_conv<false><<<dim3(TS / 64, 2, B_), dim3(256), 0, stream>>>(style_key, Wg, bg, Gt, TS);
  k_conv<true><<<dim3(TS / 64, 2, B_), dim3(256), 0, stream>>>(style, Wh, bh, Hm, TS);

  k_attn<<<dim3(1024), dim3(512), 0, stream>>>(Ft, Gt, Hm, content, cmean, crstd, out);
}

// Round 6
// 778.625 us; speedup vs baseline: 2.0599x; 1.0474x over previous
//
#include <hip/hip_runtime.h>
#include <hip/hip_fp16.h>

// AdaAttN fused pipeline, fp16 MFMA path, single-pass flash attention.
// B=8, C=512, Tc=8192, Ts=2048.
//
// ws layout (bytes):
//   Ft  [8][8192][512] fp16 :      0 .. 67,108,864
//   Gt  [8][2048][512] fp16 : 67,108,864 .. 83,886,080
//   H   [8][512][2048] fp16 : 83,886,080 .. 100,663,296
//   cmean [4096] f32        : 100,663,296
//   crstd [4096] f32        : 100,679,680

#define B_ 8
#define C_ 512
#define TC 8192
#define TS 2048

typedef unsigned short u16;
typedef __attribute__((ext_vector_type(8))) _Float16 f16x8;
typedef __attribute__((ext_vector_type(4))) float f32x4;

__device__ __forceinline__ u16 f2h(float f) {
  return __half_as_ushort(__float2half(f));
}

__device__ __forceinline__ f32x4 mfma16(f16x8 a, f16x8 b, f32x4 c) {
  return __builtin_amdgcn_mfma_f32_16x16x32_f16(a, b, c, 0, 0, 0);
}

// async global->LDS, 16B per lane; LDS dest = wave-uniform base + lane*16
__device__ __forceinline__ void stage16(const u16* g, u16* l) {
  __builtin_amdgcn_global_load_lds(
      (__attribute__((address_space(1))) void*)(const void*)g,
      (__attribute__((address_space(3))) void*)l, 16, 0, 0);
}

// raw barrier: flush LDS ops, no vmcnt drain (keeps staging loads in flight)
#define BARSYNC()                                         \
  do {                                                    \
    asm volatile("s_waitcnt lgkmcnt(0)" ::: "memory");    \
    __builtin_amdgcn_s_barrier();                         \
    __builtin_amdgcn_sched_barrier(0);                    \
  } while (0)

// ---------------- K0: per-(b,c) content stats (ddof=1) ----------------
__global__ __launch_bounds__(256) void k_content_stats(
    const float* __restrict__ x, float* __restrict__ cmean, float* __restrict__ crstd) {
  const int row = blockIdx.x;  // b*512 + c
  const float4* p = (const float4*)(x + (size_t)row * TC);
  float s = 0.f, ss = 0.f;
  for (int i = threadIdx.x; i < TC / 4; i += 256) {
    float4 v = p[i];
    s += v.x + v.y + v.z + v.w;
    ss += v.x * v.x + v.y * v.y + v.z * v.z + v.w * v.w;
  }
#pragma unroll
  for (int d = 1; d < 64; d <<= 1) {
    s += __shfl_xor(s, d);
    ss += __shfl_xor(ss, d);
  }
  __shared__ float rs[4], rss[4];
  if ((threadIdx.x & 63) == 0) {
    rs[threadIdx.x >> 6] = s;
    rss[threadIdx.x >> 6] = ss;
  }
  __syncthreads();
  if (threadIdx.x == 0) {
    float S = rs[0] + rs[1] + rs[2] + rs[3];
    float SS = rss[0] + rss[1] + rss[2] + rss[3];
    float mean = S / (float)TC;
    float var = (SS - S * mean) / (float)(TC - 1);
    cmean[row] = mean;
    crstd[row] = rsqrtf(var + 1e-5f);
  }
}

// ---------------- conv1x1 GEMM (unchanged, verified) ----------------
template <bool TRANS_OUT>
__global__ __launch_bounds__(256, 3) void k_conv(
    const float* __restrict__ X, const float* __restrict__ W,
    const float* __restrict__ bias, u16* __restrict__ Y, int M) {
  const int b = blockIdx.z;
  const int m0 = blockIdx.x * 64;
  const int n0 = blockIdx.y * 256;
  const int tid = threadIdx.x;
  const int w = tid >> 6, ln = tid & 63, lg = ln >> 4, l15 = ln & 15;
  __shared__ u16 As[64][72];
  __shared__ u16 Bs[256][72];
  const float* Xb = X + (size_t)b * C_ * M;
  const f32x4 vzero = {0.f, 0.f, 0.f, 0.f};
  f32x4 acc[4][4];
#pragma unroll
  for (int i = 0; i < 4; ++i)
#pragma unroll
    for (int j = 0; j < 4; ++j) acc[i][j] = vzero;

  for (int k0 = 0; k0 < 512; k0 += 64) {
    __syncthreads();
    {  // stage A (transpose + cvt)
      const int kk = tid >> 2, c4 = tid & 3;
      const float* src = Xb + (size_t)(k0 + kk) * M + m0 + c4 * 16;
#pragma unroll
      for (int i = 0; i < 4; ++i) {
        float4 v = *(const float4*)(src + i * 4);
        const int mo = c4 * 16 + i * 4;
        As[mo + 0][kk] = f2h(v.x);
        As[mo + 1][kk] = f2h(v.y);
        As[mo + 2][kk] = f2h(v.z);
        As[mo + 3][kk] = f2h(v.w);
      }
    }
    {  // stage B
      const float* src = W + (size_t)(n0 + tid) * 512 + k0;
#pragma unroll
      for (int i = 0; i < 16; ++i) {
        float4 v = *(const float4*)(src + i * 4);
        ushort4 hq = make_ushort4(f2h(v.x), f2h(v.y), f2h(v.z), f2h(v.w));
        *(ushort4*)&Bs[tid][i * 4] = hq;
      }
    }
    __syncthreads();
#pragma unroll
    for (int ks = 0; ks < 2; ++ks) {
      f16x8 a[4], bb[4];
#pragma unroll
      for (int mt = 0; mt < 4; ++mt)
        a[mt] = *(const f16x8*)&As[mt * 16 + l15][ks * 32 + lg * 8];
#pragma unroll
      for (int nt = 0; nt < 4; ++nt)
        bb[nt] = *(const f16x8*)&Bs[w * 64 + nt * 16 + l15][ks * 32 + lg * 8];
#pragma unroll
      for (int mt = 0; mt < 4; ++mt)
#pragma unroll
        for (int nt = 0; nt < 4; ++nt)
          acc[mt][nt] = mfma16(a[mt], bb[nt], acc[mt][nt]);
    }
  }
#pragma unroll
  for (int nt = 0; nt < 4; ++nt) {
    const int n = n0 + w * 64 + nt * 16 + l15;
    const float bv = bias[n];
#pragma unroll
    for (int mt = 0; mt < 4; ++mt) {
      const int mb = m0 + mt * 16 + lg * 4;
      f32x4 v = acc[mt][nt];
      if (!TRANS_OUT) {
        u16* yp = Y + (size_t)b * M * 512 + (size_t)mb * 512 + n;
        yp[0 * 512] = f2h(v[0] + bv);
        yp[1 * 512] = f2h(v[1] + bv);
        yp[2 * 512] = f2h(v[2] + bv);
        yp[3 * 512] = f2h(v[3] + bv);
      } else {
        ushort4 hq = make_ushort4(f2h(v[0] + bv), f2h(v[1] + bv),
                                  f2h(v[2] + bv), f2h(v[3] + bv));
        *(ushort4*)(Y + (size_t)b * 512 * M + (size_t)n * M + mb) = hq;
      }
    }
  }
}

// ---------------- K5: flash attention, pointer-hoisted addressing ----------------
// Identical structure/math/ledger to round-5 (s-tile 256, F-frag reuse across
// sh halves, defer-max, vmcnt(2) ledger). All swizzled LDS addresses are
// decomposed into per-lane base pointers + compile-time immediate offsets
// (ds_read offset folding); staging global addresses are loop-carried
// pointers bumped once per tile, +kc*128B folded into the 13-bit offset.
__global__ __launch_bounds__(512, 2) void k_attn(
    const u16* __restrict__ Ft, const u16* __restrict__ Gt,
    const u16* __restrict__ Hm, const float* __restrict__ content,
    const float* __restrict__ cmean, const float* __restrict__ crstd,
    float* __restrict__ out) {
  __shared__ u16 Fq[64 * 512];     // byte = row*1024 + sw*16, sw=(g&56)|((g^row)&7)
  __shared__ u16 UG[2][128 * 64];  // byte = bf*16384 + row*128 + sw*16, sw=(ks*4|lg)^(row&7)
  __shared__ u16 UH[2][256 * 32];  // byte = bf*16384 + row*64 + sw*16
  __shared__ u16 Ps[64 * 128];     // byte = row*256 + sw*16
  __shared__ float red[64][20];    // [t-row][wave*2]: (max2, sum), stride 80B
  __shared__ float fin_fac[64];
  __shared__ float fin_invl[64];
  __shared__ float flagv[2];

  const int bid = blockIdx.x;
  const int swz = (bid & 7) * 128 + (bid >> 3);  // XCD-contiguous (1024%8==0)
  const int b = swz >> 7;
  const int t0 = (swz & 127) * 64;
  const int tid = threadIdx.x;
  const int w = tid >> 6, ln = tid & 63, lg = ln >> 4, l15 = ln & 15;

  const u16* Ftb = Ft + ((size_t)b * TC + t0) * C_;
  const u16* Gtb = Gt + (size_t)b * TS * C_;
  const u16* Hb = Hm + (size_t)b * C_ * TS;

  // ---- Fq stage: linear global read, swizzled LDS write ----
  {
    const int r = tid >> 3, c0 = tid & 7;
    const u16* src = Ftb + (size_t)r * C_;
#pragma unroll
    for (int i = 0; i < 8; ++i) {
      const int j = c0 + 8 * i;
      uint4 v = *(const uint4*)(src + j * 8);
      const int sw = (j & 56) | ((j ^ r) & 7);
      *(uint4*)&Fq[r * 512 + sw * 8] = v;
    }
  }
  if (tid < 2) flagv[tid] = 0.f;
  __syncthreads();  // full drain once; ledger starts clean

  // ---- per-lane swizzle base pointers (all reads = base + const imm) ----
  const int cF = lg ^ (l15 & 7);
  const char* pF0 = (const char*)Fq + l15 * 1024 + cF * 16;
  const char* pF1 = (const char*)Fq + l15 * 1024 + (cF ^ 4) * 16;
  const char* pG0 = (const char*)UG + (w * 16 + l15) * 128 + cF * 16;
  const char* pG1 = (const char*)UG + (w * 16 + l15) * 128 + (cF ^ 4) * 16;
  const int cH = lg ^ (l15 & 3) ^ ((l15 >> 2) & 3);
  const char* pH = (const char*)UH + (w * 32 + l15) * 64 + cH * 16;
  const char* pP0 = (const char*)Ps + l15 * 256 + cF * 16;
  const char* pP1 = (const char*)Ps + l15 * 256 + (cF ^ 4) * 16;
  const int cW = ((((w & 3) << 1) | (lg >> 1)) ^ (l15 & 7));
  char* pPw = (char*)Ps + l15 * 256 + (w & 4) * 32 + cW * 16 + (lg & 1) * 8;

  auto readF = [&](int tt, int kc_, int ks) -> f16x8 {
    return *(const f16x8*)((ks ? pF1 : pF0) + tt * 16384 + kc_ * 128);
  };
  auto readG = [&](int bf, int ks) -> f16x8 {
    return *(const f16x8*)((ks ? pG1 : pG0) + bf * 16384);
  };
  auto readH = [&](int bf, int nt) -> f16x8 {
    return *(const f16x8*)(pH + bf * 16384 + nt * 1024);
  };
  auto readPa = [&](int mt, int ksl) -> f16x8 {
    return *(const f16x8*)(((ksl & 1) ? pP1 : pP0) + mt * 4096 + (ksl & 2) * 64);
  };

  // ---- loop-carried staging source pointers (u16 units) ----
  const int gl = (ln & 7) ^ ((ln >> 3) & 7);
  const u16* sG[2][2];
#pragma unroll
  for (int sh = 0; sh < 2; ++sh)
#pragma unroll
    for (int i = 0; i < 2; ++i)
      sG[sh][i] = Gtb + (size_t)(sh * 128 + w * 16 + i * 8 + (ln >> 3)) * 512 + gl * 8;
  const int hl = (ln & 3) ^ ((ln >> 2) & 3) ^ ((ln >> 4) & 3);
  const u16* sH[2][2];
#pragma unroll
  for (int ch = 0; ch < 2; ++ch)
#pragma unroll
    for (int i = 0; i < 2; ++i)
      sH[ch][i] = Hb + (size_t)(ch * 256 + w * 32 + i * 16 + (ln >> 2)) * 2048 + hl * 8;

  auto stageG2 = [&](int kc_, int sh, int bf) {
    stage16(sG[sh][0] + kc_ * 64, (u16*)((char*)UG + bf * 16384 + (w * 16 + 0) * 128));
    stage16(sG[sh][1] + kc_ * 64, (u16*)((char*)UG + bf * 16384 + (w * 16 + 8) * 128));
  };
  auto stageH2 = [&](int hc, int bf) {
    const int ch = hc & 1, kslg = hc >> 1;
    stage16(sH[ch][0] + kslg * 32, (u16*)((char*)UH + bf * 16384 + (w * 32 + 0) * 64));
    stage16(sH[ch][1] + kslg * 32, (u16*)((char*)UH + bf * 16384 + (w * 32 + 16) * 64));
  };
  auto stageGn = [&](int sh, int bf, int dnext) {  // next tile, chunk (kc=0, sh)
    stage16(sG[sh][0] + dnext, (u16*)((char*)UG + bf * 16384 + (w * 16 + 0) * 128));
    stage16(sG[sh][1] + dnext, (u16*)((char*)UG + bf * 16384 + (w * 16 + 8) * 128));
  };

  // prologue stages: tile 0, G chunks (0,0)->buf0, (0,1)->buf1
  stageG2(0, 0, 0);
  stageG2(0, 1, 1);

  const f32x4 vzero = {0.f, 0.f, 0.f, 0.f};
  f32x4 pvm[4][2][2], pvs[4][2][2];
#pragma unroll
  for (int mt = 0; mt < 4; ++mt)
#pragma unroll
    for (int ch = 0; ch < 2; ++ch)
#pragma unroll
      for (int nt = 0; nt < 2; ++nt) {
        pvm[mt][ch][nt] = vzero;
        pvs[mt][ch][nt] = vzero;
      }
  // per-lane online state for its 4 t-rows (tt*16 + l15), base-2 units
  float m_run[4] = {-1e30f, -1e30f, -1e30f, -1e30f};
  float l_run[4] = {0.f, 0.f, 0.f, 0.f};
  const float LOG2E = 1.44269504f;

  for (int st = 0; st < 8; ++st) {
    if (st > 0) {
#pragma unroll
      for (int sh = 0; sh < 2; ++sh)
#pragma unroll
        for (int i = 0; i < 2; ++i) {
          sG[sh][i] += 131072;  // +256 s-rows
          sH[sh][i] += 256;     // +512 B along s
        }
    }
    const int dnext = (st == 7) ? -917504 : 131072;
    f32x4 sacc[2][4];  // [sh][tt]
#pragma unroll
    for (int sh = 0; sh < 2; ++sh)
#pragma unroll
      for (int tt = 0; tt < 4; ++tt) sacc[sh][tt] = vzero;

    // ---- QK: 16 phases (kc x sh); F-frags read at sh==0, reused at sh==1 ----
#pragma unroll
    for (int kc = 0; kc < 8; ++kc) {
      f16x8 fA[2][4];
#pragma unroll
      for (int sh = 0; sh < 2; ++sh) {
        const int q = kc * 2 + sh;
        asm volatile("s_waitcnt vmcnt(2)" ::: "memory");
        const int bf = q & 1;
        if (sh == 0) {
#pragma unroll
          for (int ks = 0; ks < 2; ++ks)
#pragma unroll
            for (int tt = 0; tt < 4; ++tt) fA[ks][tt] = readF(tt, kc, ks);
        }
        __builtin_amdgcn_s_setprio(1);
#pragma unroll
        for (int ks = 0; ks < 2; ++ks) {
          f16x8 gv = readG(bf, ks);
          sacc[sh][0] = mfma16(gv, fA[ks][0], sacc[sh][0]);
          sacc[sh][1] = mfma16(gv, fA[ks][1], sacc[sh][1]);
          sacc[sh][2] = mfma16(gv, fA[ks][2], sacc[sh][2]);
          sacc[sh][3] = mfma16(gv, fA[ks][3], sacc[sh][3]);
        }
        __builtin_amdgcn_s_setprio(0);
        __builtin_amdgcn_sched_barrier(0);
        const int qn = q + 2;
        if (qn < 16) stageG2(qn >> 1, qn & 1, bf);
        else stageH2(qn - 16, bf);  // qn=16,17 -> H chunks 0,1
      }
    }

    // ---- per-wave partial stats over this wave's 32 s (2 sh x 4 rg + lg) ----
    float mx4[4];
#pragma unroll
    for (int tt = 0; tt < 4; ++tt) {
      f32x4 v0 = sacc[0][tt] * LOG2E;
      f32x4 v1 = sacc[1][tt] * LOG2E;
      float mx = fmaxf(fmaxf(fmaxf(v0[0], v0[1]), fmaxf(v0[2], v0[3])),
                       fmaxf(fmaxf(v1[0], v1[1]), fmaxf(v1[2], v1[3])));
      mx = fmaxf(mx, __shfl_xor(mx, 16));
      mx = fmaxf(mx, __shfl_xor(mx, 32));
      f32x4 p0, p1;
#pragma unroll
      for (int rg = 0; rg < 4; ++rg) {
        p0[rg] = exp2f(v0[rg] - mx);
        p1[rg] = exp2f(v1[rg] - mx);
      }
      float sm = p0[0] + p0[1] + p0[2] + p0[3] + p1[0] + p1[1] + p1[2] + p1[3];
      sm += __shfl_xor(sm, 16);
      sm += __shfl_xor(sm, 32);
      sacc[0][tt] = p0;
      sacc[1][tt] = p1;
      mx4[tt] = mx;
      if (lg == 0)
        *(float2*)&red[tt * 16 + l15][w * 2] = make_float2(mx, sm);
    }
    BARSYNC();  // [A]

    // ---- per-lane redundant merge for rows t = tt*16 + l15 ----
    float fac_p[4];
    {
      bool changed = false;
#pragma unroll
      for (int tt = 0; tt < 4; ++tt) {
        const int row = tt * 16 + l15;
        float4 r0 = *(const float4*)&red[row][0];
        float4 r1 = *(const float4*)&red[row][4];
        float4 r2 = *(const float4*)&red[row][8];
        float4 r3 = *(const float4*)&red[row][12];
        float mc = fmaxf(m_run[tt],
                   fmaxf(fmaxf(fmaxf(r0.x, r0.z), fmaxf(r1.x, r1.z)),
                         fmaxf(fmaxf(r2.x, r2.z), fmaxf(r3.x, r3.z))));
        const float m_new = (mc - m_run[tt] <= 11.0f) ? m_run[tt] : mc;
        float l_new = l_run[tt] * exp2f(m_run[tt] - m_new);
        l_new += r0.y * exp2f(r0.x - m_new) + r0.w * exp2f(r0.z - m_new);
        l_new += r1.y * exp2f(r1.x - m_new) + r1.w * exp2f(r1.z - m_new);
        l_new += r2.y * exp2f(r2.x - m_new) + r2.w * exp2f(r2.z - m_new);
        l_new += r3.y * exp2f(r3.x - m_new) + r3.w * exp2f(r3.z - m_new);
        fac_p[tt] = exp2f(mx4[tt] - m_new);
        if (m_new != m_run[tt]) changed = true;
        if (w == 0 && lg == 0) {
          fin_fac[row] = exp2f(m_run[tt] - m_new);
          if (st == 7) fin_invl[row] = 1.0f / l_new;
        }
        m_run[tt] = m_new;
        l_run[tt] = l_new;
      }
      if (w == 0 && changed) flagv[st & 1] = 1.0f;
    }
    // ---- P-write sh0: packed b64, swizzled [t][s-local] ----
#pragma unroll
    for (int tt = 0; tt < 4; ++tt) {
      const f32x4 pe = sacc[0][tt];
      const float fp = fac_p[tt];
      ushort4 pk = make_ushort4(f2h(pe[0] * fp), f2h(pe[1] * fp),
                                f2h(pe[2] * fp), f2h(pe[3] * fp));
      *(ushort4*)(pPw + tt * 4096) = pk;
    }
    BARSYNC();  // [B] — Ps(sh0) + fin stable

    // ---- rescale (uniform skip via defer-max flag) ----
    {
      const float fl = flagv[st & 1];
      if (fl != 0.f) {
#pragma unroll
        for (int mt = 0; mt < 4; ++mt) {
          const f32x4 fac = *(const f32x4*)&fin_fac[mt * 16 + lg * 4];
#pragma unroll
          for (int ch = 0; ch < 2; ++ch)
#pragma unroll
            for (int nt = 0; nt < 2; ++nt) {
              pvm[mt][ch][nt] *= fac;
              pvs[mt][ch][nt] *= fac;
            }
        }
      }
      if (tid == 0) flagv[(st + 1) & 1] = 0.f;
    }

    // ---- PV: 2 halves x 8 phases; P-frags held across ch ----
#pragma unroll
    for (int half = 0; half < 2; ++half) {
      if (half == 1) {
        BARSYNC();  // [C] — half0 done reading Ps
#pragma unroll
        for (int tt = 0; tt < 4; ++tt) {
          const f32x4 pe = sacc[1][tt];
          const float fp = fac_p[tt];
          ushort4 pk = make_ushort4(f2h(pe[0] * fp), f2h(pe[1] * fp),
                                    f2h(pe[2] * fp), f2h(pe[3] * fp));
          *(ushort4*)(pPw + tt * 4096) = pk;
        }
        BARSYNC();  // [D] — Ps(sh1) stable
      }
      f16x8 pf0, pf1, pf2, pf3;
#pragma unroll
      for (int pp = 0; pp < 8; ++pp) {
        const int P_ = half * 8 + pp;
        asm volatile("s_waitcnt vmcnt(2)" ::: "memory");
        const int bf = P_ & 1;
        const int ch = pp & 1, ksl = pp >> 1;
        if (ch == 0) {
          pf0 = readPa(0, ksl);
          pf1 = readPa(1, ksl);
          pf2 = readPa(2, ksl);
          pf3 = readPa(3, ksl);
        }
        f16x8 h0 = readH(bf, 0), h1 = readH(bf, 1);
        f16x8 q0 = h0 * h0, q1 = h1 * h1;
        __builtin_amdgcn_s_setprio(1);
        pvm[0][ch][0] = mfma16(pf0, h0, pvm[0][ch][0]);
        pvm[1][ch][0] = mfma16(pf1, h0, pvm[1][ch][0]);
        pvm[2][ch][0] = mfma16(pf2, h0, pvm[2][ch][0]);
        pvm[3][ch][0] = mfma16(pf3, h0, pvm[3][ch][0]);
        pvs[0][ch][0] = mfma16(pf0, q0, pvs[0][ch][0]);
        pvs[1][ch][0] = mfma16(pf1, q0, pvs[1][ch][0]);
        pvs[2][ch][0] = mfma16(pf2, q0, pvs[2][ch][0]);
        pvs[3][ch][0] = mfma16(pf3, q0, pvs[3][ch][0]);
        pvm[0][ch][1] = mfma16(pf0, h1, pvm[0][ch][1]);
        pvm[1][ch][1] = mfma16(pf1, h1, pvm[1][ch][1]);
        pvm[2][ch][1] = mfma16(pf2, h1, pvm[2][ch][1]);
        pvm[3][ch][1] = mfma16(pf3, h1, pvm[3][ch][1]);
        pvs[0][ch][1] = mfma16(pf0, q1, pvs[0][ch][1]);
        pvs[1][ch][1] = mfma16(pf1, q1, pvs[1][ch][1]);
        pvs[2][ch][1] = mfma16(pf2, q1, pvs[2][ch][1]);
        pvs[3][ch][1] = mfma16(pf3, q1, pvs[3][ch][1]);
        __builtin_amdgcn_s_setprio(0);
        __builtin_amdgcn_sched_barrier(0);
        const int pn = P_ + 2;
        if (pn < 16) stageH2(pn, bf);
        else stageGn(pn - 16, bf, dnext);  // next tile G chunks (0,0),(0,1)
      }
    }
  }
  asm volatile("s_waitcnt vmcnt(0)" ::: "memory");

  // ---- epilogue: out[b][c][t] = std * (content - cm)*cr + mean ----
  f32x4 invq[4];
#pragma unroll
  for (int mt = 0; mt < 4; ++mt)
    invq[mt] = *(const f32x4*)&fin_invl[mt * 16 + lg * 4];
#pragma unroll
  for (int ch = 0; ch < 2; ++ch)
#pragma unroll
    for (int nt = 0; nt < 2; ++nt) {
      const int c = ch * 256 + w * 32 + nt * 16 + l15;
      const size_t row = (size_t)b * C_ + c;
      const float cm = cmean[row];
      const float cr = crstd[row];
      const float* cp = content + row * TC + t0;
      float* op = out + row * TC + t0;
#pragma unroll
      for (int mt = 0; mt < 4; ++mt) {
        const int q0 = mt * 16 + lg * 4;
        const float4 x = *(const float4*)(cp + q0);
        const f32x4 mu = pvm[mt][ch][nt] * invq[mt];
        const f32x4 se = pvs[mt][ch][nt] * invq[mt];
        float4 y;
        y.x = sqrtf(fmaxf(se[0] - mu[0] * mu[0], 0.f)) * ((x.x - cm) * cr) + mu[0];
        y.y = sqrtf(fmaxf(se[1] - mu[1] * mu[1], 0.f)) * ((x.y - cm) * cr) + mu[1];
        y.z = sqrtf(fmaxf(se[2] - mu[2] * mu[2], 0.f)) * ((x.z - cm) * cr) + mu[2];
        y.w = sqrtf(fmaxf(se[3] - mu[3] * mu[3], 0.f)) * ((x.w - cm) * cr) + mu[3];
        *(float4*)(op + q0) = y;
      }
    }
}

extern "C" void kernel_launch(void* const* d_in, const int* in_sizes, int n_in,
                              void* d_out, int out_size, void* d_ws, size_t ws_size,
                              hipStream_t stream) {
  (void)in_sizes;
  (void)n_in;
  (void)out_size;
  (void)ws_size;  // needs ~96 MB
  const float* content = (const float*)d_in[0];
  const float* style = (const float*)d_in[1];
  const float* content_key = (const float*)d_in[2];
  const float* style_key = (const float*)d_in[3];
  const float* Wf = (const float*)d_in[4];
  const float* bf = (const float*)d_in[5];
  const float* Wg = (const float*)d_in[6];
  const float* bg = (const float*)d_in[7];
  const float* Wh = (const float*)d_in[8];
  const float* bh = (const float*)d_in[9];
  float* out = (float*)d_out;

  char* ws = (char*)d_ws;
  u16* Ft = (u16*)(ws);
  u16* Gt = (u16*)(ws + 67108864);
  u16* Hm = (u16*)(ws + 83886080);
  float* cmean = (float*)(ws + 100663296);
  float* crstd = (float*)(ws + 100663296 + 16384);

  k_content_stats<<<dim3(B_ * C_), dim3(256), 0, stream>>>(content, cmean, crstd);
  k_conv<false><<<dim3(TC / 64, 2, B_), dim3(256), 0, stream>>>(content_key, Wf, bf, Ft, TC);
  k_conv<false><<<dim3(TS / 64, 2, B_), dim3(256), 0, stream>>>(style_key, Wg, bg, Gt, TS);
  k_conv<true><<<dim3(TS / 64, 2, B_), dim3(256), 0, stream>>>(style, Wh, bh, Hm, TS);

  k_attn<<<dim3(1024), dim3(512), 0, stream>>>(Ft, Gt, Hm, content, cmean, crstd, out);
}

// Round 7
// 770.913 us; speedup vs baseline: 2.0805x; 1.0100x over previous
//
#include <hip/hip_runtime.h>
#include <hip/hip_fp16.h>

// AdaAttN fused pipeline, fp16 MFMA path, single-pass flash attention.
// B=8, C=512, Tc=8192, Ts=2048.
//
// ws layout (bytes):
//   Ft  [8][8192][512] fp16 :      0 .. 67,108,864
//   Gt  [8][2048][512] fp16 : 67,108,864 .. 83,886,080
//   H   [8][512][2048] fp16 : 83,886,080 .. 100,663,296
//   cmean [4096] f32        : 100,663,296
//   crstd [4096] f32        : 100,679,680

#define B_ 8
#define C_ 512
#define TC 8192
#define TS 2048

typedef unsigned short u16;
typedef __attribute__((ext_vector_type(8))) _Float16 f16x8;
typedef __attribute__((ext_vector_type(4))) float f32x4;

__device__ __forceinline__ u16 f2h(float f) {
  return __half_as_ushort(__float2half(f));
}

__device__ __forceinline__ f32x4 mfma16(f16x8 a, f16x8 b, f32x4 c) {
  return __builtin_amdgcn_mfma_f32_16x16x32_f16(a, b, c, 0, 0, 0);
}

// async global->LDS, 16B per lane; LDS dest = wave-uniform base + lane*16
__device__ __forceinline__ void stage16(const u16* g, u16* l) {
  __builtin_amdgcn_global_load_lds(
      (__attribute__((address_space(1))) void*)(const void*)g,
      (__attribute__((address_space(3))) void*)l, 16, 0, 0);
}

// raw barrier: flush LDS ops, no vmcnt drain (keeps staging loads in flight)
#define BARSYNC()                                         \
  do {                                                    \
    asm volatile("s_waitcnt lgkmcnt(0)" ::: "memory");    \
    __builtin_amdgcn_s_barrier();                         \
    __builtin_amdgcn_sched_barrier(0);                    \
  } while (0)

// ---------------- K0: per-(b,c) content stats (ddof=1) ----------------
__global__ __launch_bounds__(256) void k_content_stats(
    const float* __restrict__ x, float* __restrict__ cmean, float* __restrict__ crstd) {
  const int row = blockIdx.x;  // b*512 + c
  const float4* p = (const float4*)(x + (size_t)row * TC);
  float s = 0.f, ss = 0.f;
  for (int i = threadIdx.x; i < TC / 4; i += 256) {
    float4 v = p[i];
    s += v.x + v.y + v.z + v.w;
    ss += v.x * v.x + v.y * v.y + v.z * v.z + v.w * v.w;
  }
#pragma unroll
  for (int d = 1; d < 64; d <<= 1) {
    s += __shfl_xor(s, d);
    ss += __shfl_xor(ss, d);
  }
  __shared__ float rs[4], rss[4];
  if ((threadIdx.x & 63) == 0) {
    rs[threadIdx.x >> 6] = s;
    rss[threadIdx.x >> 6] = ss;
  }
  __syncthreads();
  if (threadIdx.x == 0) {
    float S = rs[0] + rs[1] + rs[2] + rs[3];
    float SS = rss[0] + rss[1] + rss[2] + rss[3];
    float mean = S / (float)TC;
    float var = (SS - S * mean) / (float)(TC - 1);
    cmean[row] = mean;
    crstd[row] = rsqrtf(var + 1e-5f);
  }
}

// ---------------- conv1x1 GEMM ----------------
// A-stage: 4x4 in-register transpose, packed ushort4 LDS writes (was 16 scalar).
template <bool TRANS_OUT>
__global__ __launch_bounds__(256, 3) void k_conv(
    const float* __restrict__ X, const float* __restrict__ W,
    const float* __restrict__ bias, u16* __restrict__ Y, int M) {
  const int b = blockIdx.z;
  const int m0 = blockIdx.x * 64;
  const int n0 = blockIdx.y * 256;
  const int tid = threadIdx.x;
  const int w = tid >> 6, ln = tid & 63, lg = ln >> 4, l15 = ln & 15;
  __shared__ u16 As[64][72];
  __shared__ u16 Bs[256][72];
  const float* Xb = X + (size_t)b * C_ * M;
  const f32x4 vzero = {0.f, 0.f, 0.f, 0.f};
  f32x4 acc[4][4];
#pragma unroll
  for (int i = 0; i < 4; ++i)
#pragma unroll
    for (int j = 0; j < 4; ++j) acc[i][j] = vzero;

  const int mq = tid & 15, kq = tid >> 4;  // m-quad (coalesced), k-quad
  for (int k0 = 0; k0 < 512; k0 += 64) {
    __syncthreads();
    {  // stage A: X[k0..+64][m0..+64] -> As[m][k], 4x4 reg transpose
      const float* src = Xb + (size_t)(k0 + kq * 4) * M + m0 + mq * 4;
      float4 r0 = *(const float4*)(src);
      float4 r1 = *(const float4*)(src + M);
      float4 r2 = *(const float4*)(src + 2 * M);
      float4 r3 = *(const float4*)(src + 3 * M);
      *(ushort4*)&As[mq * 4 + 0][kq * 4] =
          make_ushort4(f2h(r0.x), f2h(r1.x), f2h(r2.x), f2h(r3.x));
      *(ushort4*)&As[mq * 4 + 1][kq * 4] =
          make_ushort4(f2h(r0.y), f2h(r1.y), f2h(r2.y), f2h(r3.y));
      *(ushort4*)&As[mq * 4 + 2][kq * 4] =
          make_ushort4(f2h(r0.z), f2h(r1.z), f2h(r2.z), f2h(r3.z));
      *(ushort4*)&As[mq * 4 + 3][kq * 4] =
          make_ushort4(f2h(r0.w), f2h(r1.w), f2h(r2.w), f2h(r3.w));
    }
    {  // stage B
      const float* src = W + (size_t)(n0 + tid) * 512 + k0;
#pragma unroll
      for (int i = 0; i < 16; ++i) {
        float4 v = *(const float4*)(src + i * 4);
        ushort4 hq = make_ushort4(f2h(v.x), f2h(v.y), f2h(v.z), f2h(v.w));
        *(ushort4*)&Bs[tid][i * 4] = hq;
      }
    }
    __syncthreads();
#pragma unroll
    for (int ks = 0; ks < 2; ++ks) {
      f16x8 a[4], bb[4];
#pragma unroll
      for (int mt = 0; mt < 4; ++mt)
        a[mt] = *(const f16x8*)&As[mt * 16 + l15][ks * 32 + lg * 8];
#pragma unroll
      for (int nt = 0; nt < 4; ++nt)
        bb[nt] = *(const f16x8*)&Bs[w * 64 + nt * 16 + l15][ks * 32 + lg * 8];
#pragma unroll
      for (int mt = 0; mt < 4; ++mt)
#pragma unroll
        for (int nt = 0; nt < 4; ++nt)
          acc[mt][nt] = mfma16(a[mt], bb[nt], acc[mt][nt]);
    }
  }
#pragma unroll
  for (int nt = 0; nt < 4; ++nt) {
    const int n = n0 + w * 64 + nt * 16 + l15;
    const float bv = bias[n];
#pragma unroll
    for (int mt = 0; mt < 4; ++mt) {
      const int mb = m0 + mt * 16 + lg * 4;
      f32x4 v = acc[mt][nt];
      if (!TRANS_OUT) {
        u16* yp = Y + (size_t)b * M * 512 + (size_t)mb * 512 + n;
        yp[0 * 512] = f2h(v[0] + bv);
        yp[1 * 512] = f2h(v[1] + bv);
        yp[2 * 512] = f2h(v[2] + bv);
        yp[3 * 512] = f2h(v[3] + bv);
      } else {
        ushort4 hq = make_ushort4(f2h(v[0] + bv), f2h(v[1] + bv),
                                  f2h(v[2] + bv), f2h(v[3] + bv));
        *(ushort4*)(Y + (size_t)b * 512 * M + (size_t)n * M + mb) = hq;
      }
    }
  }
}

// ---------------- K5: flash attention (r6 structure, unpinned scheduling) ----
// sched_barrier(0) per-phase pins REMOVED: Fq reads are ledger-free (write-once)
// so the compiler may hoist them across MFMA clusters; stage16/ds_reads are
// still fenced by the asm-volatile vmcnt waits and same-address dependences.
__global__ __launch_bounds__(512, 2) void k_attn(
    const u16* __restrict__ Ft, const u16* __restrict__ Gt,
    const u16* __restrict__ Hm, const float* __restrict__ content,
    const float* __restrict__ cmean, const float* __restrict__ crstd,
    float* __restrict__ out) {
  __shared__ u16 Fq[64 * 512];     // byte = row*1024 + sw*16, sw=(g&56)|((g^row)&7)
  __shared__ u16 UG[2][128 * 64];  // byte = bf*16384 + row*128 + sw*16
  __shared__ u16 UH[2][256 * 32];  // byte = bf*16384 + row*64 + sw*16
  __shared__ u16 Ps[64 * 128];     // byte = row*256 + sw*16
  __shared__ float red[64][20];    // [t-row][wave*2]: (max2, sum), stride 80B
  __shared__ float fin_fac[64];
  __shared__ float fin_invl[64];
  __shared__ float flagv[2];

  const int bid = blockIdx.x;
  const int swz = (bid & 7) * 128 + (bid >> 3);  // XCD-contiguous (1024%8==0)
  const int b = swz >> 7;
  const int t0 = (swz & 127) * 64;
  const int tid = threadIdx.x;
  const int w = tid >> 6, ln = tid & 63, lg = ln >> 4, l15 = ln & 15;

  const u16* Ftb = Ft + ((size_t)b * TC + t0) * C_;
  const u16* Gtb = Gt + (size_t)b * TS * C_;
  const u16* Hb = Hm + (size_t)b * C_ * TS;

  // ---- Fq stage: linear global read, swizzled LDS write ----
  {
    const int r = tid >> 3, c0 = tid & 7;
    const u16* src = Ftb + (size_t)r * C_;
#pragma unroll
    for (int i = 0; i < 8; ++i) {
      const int j = c0 + 8 * i;
      uint4 v = *(const uint4*)(src + j * 8);
      const int sw = (j & 56) | ((j ^ r) & 7);
      *(uint4*)&Fq[r * 512 + sw * 8] = v;
    }
  }
  if (tid < 2) flagv[tid] = 0.f;
  __syncthreads();  // full drain once; ledger starts clean

  // ---- per-lane swizzle base pointers (all reads = base + const imm) ----
  const int cF = lg ^ (l15 & 7);
  const char* pF0 = (const char*)Fq + l15 * 1024 + cF * 16;
  const char* pF1 = (const char*)Fq + l15 * 1024 + (cF ^ 4) * 16;
  const char* pG0 = (const char*)UG + (w * 16 + l15) * 128 + cF * 16;
  const char* pG1 = (const char*)UG + (w * 16 + l15) * 128 + (cF ^ 4) * 16;
  const int cH = lg ^ (l15 & 3) ^ ((l15 >> 2) & 3);
  const char* pH = (const char*)UH + (w * 32 + l15) * 64 + cH * 16;
  const char* pP0 = (const char*)Ps + l15 * 256 + cF * 16;
  const char* pP1 = (const char*)Ps + l15 * 256 + (cF ^ 4) * 16;
  const int cW = ((((w & 3) << 1) | (lg >> 1)) ^ (l15 & 7));
  char* pPw = (char*)Ps + l15 * 256 + (w & 4) * 32 + cW * 16 + (lg & 1) * 8;

  auto readF = [&](int tt, int kc_, int ks) -> f16x8 {
    return *(const f16x8*)((ks ? pF1 : pF0) + tt * 16384 + kc_ * 128);
  };
  auto readG = [&](int bf, int ks) -> f16x8 {
    return *(const f16x8*)((ks ? pG1 : pG0) + bf * 16384);
  };
  auto readH = [&](int bf, int nt) -> f16x8 {
    return *(const f16x8*)(pH + bf * 16384 + nt * 1024);
  };
  auto readPa = [&](int mt, int ksl) -> f16x8 {
    return *(const f16x8*)(((ksl & 1) ? pP1 : pP0) + mt * 4096 + (ksl & 2) * 64);
  };

  // ---- loop-carried staging source pointers (u16 units) ----
  const int gl = (ln & 7) ^ ((ln >> 3) & 7);
  const u16* sG[2][2];
#pragma unroll
  for (int sh = 0; sh < 2; ++sh)
#pragma unroll
    for (int i = 0; i < 2; ++i)
      sG[sh][i] = Gtb + (size_t)(sh * 128 + w * 16 + i * 8 + (ln >> 3)) * 512 + gl * 8;
  const int hl = (ln & 3) ^ ((ln >> 2) & 3) ^ ((ln >> 4) & 3);
  const u16* sH[2][2];
#pragma unroll
  for (int ch = 0; ch < 2; ++ch)
#pragma unroll
    for (int i = 0; i < 2; ++i)
      sH[ch][i] = Hb + (size_t)(ch * 256 + w * 32 + i * 16 + (ln >> 2)) * 2048 + hl * 8;

  auto stageG2 = [&](int kc_, int sh, int bf) {
    stage16(sG[sh][0] + kc_ * 64, (u16*)((char*)UG + bf * 16384 + (w * 16 + 0) * 128));
    stage16(sG[sh][1] + kc_ * 64, (u16*)((char*)UG + bf * 16384 + (w * 16 + 8) * 128));
  };
  auto stageH2 = [&](int hc, int bf) {
    const int ch = hc & 1, kslg = hc >> 1;
    stage16(sH[ch][0] + kslg * 32, (u16*)((char*)UH + bf * 16384 + (w * 32 + 0) * 64));
    stage16(sH[ch][1] + kslg * 32, (u16*)((char*)UH + bf * 16384 + (w * 32 + 16) * 64));
  };
  auto stageGn = [&](int sh, int bf, int dnext) {  // next tile, chunk (kc=0, sh)
    stage16(sG[sh][0] + dnext, (u16*)((char*)UG + bf * 16384 + (w * 16 + 0) * 128));
    stage16(sG[sh][1] + dnext, (u16*)((char*)UG + bf * 16384 + (w * 16 + 8) * 128));
  };

  // prologue stages: tile 0, G chunks (0,0)->buf0, (0,1)->buf1
  stageG2(0, 0, 0);
  stageG2(0, 1, 1);

  const f32x4 vzero = {0.f, 0.f, 0.f, 0.f};
  f32x4 pvm[4][2][2], pvs[4][2][2];
#pragma unroll
  for (int mt = 0; mt < 4; ++mt)
#pragma unroll
    for (int ch = 0; ch < 2; ++ch)
#pragma unroll
      for (int nt = 0; nt < 2; ++nt) {
        pvm[mt][ch][nt] = vzero;
        pvs[mt][ch][nt] = vzero;
      }
  // per-lane online state for its 4 t-rows (tt*16 + l15), base-2 units
  float m_run[4] = {-1e30f, -1e30f, -1e30f, -1e30f};
  float l_run[4] = {0.f, 0.f, 0.f, 0.f};
  const float LOG2E = 1.44269504f;

  for (int st = 0; st < 8; ++st) {
    if (st > 0) {
#pragma unroll
      for (int sh = 0; sh < 2; ++sh)
#pragma unroll
        for (int i = 0; i < 2; ++i) {
          sG[sh][i] += 131072;  // +256 s-rows
          sH[sh][i] += 256;     // +512 B along s
        }
    }
    const int dnext = (st == 7) ? -917504 : 131072;
    f32x4 sacc[2][4];  // [sh][tt]
#pragma unroll
    for (int sh = 0; sh < 2; ++sh)
#pragma unroll
      for (int tt = 0; tt < 4; ++tt) sacc[sh][tt] = vzero;

    // ---- QK: 16 phases (kc x sh); F-frags read at sh==0, reused at sh==1 ----
#pragma unroll
    for (int kc = 0; kc < 8; ++kc) {
      f16x8 fA[2][4];
#pragma unroll
      for (int sh = 0; sh < 2; ++sh) {
        const int q = kc * 2 + sh;
        asm volatile("s_waitcnt vmcnt(2)" ::: "memory");
        const int bf = q & 1;
        if (sh == 0) {
#pragma unroll
          for (int ks = 0; ks < 2; ++ks)
#pragma unroll
            for (int tt = 0; tt < 4; ++tt) fA[ks][tt] = readF(tt, kc, ks);
        }
        __builtin_amdgcn_s_setprio(1);
#pragma unroll
        for (int ks = 0; ks < 2; ++ks) {
          f16x8 gv = readG(bf, ks);
          sacc[sh][0] = mfma16(gv, fA[ks][0], sacc[sh][0]);
          sacc[sh][1] = mfma16(gv, fA[ks][1], sacc[sh][1]);
          sacc[sh][2] = mfma16(gv, fA[ks][2], sacc[sh][2]);
          sacc[sh][3] = mfma16(gv, fA[ks][3], sacc[sh][3]);
        }
        __builtin_amdgcn_s_setprio(0);
        const int qn = q + 2;
        if (qn < 16) stageG2(qn >> 1, qn & 1, bf);
        else stageH2(qn - 16, bf);  // qn=16,17 -> H chunks 0,1
      }
    }

    // ---- per-wave partial stats over this wave's 32 s (2 sh x 4 rg + lg) ----
    float mx4[4];
#pragma unroll
    for (int tt = 0; tt < 4; ++tt) {
      f32x4 v0 = sacc[0][tt] * LOG2E;
      f32x4 v1 = sacc[1][tt] * LOG2E;
      float mx = fmaxf(fmaxf(fmaxf(v0[0], v0[1]), fmaxf(v0[2], v0[3])),
                       fmaxf(fmaxf(v1[0], v1[1]), fmaxf(v1[2], v1[3])));
      mx = fmaxf(mx, __shfl_xor(mx, 16));
      mx = fmaxf(mx, __shfl_xor(mx, 32));
      f32x4 p0, p1;
#pragma unroll
      for (int rg = 0; rg < 4; ++rg) {
        p0[rg] = exp2f(v0[rg] - mx);
        p1[rg] = exp2f(v1[rg] - mx);
      }
      float sm = p0[0] + p0[1] + p0[2] + p0[3] + p1[0] + p1[1] + p1[2] + p1[3];
      sm += __shfl_xor(sm, 16);
      sm += __shfl_xor(sm, 32);
      sacc[0][tt] = p0;
      sacc[1][tt] = p1;
      mx4[tt] = mx;
      if (lg == 0)
        *(float2*)&red[tt * 16 + l15][w * 2] = make_float2(mx, sm);
    }
    BARSYNC();  // [A]

    // ---- per-lane redundant merge for rows t = tt*16 + l15 ----
    float fac_p[4];
    {
      bool changed = false;
#pragma unroll
      for (int tt = 0; tt < 4; ++tt) {
        const int row = tt * 16 + l15;
        float4 r0 = *(const float4*)&red[row][0];
        float4 r1 = *(const float4*)&red[row][4];
        float4 r2 = *(const float4*)&red[row][8];
        float4 r3 = *(const float4*)&red[row][12];
        float mc = fmaxf(m_run[tt],
                   fmaxf(fmaxf(fmaxf(r0.x, r0.z), fmaxf(r1.x, r1.z)),
                         fmaxf(fmaxf(r2.x, r2.z), fmaxf(r3.x, r3.z))));
        const float m_new = (mc - m_run[tt] <= 11.0f) ? m_run[tt] : mc;
        float l_new = l_run[tt] * exp2f(m_run[tt] - m_new);
        l_new += r0.y * exp2f(r0.x - m_new) + r0.w * exp2f(r0.z - m_new);
        l_new += r1.y * exp2f(r1.x - m_new) + r1.w * exp2f(r1.z - m_new);
        l_new += r2.y * exp2f(r2.x - m_new) + r2.w * exp2f(r2.z - m_new);
        l_new += r3.y * exp2f(r3.x - m_new) + r3.w * exp2f(r3.z - m_new);
        fac_p[tt] = exp2f(mx4[tt] - m_new);
        if (m_new != m_run[tt]) changed = true;
        if (w == 0 && lg == 0) {
          fin_fac[row] = exp2f(m_run[tt] - m_new);
          if (st == 7) fin_invl[row] = 1.0f / l_new;
        }
        m_run[tt] = m_new;
        l_run[tt] = l_new;
      }
      if (w == 0 && changed) flagv[st & 1] = 1.0f;
    }
    // ---- P-write sh0: packed b64, swizzled [t][s-local] ----
#pragma unroll
    for (int tt = 0; tt < 4; ++tt) {
      const f32x4 pe = sacc[0][tt];
      const float fp = fac_p[tt];
      ushort4 pk = make_ushort4(f2h(pe[0] * fp), f2h(pe[1] * fp),
                                f2h(pe[2] * fp), f2h(pe[3] * fp));
      *(ushort4*)(pPw + tt * 4096) = pk;
    }
    BARSYNC();  // [B] — Ps(sh0) + fin stable

    // ---- rescale (uniform skip via defer-max flag) ----
    {
      const float fl = flagv[st & 1];
      if (fl != 0.f) {
#pragma unroll
        for (int mt = 0; mt < 4; ++mt) {
          const f32x4 fac = *(const f32x4*)&fin_fac[mt * 16 + lg * 4];
#pragma unroll
          for (int ch = 0; ch < 2; ++ch)
#pragma unroll
            for (int nt = 0; nt < 2; ++nt) {
              pvm[mt][ch][nt] *= fac;
              pvs[mt][ch][nt] *= fac;
            }
        }
      }
      if (tid == 0) flagv[(st + 1) & 1] = 0.f;
    }

    // ---- PV: 2 halves x 8 phases; P-frags held across ch ----
#pragma unroll
    for (int half = 0; half < 2; ++half) {
      if (half == 1) {
        BARSYNC();  // [C] — half0 done reading Ps
#pragma unroll
        for (int tt = 0; tt < 4; ++tt) {
          const f32x4 pe = sacc[1][tt];
          const float fp = fac_p[tt];
          ushort4 pk = make_ushort4(f2h(pe[0] * fp), f2h(pe[1] * fp),
                                    f2h(pe[2] * fp), f2h(pe[3] * fp));
          *(ushort4*)(pPw + tt * 4096) = pk;
        }
        BARSYNC();  // [D] — Ps(sh1) stable
      }
      f16x8 pf0, pf1, pf2, pf3;
#pragma unroll
      for (int pp = 0; pp < 8; ++pp) {
        const int P_ = half * 8 + pp;
        asm volatile("s_waitcnt vmcnt(2)" ::: "memory");
        const int bf = P_ & 1;
        const int ch = pp & 1, ksl = pp >> 1;
        if (ch == 0) {
          pf0 = readPa(0, ksl);
          pf1 = readPa(1, ksl);
          pf2 = readPa(2, ksl);
          pf3 = readPa(3, ksl);
        }
        f16x8 h0 = readH(bf, 0), h1 = readH(bf, 1);
        f16x8 q0 = h0 * h0, q1 = h1 * h1;
        __builtin_amdgcn_s_setprio(1);
        pvm[0][ch][0] = mfma16(pf0, h0, pvm[0][ch][0]);
        pvm[1][ch][0] = mfma16(pf1, h0, pvm[1][ch][0]);
        pvm[2][ch][0] = mfma16(pf2, h0, pvm[2][ch][0]);
        pvm[3][ch][0] = mfma16(pf3, h0, pvm[3][ch][0]);
        pvs[0][ch][0] = mfma16(pf0, q0, pvs[0][ch][0]);
        pvs[1][ch][0] = mfma16(pf1, q0, pvs[1][ch][0]);
        pvs[2][ch][0] = mfma16(pf2, q0, pvs[2][ch][0]);
        pvs[3][ch][0] = mfma16(pf3, q0, pvs[3][ch][0]);
        pvm[0][ch][1] = mfma16(pf0, h1, pvm[0][ch][1]);
        pvm[1][ch][1] = mfma16(pf1, h1, pvm[1][ch][1]);
        pvm[2][ch][1] = mfma16(pf2, h1, pvm[2][ch][1]);
        pvm[3][ch][1] = mfma16(pf3, h1, pvm[3][ch][1]);
        pvs[0][ch][1] = mfma16(pf0, q1, pvs[0][ch][1]);
        pvs[1][ch][1] = mfma16(pf1, q1, pvs[1][ch][1]);
        pvs[2][ch][1] = mfma16(pf2, q1, pvs[2][ch][1]);
        pvs[3][ch][1] = mfma16(pf3, q1, pvs[3][ch][1]);
        __builtin_amdgcn_s_setprio(0);
        const int pn = P_ + 2;
        if (pn < 16) stageH2(pn, bf);
        else stageGn(pn - 16, bf, dnext);  // next tile G chunks (0,0),(0,1)
      }
    }
  }
  asm volatile("s_waitcnt vmcnt(0)" ::: "memory");

  // ---- epilogue: out[b][c][t] = std * (content - cm)*cr + mean ----
  f32x4 invq[4];
#pragma unroll
  for (int mt = 0; mt < 4; ++mt)
    invq[mt] = *(const f32x4*)&fin_invl[mt * 16 + lg * 4];
#pragma unroll
  for (int ch = 0; ch < 2; ++ch)
#pragma unroll
    for (int nt = 0; nt < 2; ++nt) {
      const int c = ch * 256 + w * 32 + nt * 16 + l15;
      const size_t row = (size_t)b * C_ + c;
      const float cm = cmean[row];
      const float cr = crstd[row];
      const float* cp = content + row * TC + t0;
      float* op = out + row * TC + t0;
#pragma unroll
      for (int mt = 0; mt < 4; ++mt) {
        const int q0 = mt * 16 + lg * 4;
        const float4 x = *(const float4*)(cp + q0);
        const f32x4 mu = pvm[mt][ch][nt] * invq[mt];
        const f32x4 se = pvs[mt][ch][nt] * invq[mt];
        float4 y;
        y.x = sqrtf(fmaxf(se[0] - mu[0] * mu[0], 0.f)) * ((x.x - cm) * cr) + mu[0];
        y.y = sqrtf(fmaxf(se[1] - mu[1] * mu[1], 0.f)) * ((x.y - cm) * cr) + mu[1];
        y.z = sqrtf(fmaxf(se[2] - mu[2] * mu[2], 0.f)) * ((x.z - cm) * cr) + mu[2];
        y.w = sqrtf(fmaxf(se[3] - mu[3] * mu[3], 0.f)) * ((x.w - cm) * cr) + mu[3];
        *(float4*)(op + q0) = y;
      }
    }
}

extern "C" void kernel_launch(void* const* d_in, const int* in_sizes, int n_in,
                              void* d_out, int out_size, void* d_ws, size_t ws_size,
                              hipStream_t stream) {
  (void)in_sizes;
  (void)n_in;
  (void)out_size;
  (void)ws_size;  // needs ~96 MB
  const float* content = (const float*)d_in[0];
  const float* style = (const float*)d_in[1];
  const float* content_key = (const float*)d_in[2];
  const float* style_key = (const float*)d_in[3];
  const float* Wf = (const float*)d_in[4];
  const float* bf = (const float*)d_in[5];
  const float* Wg = (const float*)d_in[6];
  const float* bg = (const float*)d_in[7];
  const float* Wh = (const float*)d_in[8];
  const float* bh = (const float*)d_in[9];
  float* out = (float*)d_out;

  char* ws = (char*)d_ws;
  u16* Ft = (u16*)(ws);
  u16* Gt = (u16*)(ws + 67108864);
  u16* Hm = (u16*)(ws + 83886080);
  float* cmean = (float*)(ws + 100663296);
  float* crstd = (float*)(ws + 100663296 + 16384);

  k_content_stats<<<dim3(B_ * C_), dim3(256), 0, stream>>>(content, cmean, crstd);
  k_conv<false><<<dim3(TC / 64, 2, B_), dim3(256), 0, stream>>>(content_key, Wf, bf, Ft, TC);
  k_conv<false><<<dim3(TS / 64, 2, B_), dim3(256), 0, stream>>>(style_key, Wg, bg, Gt, TS);
  k_conv<true><<<dim3(TS / 64, 2, B_), dim3(256), 0, stream>>>(style, Wh, bh, Hm, TS);

  k_attn<<<dim3(1024), dim3(512), 0, stream>>>(Ft, Gt, Hm, content, cmean, crstd, out);
}

// Round 8
// 731.810 us; speedup vs baseline: 2.1917x; 1.0534x over previous
//
#include <hip/hip_runtime.h>
#include <hip/hip_fp16.h>

// AdaAttN fused pipeline, fp16 MFMA path, single-pass flash attention.
// B=8, C=512, Tc=8192, Ts=2048.
//
// Algebraic fusion: score = F.G = (Wf ck + bf).(Wg sk + bg)
//   = ck . G' + beta,  G' = conv(Wfg, sk) + b',  Wfg = Wf^T Wg,
//   b' = Wf^T bg, beta[s] = (Wg^T bf).sk[:,s] + bf.bg
// -> no Ft tensor, content_key staged directly as the QK B-operand.
//
// ws layout (bytes):
//   Wfg  [512][512] f32 :         0 .. 1,048,576
//   wbeta[512] f32      : 1,048,576
//   bprime[512] f32     : 1,052,672  (offset 1,048,576+4096)
//   c0   [1] f32        : 1,056,768
//   beta [8][2048] f32  : 1,060,864 .. 1,126,400
//   Gt(G')[8][2048][512] fp16 : 67,108,864 .. 83,886,080
//   H   [8][512][2048] fp16   : 83,886,080 .. 100,663,296
//   cmean [4096] f32          : 100,663,296
//   crstd [4096] f32          : 100,679,680

#define B_ 8
#define C_ 512
#define TC 8192
#define TS 2048

typedef unsigned short u16;
typedef __attribute__((ext_vector_type(8))) _Float16 f16x8;
typedef __attribute__((ext_vector_type(4))) float f32x4;

__device__ __forceinline__ u16 f2h(float f) {
  return __half_as_ushort(__float2half(f));
}

__device__ __forceinline__ f32x4 mfma16(f16x8 a, f16x8 b, f32x4 c) {
  return __builtin_amdgcn_mfma_f32_16x16x32_f16(a, b, c, 0, 0, 0);
}

// async global->LDS, 16B per lane; LDS dest = wave-uniform base + lane*16
__device__ __forceinline__ void stage16(const u16* g, u16* l) {
  __builtin_amdgcn_global_load_lds(
      (__attribute__((address_space(1))) void*)(const void*)g,
      (__attribute__((address_space(3))) void*)l, 16, 0, 0);
}

// raw barrier: flush LDS ops, no vmcnt drain (keeps staging loads in flight)
#define BARSYNC()                                         \
  do {                                                    \
    asm volatile("s_waitcnt lgkmcnt(0)" ::: "memory");    \
    __builtin_amdgcn_s_barrier();                         \
    __builtin_amdgcn_sched_barrier(0);                    \
  } while (0)

// ---------------- K0: per-(b,c) content stats (ddof=1) ----------------
__global__ __launch_bounds__(256) void k_content_stats(
    const float* __restrict__ x, float* __restrict__ cmean, float* __restrict__ crstd) {
  const int row = blockIdx.x;  // b*512 + c
  const float4* p = (const float4*)(x + (size_t)row * TC);
  float s = 0.f, ss = 0.f;
  for (int i = threadIdx.x; i < TC / 4; i += 256) {
    float4 v = p[i];
    s += v.x + v.y + v.z + v.w;
    ss += v.x * v.x + v.y * v.y + v.z * v.z + v.w * v.w;
  }
#pragma unroll
  for (int d = 1; d < 64; d <<= 1) {
    s += __shfl_xor(s, d);
    ss += __shfl_xor(ss, d);
  }
  __shared__ float rs[4], rss[4];
  if ((threadIdx.x & 63) == 0) {
    rs[threadIdx.x >> 6] = s;
    rss[threadIdx.x >> 6] = ss;
  }
  __syncthreads();
  if (threadIdx.x == 0) {
    float S = rs[0] + rs[1] + rs[2] + rs[3];
    float SS = rss[0] + rss[1] + rss[2] + rss[3];
    float mean = S / (float)TC;
    float var = (SS - S * mean) / (float)(TC - 1);
    cmean[row] = mean;
    crstd[row] = rsqrtf(var + 1e-5f);
  }
}

// ---------------- K-WFG: Wfg[i][j] = sum_o Wf[o][i] * Wg[o][j]  (fp32 out) ----
__global__ __launch_bounds__(256) void k_wfg(
    const float* __restrict__ Wf, const float* __restrict__ Wg,
    float* __restrict__ Wfg) {
  const int i0 = blockIdx.x * 64;
  const int j0 = blockIdx.y * 256;
  const int tid = threadIdx.x;
  const int w = tid >> 6, ln = tid & 63, lg = ln >> 4, l15 = ln & 15;
  __shared__ u16 As[64][72];
  __shared__ u16 Bs[256][72];
  const f32x4 vzero = {0.f, 0.f, 0.f, 0.f};
  f32x4 acc[4][4];
#pragma unroll
  for (int i = 0; i < 4; ++i)
#pragma unroll
    for (int j = 0; j < 4; ++j) acc[i][j] = vzero;

  for (int o0 = 0; o0 < 512; o0 += 64) {
    __syncthreads();
    {  // A: Wf[o0..+64][i0..+64] -> As[i][o]  (4x4 reg transpose)
      const int iq = tid & 15, oq = tid >> 4;
      const float* src = Wf + (size_t)(o0 + oq * 4) * 512 + i0 + iq * 4;
      float4 r0 = *(const float4*)(src);
      float4 r1 = *(const float4*)(src + 512);
      float4 r2 = *(const float4*)(src + 1024);
      float4 r3 = *(const float4*)(src + 1536);
      *(ushort4*)&As[iq * 4 + 0][oq * 4] = make_ushort4(f2h(r0.x), f2h(r1.x), f2h(r2.x), f2h(r3.x));
      *(ushort4*)&As[iq * 4 + 1][oq * 4] = make_ushort4(f2h(r0.y), f2h(r1.y), f2h(r2.y), f2h(r3.y));
      *(ushort4*)&As[iq * 4 + 2][oq * 4] = make_ushort4(f2h(r0.z), f2h(r1.z), f2h(r2.z), f2h(r3.z));
      *(ushort4*)&As[iq * 4 + 3][oq * 4] = make_ushort4(f2h(r0.w), f2h(r1.w), f2h(r2.w), f2h(r3.w));
    }
    {  // B: Wg[o0..+64][j0..+256] -> Bs[j][o]  (4 tiles per thread)
      const int jq = tid & 63, og = tid >> 6;
#pragma unroll
      for (int ii = 0; ii < 4; ++ii) {
        const int oq = og * 4 + ii;
        const float* src = Wg + (size_t)(o0 + oq * 4) * 512 + j0 + jq * 4;
        float4 r0 = *(const float4*)(src);
        float4 r1 = *(const float4*)(src + 512);
        float4 r2 = *(const float4*)(src + 1024);
        float4 r3 = *(const float4*)(src + 1536);
        *(ushort4*)&Bs[jq * 4 + 0][oq * 4] = make_ushort4(f2h(r0.x), f2h(r1.x), f2h(r2.x), f2h(r3.x));
        *(ushort4*)&Bs[jq * 4 + 1][oq * 4] = make_ushort4(f2h(r0.y), f2h(r1.y), f2h(r2.y), f2h(r3.y));
        *(ushort4*)&Bs[jq * 4 + 2][oq * 4] = make_ushort4(f2h(r0.z), f2h(r1.z), f2h(r2.z), f2h(r3.z));
        *(ushort4*)&Bs[jq * 4 + 3][oq * 4] = make_ushort4(f2h(r0.w), f2h(r1.w), f2h(r2.w), f2h(r3.w));
      }
    }
    __syncthreads();
#pragma unroll
    for (int ks = 0; ks < 2; ++ks) {
      f16x8 a[4], bb[4];
#pragma unroll
      for (int mt = 0; mt < 4; ++mt)
        a[mt] = *(const f16x8*)&As[mt * 16 + l15][ks * 32 + lg * 8];
#pragma unroll
      for (int nt = 0; nt < 4; ++nt)
        bb[nt] = *(const f16x8*)&Bs[w * 64 + nt * 16 + l15][ks * 32 + lg * 8];
#pragma unroll
      for (int mt = 0; mt < 4; ++mt)
#pragma unroll
        for (int nt = 0; nt < 4; ++nt)
          acc[mt][nt] = mfma16(a[mt], bb[nt], acc[mt][nt]);
    }
  }
#pragma unroll
  for (int nt = 0; nt < 4; ++nt) {
    const int n = j0 + w * 64 + nt * 16 + l15;
#pragma unroll
    for (int mt = 0; mt < 4; ++mt) {
      const int mb = i0 + mt * 16 + lg * 4;
      f32x4 v = acc[mt][nt];
      float* yp = Wfg + (size_t)mb * 512 + n;
      yp[0 * 512] = v[0];
      yp[1 * 512] = v[1];
      yp[2 * 512] = v[2];
      yp[3 * 512] = v[3];
    }
  }
}

// ---------------- K-WBETA: wb = Wg^T bf, bp = Wf^T bg, c0 = bf.bg ----------------
__global__ __launch_bounds__(512) void k_wbeta(
    const float* __restrict__ Wf, const float* __restrict__ Wg,
    const float* __restrict__ bfv, const float* __restrict__ bgv,
    float* __restrict__ wb, float* __restrict__ bp, float* __restrict__ c0) {
  const int j = threadIdx.x;
  float a = 0.f, b2 = 0.f;
  for (int o = 0; o < 512; ++o) {
    a += bfv[o] * Wg[(size_t)o * 512 + j];
    b2 += bgv[o] * Wf[(size_t)o * 512 + j];
  }
  wb[j] = a;
  bp[j] = b2;
  if (j == 0) {
    float c = 0.f;
    for (int o = 0; o < 512; ++o) c += bfv[o] * bgv[o];
    *c0 = c;
  }
}

// ---------------- K-BETA: beta[b][s] = sum_j wb[j]*sk[b][j][s] + c0 ----------------
__global__ __launch_bounds__(256) void k_beta(
    const float* __restrict__ sk, const float* __restrict__ wb,
    const float* __restrict__ c0, float* __restrict__ beta) {
  const int b = blockIdx.y;
  const int s = blockIdx.x * 256 + threadIdx.x;
  const float* p = sk + (size_t)b * 512 * TS + s;
  float acc = *c0;
  for (int j = 0; j < 512; ++j) acc += wb[j] * p[(size_t)j * TS];
  beta[b * TS + s] = acc;
}

// ---------------- conv1x1 GEMM (round-7, verified) ----------------
template <bool TRANS_OUT>
__global__ __launch_bounds__(256, 3) void k_conv(
    const float* __restrict__ X, const float* __restrict__ W,
    const float* __restrict__ bias, u16* __restrict__ Y, int M) {
  const int b = blockIdx.z;
  const int m0 = blockIdx.x * 64;
  const int n0 = blockIdx.y * 256;
  const int tid = threadIdx.x;
  const int w = tid >> 6, ln = tid & 63, lg = ln >> 4, l15 = ln & 15;
  __shared__ u16 As[64][72];
  __shared__ u16 Bs[256][72];
  const float* Xb = X + (size_t)b * C_ * M;
  const f32x4 vzero = {0.f, 0.f, 0.f, 0.f};
  f32x4 acc[4][4];
#pragma unroll
  for (int i = 0; i < 4; ++i)
#pragma unroll
    for (int j = 0; j < 4; ++j) acc[i][j] = vzero;

  const int mq = tid & 15, kq = tid >> 4;  // m-quad (coalesced), k-quad
  for (int k0 = 0; k0 < 512; k0 += 64) {
    __syncthreads();
    {  // stage A: X[k0..+64][m0..+64] -> As[m][k], 4x4 reg transpose
      const float* src = Xb + (size_t)(k0 + kq * 4) * M + m0 + mq * 4;
      float4 r0 = *(const float4*)(src);
      float4 r1 = *(const float4*)(src + M);
      float4 r2 = *(const float4*)(src + 2 * M);
      float4 r3 = *(const float4*)(src + 3 * M);
      *(ushort4*)&As[mq * 4 + 0][kq * 4] =
          make_ushort4(f2h(r0.x), f2h(r1.x), f2h(r2.x), f2h(r3.x));
      *(ushort4*)&As[mq * 4 + 1][kq * 4] =
          make_ushort4(f2h(r0.y), f2h(r1.y), f2h(r2.y), f2h(r3.y));
      *(ushort4*)&As[mq * 4 + 2][kq * 4] =
          make_ushort4(f2h(r0.z), f2h(r1.z), f2h(r2.z), f2h(r3.z));
      *(ushort4*)&As[mq * 4 + 3][kq * 4] =
          make_ushort4(f2h(r0.w), f2h(r1.w), f2h(r2.w), f2h(r3.w));
    }
    {  // stage B
      const float* src = W + (size_t)(n0 + tid) * 512 + k0;
#pragma unroll
      for (int i = 0; i < 16; ++i) {
        float4 v = *(const float4*)(src + i * 4);
        ushort4 hq = make_ushort4(f2h(v.x), f2h(v.y), f2h(v.z), f2h(v.w));
        *(ushort4*)&Bs[tid][i * 4] = hq;
      }
    }
    __syncthreads();
#pragma unroll
    for (int ks = 0; ks < 2; ++ks) {
      f16x8 a[4], bb[4];
#pragma unroll
      for (int mt = 0; mt < 4; ++mt)
        a[mt] = *(const f16x8*)&As[mt * 16 + l15][ks * 32 + lg * 8];
#pragma unroll
      for (int nt = 0; nt < 4; ++nt)
        bb[nt] = *(const f16x8*)&Bs[w * 64 + nt * 16 + l15][ks * 32 + lg * 8];
#pragma unroll
      for (int mt = 0; mt < 4; ++mt)
#pragma unroll
        for (int nt = 0; nt < 4; ++nt)
          acc[mt][nt] = mfma16(a[mt], bb[nt], acc[mt][nt]);
    }
  }
#pragma unroll
  for (int nt = 0; nt < 4; ++nt) {
    const int n = n0 + w * 64 + nt * 16 + l15;
    const float bv = bias[n];
#pragma unroll
    for (int mt = 0; mt < 4; ++mt) {
      const int mb = m0 + mt * 16 + lg * 4;
      f32x4 v = acc[mt][nt];
      if (!TRANS_OUT) {
        u16* yp = Y + (size_t)b * M * 512 + (size_t)mb * 512 + n;
        yp[0 * 512] = f2h(v[0] + bv);
        yp[1 * 512] = f2h(v[1] + bv);
        yp[2 * 512] = f2h(v[2] + bv);
        yp[3 * 512] = f2h(v[3] + bv);
      } else {
        ushort4 hq = make_ushort4(f2h(v[0] + bv), f2h(v[1] + bv),
                                  f2h(v[2] + bv), f2h(v[3] + bv));
        *(ushort4*)(Y + (size_t)b * 512 * M + (size_t)n * M + mb) = hq;
      }
    }
  }
}

// ---------------- K5: flash attention, Wf folded into G' ----------------
// score[t][s] = sum_i G'[s][i] ckT[t][i] + beta[s]; ckT staged from content_key
// (fp32, 4x4 reg transpose) into the same swizzled layout readF uses.
__global__ __launch_bounds__(512, 2) void k_attn(
    const float* __restrict__ ck, const u16* __restrict__ Gt,
    const u16* __restrict__ Hm, const float* __restrict__ betap,
    const float* __restrict__ content, const float* __restrict__ cmean,
    const float* __restrict__ crstd, float* __restrict__ out) {
  __shared__ u16 Fq[64 * 512];     // ckT: byte = t*1024 + sw*16, sw=(g&56)|((g^t)&7)
  __shared__ u16 UG[2][128 * 64];  // G' chunk [128 s][64 i]
  __shared__ u16 UH[2][256 * 32];  // H chunk [256 c][32 s]
  __shared__ u16 Ps[64 * 128];     // [t][s-local]
  __shared__ float red[64][20];    // [t-row][wave*2]: (max2, sum), stride 80B
  __shared__ float fin_fac[64];
  __shared__ float fin_invl[64];
  __shared__ float flagv[2];

  const int bid = blockIdx.x;
  const int swz = (bid & 7) * 128 + (bid >> 3);  // XCD-contiguous (1024%8==0)
  const int b = swz >> 7;
  const int t0 = (swz & 127) * 64;
  const int tid = threadIdx.x;
  const int w = tid >> 6, ln = tid & 63, lg = ln >> 4, l15 = ln & 15;

  const u16* Gtb = Gt + (size_t)b * TS * C_;
  const u16* Hb = Hm + (size_t)b * C_ * TS;

  // ---- ckT stage: content_key[b][j][t0..+64] fp32 -> Fq[t][j] fp16 swizzled ----
  {
    const int tq = tid & 15;         // t-quad
    const int jq0 = (tid >> 4) * 4;  // j-quad base (0..124)
    const float* ckb = ck + (size_t)b * C_ * TC + t0;
#pragma unroll
    for (int i = 0; i < 4; ++i) {
      const int jq = jq0 + i;
      const float* src = ckb + (size_t)(jq * 4) * TC + tq * 4;
      float4 r0 = *(const float4*)(src);
      float4 r1 = *(const float4*)(src + TC);
      float4 r2 = *(const float4*)(src + 2 * TC);
      float4 r3 = *(const float4*)(src + 3 * TC);
      const int g = jq >> 1, half = (jq & 1) * 8;
      const float* q0 = (const float*)&r0;
      const float* q1 = (const float*)&r1;
      const float* q2 = (const float*)&r2;
      const float* q3 = (const float*)&r3;
#pragma unroll
      for (int dt = 0; dt < 4; ++dt) {
        const int t = tq * 4 + dt;
        const int sw = (g & 56) | ((g ^ t) & 7);
        ushort4 pk = make_ushort4(f2h(q0[dt]), f2h(q1[dt]), f2h(q2[dt]), f2h(q3[dt]));
        *(ushort4*)((char*)Fq + t * 1024 + sw * 16 + half) = pk;
      }
    }
  }
  if (tid < 2) flagv[tid] = 0.f;
  __syncthreads();  // full drain once; ledger starts clean

  // ---- per-lane swizzle base pointers (all reads = base + const imm) ----
  const int cF = lg ^ (l15 & 7);
  const char* pF0 = (const char*)Fq + l15 * 1024 + cF * 16;
  const char* pF1 = (const char*)Fq + l15 * 1024 + (cF ^ 4) * 16;
  const char* pG0 = (const char*)UG + (w * 16 + l15) * 128 + cF * 16;
  const char* pG1 = (const char*)UG + (w * 16 + l15) * 128 + (cF ^ 4) * 16;
  const int cH = lg ^ (l15 & 3) ^ ((l15 >> 2) & 3);
  const char* pH = (const char*)UH + (w * 32 + l15) * 64 + cH * 16;
  const char* pP0 = (const char*)Ps + l15 * 256 + cF * 16;
  const char* pP1 = (const char*)Ps + l15 * 256 + (cF ^ 4) * 16;
  const int cW = ((((w & 3) << 1) | (lg >> 1)) ^ (l15 & 7));
  char* pPw = (char*)Ps + l15 * 256 + (w & 4) * 32 + cW * 16 + (lg & 1) * 8;

  auto readF = [&](int tt, int kc_, int ks) -> f16x8 {
    return *(const f16x8*)((ks ? pF1 : pF0) + tt * 16384 + kc_ * 128);
  };
  auto readG = [&](int bf, int ks) -> f16x8 {
    return *(const f16x8*)((ks ? pG1 : pG0) + bf * 16384);
  };
  auto readH = [&](int bf, int nt) -> f16x8 {
    return *(const f16x8*)(pH + bf * 16384 + nt * 1024);
  };
  auto readPa = [&](int mt, int ksl) -> f16x8 {
    return *(const f16x8*)(((ksl & 1) ? pP1 : pP0) + mt * 4096 + (ksl & 2) * 64);
  };

  // ---- loop-carried staging source pointers (u16 units) ----
  const int gl = (ln & 7) ^ ((ln >> 3) & 7);
  const u16* sG[2][2];
#pragma unroll
  for (int sh = 0; sh < 2; ++sh)
#pragma unroll
    for (int i = 0; i < 2; ++i)
      sG[sh][i] = Gtb + (size_t)(sh * 128 + w * 16 + i * 8 + (ln >> 3)) * 512 + gl * 8;
  const int hl = (ln & 3) ^ ((ln >> 2) & 3) ^ ((ln >> 4) & 3);
  const u16* sH[2][2];
#pragma unroll
  for (int ch = 0; ch < 2; ++ch)
#pragma unroll
    for (int i = 0; i < 2; ++i)
      sH[ch][i] = Hb + (size_t)(ch * 256 + w * 32 + i * 16 + (ln >> 2)) * 2048 + hl * 8;

  auto stageG2 = [&](int kc_, int sh, int bf) {
    stage16(sG[sh][0] + kc_ * 64, (u16*)((char*)UG + bf * 16384 + (w * 16 + 0) * 128));
    stage16(sG[sh][1] + kc_ * 64, (u16*)((char*)UG + bf * 16384 + (w * 16 + 8) * 128));
  };
  auto stageH2 = [&](int hc, int bf) {
    const int ch = hc & 1, kslg = hc >> 1;
    stage16(sH[ch][0] + kslg * 32, (u16*)((char*)UH + bf * 16384 + (w * 32 + 0) * 64));
    stage16(sH[ch][1] + kslg * 32, (u16*)((char*)UH + bf * 16384 + (w * 32 + 16) * 64));
  };
  auto stageGn = [&](int sh, int bf, int dnext) {  // next tile, chunk (kc=0, sh)
    stage16(sG[sh][0] + dnext, (u16*)((char*)UG + bf * 16384 + (w * 16 + 0) * 128));
    stage16(sG[sh][1] + dnext, (u16*)((char*)UG + bf * 16384 + (w * 16 + 8) * 128));
  };

  // prologue stages: tile 0, G chunks (0,0)->buf0, (0,1)->buf1
  stageG2(0, 0, 0);
  stageG2(0, 1, 1);

  const f32x4 vzero = {0.f, 0.f, 0.f, 0.f};
  f32x4 pvm[4][2][2], pvs[4][2][2];
#pragma unroll
  for (int mt = 0; mt < 4; ++mt)
#pragma unroll
    for (int ch = 0; ch < 2; ++ch)
#pragma unroll
      for (int nt = 0; nt < 2; ++nt) {
        pvm[mt][ch][nt] = vzero;
        pvs[mt][ch][nt] = vzero;
      }
  // per-lane online state for its 4 t-rows (tt*16 + l15), base-2 units
  float m_run[4] = {-1e30f, -1e30f, -1e30f, -1e30f};
  float l_run[4] = {0.f, 0.f, 0.f, 0.f};
  const float LOG2E = 1.44269504f;
  const float* betab = betap + b * TS + w * 16 + lg * 4;

  for (int st = 0; st < 8; ++st) {
    if (st > 0) {
#pragma unroll
      for (int sh = 0; sh < 2; ++sh)
#pragma unroll
        for (int i = 0; i < 2; ++i) {
          sG[sh][i] += 131072;  // +256 s-rows
          sH[sh][i] += 256;     // +512 B along s
        }
    }
    const int dnext = (st == 7) ? -917504 : 131072;
    f32x4 sacc[2][4];  // [sh][tt]
#pragma unroll
    for (int sh = 0; sh < 2; ++sh)
#pragma unroll
      for (int tt = 0; tt < 4; ++tt) sacc[sh][tt] = vzero;

    // ---- QK: 16 phases (kc x sh); F-frags read at sh==0, reused at sh==1 ----
#pragma unroll
    for (int kc = 0; kc < 8; ++kc) {
      f16x8 fA[2][4];
#pragma unroll
      for (int sh = 0; sh < 2; ++sh) {
        const int q = kc * 2 + sh;
        asm volatile("s_waitcnt vmcnt(2)" ::: "memory");
        const int bf = q & 1;
        if (sh == 0) {
#pragma unroll
          for (int ks = 0; ks < 2; ++ks)
#pragma unroll
            for (int tt = 0; tt < 4; ++tt) fA[ks][tt] = readF(tt, kc, ks);
        }
        __builtin_amdgcn_s_setprio(1);
#pragma unroll
        for (int ks = 0; ks < 2; ++ks) {
          f16x8 gv = readG(bf, ks);
          sacc[sh][0] = mfma16(gv, fA[ks][0], sacc[sh][0]);
          sacc[sh][1] = mfma16(gv, fA[ks][1], sacc[sh][1]);
          sacc[sh][2] = mfma16(gv, fA[ks][2], sacc[sh][2]);
          sacc[sh][3] = mfma16(gv, fA[ks][3], sacc[sh][3]);
        }
        __builtin_amdgcn_s_setprio(0);
        const int qn = q + 2;
        if (qn < 16) stageG2(qn >> 1, qn & 1, bf);
        else stageH2(qn - 16, bf);  // qn=16,17 -> H chunks 0,1
      }
    }

    // ---- beta add: rows = s; same for all tt ----
    {
      const float4 be0 = *(const float4*)(betab + st * 256);
      const float4 be1 = *(const float4*)(betab + st * 256 + 128);
      f32x4 bv0 = {be0.x, be0.y, be0.z, be0.w};
      f32x4 bv1 = {be1.x, be1.y, be1.z, be1.w};
#pragma unroll
      for (int tt = 0; tt < 4; ++tt) {
        sacc[0][tt] += bv0;
        sacc[1][tt] += bv1;
      }
    }

    // ---- per-wave partial stats over this wave's 32 s (2 sh x 4 rg + lg) ----
    float mx4[4];
#pragma unroll
    for (int tt = 0; tt < 4; ++tt) {
      f32x4 v0 = sacc[0][tt] * LOG2E;
      f32x4 v1 = sacc[1][tt] * LOG2E;
      float mx = fmaxf(fmaxf(fmaxf(v0[0], v0[1]), fmaxf(v0[2], v0[3])),
                       fmaxf(fmaxf(v1[0], v1[1]), fmaxf(v1[2], v1[3])));
      mx = fmaxf(mx, __shfl_xor(mx, 16));
      mx = fmaxf(mx, __shfl_xor(mx, 32));
      f32x4 p0, p1;
#pragma unroll
      for (int rg = 0; rg < 4; ++rg) {
        p0[rg] = exp2f(v0[rg] - mx);
        p1[rg] = exp2f(v1[rg] - mx);
      }
      float sm = p0[0] + p0[1] + p0[2] + p0[3] + p1[0] + p1[1] + p1[2] + p1[3];
      sm += __shfl_xor(sm, 16);
      sm += __shfl_xor(sm, 32);
      sacc[0][tt] = p0;
      sacc[1][tt] = p1;
      mx4[tt] = mx;
      if (lg == 0)
        *(float2*)&red[tt * 16 + l15][w * 2] = make_float2(mx, sm);
    }
    BARSYNC();  // [A]

    // ---- per-lane redundant merge for rows t = tt*16 + l15 ----
    float fac_p[4];
    {
      bool changed = false;
#pragma unroll
      for (int tt = 0; tt < 4; ++tt) {
        const int row = tt * 16 + l15;
        float4 r0 = *(const float4*)&red[row][0];
        float4 r1 = *(const float4*)&red[row][4];
        float4 r2 = *(const float4*)&red[row][8];
        float4 r3 = *(const float4*)&red[row][12];
        float mc = fmaxf(m_run[tt],
                   fmaxf(fmaxf(fmaxf(r0.x, r0.z), fmaxf(r1.x, r1.z)),
                         fmaxf(fmaxf(r2.x, r2.z), fmaxf(r3.x, r3.z))));
        const float m_new = (mc - m_run[tt] <= 11.0f) ? m_run[tt] : mc;
        float l_new = l_run[tt] * exp2f(m_run[tt] - m_new);
        l_new += r0.y * exp2f(r0.x - m_new) + r0.w * exp2f(r0.z - m_new);
        l_new += r1.y * exp2f(r1.x - m_new) + r1.w * exp2f(r1.z - m_new);
        l_new += r2.y * exp2f(r2.x - m_new) + r2.w * exp2f(r2.z - m_new);
        l_new += r3.y * exp2f(r3.x - m_new) + r3.w * exp2f(r3.z - m_new);
        fac_p[tt] = exp2f(mx4[tt] - m_new);
        if (m_new != m_run[tt]) changed = true;
        if (w == 0 && lg == 0) {
          fin_fac[row] = exp2f(m_run[tt] - m_new);
          if (st == 7) fin_invl[row] = 1.0f / l_new;
        }
        m_run[tt] = m_new;
        l_run[tt] = l_new;
      }
      if (w == 0 && changed) flagv[st & 1] = 1.0f;
    }
    // ---- P-write sh0: packed b64, swizzled [t][s-local] ----
#pragma unroll
    for (int tt = 0; tt < 4; ++tt) {
      const f32x4 pe = sacc[0][tt];
      const float fp = fac_p[tt];
      ushort4 pk = make_ushort4(f2h(pe[0] * fp), f2h(pe[1] * fp),
                                f2h(pe[2] * fp), f2h(pe[3] * fp));
      *(ushort4*)(pPw + tt * 4096) = pk;
    }
    BARSYNC();  // [B] — Ps(sh0) + fin stable

    // ---- rescale (uniform skip via defer-max flag) ----
    {
      const float fl = flagv[st & 1];
      if (fl != 0.f) {
#pragma unroll
        for (int mt = 0; mt < 4; ++mt) {
          const f32x4 fac = *(const f32x4*)&fin_fac[mt * 16 + lg * 4];
#pragma unroll
          for (int ch = 0; ch < 2; ++ch)
#pragma unroll
            for (int nt = 0; nt < 2; ++nt) {
              pvm[mt][ch][nt] *= fac;
              pvs[mt][ch][nt] *= fac;
            }
        }
      }
      if (tid == 0) flagv[(st + 1) & 1] = 0.f;
    }

    // ---- PV: 2 halves x 8 phases; P-frags held across ch ----
#pragma unroll
    for (int half = 0; half < 2; ++half) {
      if (half == 1) {
        BARSYNC();  // [C] — half0 done reading Ps
#pragma unroll
        for (int tt = 0; tt < 4; ++tt) {
          const f32x4 pe = sacc[1][tt];
          const float fp = fac_p[tt];
          ushort4 pk = make_ushort4(f2h(pe[0] * fp), f2h(pe[1] * fp),
                                    f2h(pe[2] * fp), f2h(pe[3] * fp));
          *(ushort4*)(pPw + tt * 4096) = pk;
        }
        BARSYNC();  // [D] — Ps(sh1) stable
      }
      f16x8 pf0, pf1, pf2, pf3;
#pragma unroll
      for (int pp = 0; pp < 8; ++pp) {
        const int P_ = half * 8 + pp;
        asm volatile("s_waitcnt vmcnt(2)" ::: "memory");
        const int bf = P_ & 1;
        const int ch = pp & 1, ksl = pp >> 1;
        if (ch == 0) {
          pf0 = readPa(0, ksl);
          pf1 = readPa(1, ksl);
          pf2 = readPa(2, ksl);
          pf3 = readPa(3, ksl);
        }
        f16x8 h0 = readH(bf, 0), h1 = readH(bf, 1);
        f16x8 q0 = h0 * h0, q1 = h1 * h1;
        __builtin_amdgcn_s_setprio(1);
        pvm[0][ch][0] = mfma16(pf0, h0, pvm[0][ch][0]);
        pvm[1][ch][0] = mfma16(pf1, h0, pvm[1][ch][0]);
        pvm[2][ch][0] = mfma16(pf2, h0, pvm[2][ch][0]);
        pvm[3][ch][0] = mfma16(pf3, h0, pvm[3][ch][0]);
        pvs[0][ch][0] = mfma16(pf0, q0, pvs[0][ch][0]);
        pvs[1][ch][0] = mfma16(pf1, q0, pvs[1][ch][0]);
        pvs[2][ch][0] = mfma16(pf2, q0, pvs[2][ch][0]);
        pvs[3][ch][0] = mfma16(pf3, q0, pvs[3][ch][0]);
        pvm[0][ch][1] = mfma16(pf0, h1, pvm[0][ch][1]);
        pvm[1][ch][1] = mfma16(pf1, h1, pvm[1][ch][1]);
        pvm[2][ch][1] = mfma16(pf2, h1, pvm[2][ch][1]);
        pvm[3][ch][1] = mfma16(pf3, h1, pvm[3][ch][1]);
        pvs[0][ch][1] = mfma16(pf0, q1, pvs[0][ch][1]);
        pvs[1][ch][1] = mfma16(pf1, q1, pvs[1][ch][1]);
        pvs[2][ch][1] = mfma16(pf2, q1, pvs[2][ch][1]);
        pvs[3][ch][1] = mfma16(pf3, q1, pvs[3][ch][1]);
        __builtin_amdgcn_s_setprio(0);
        const int pn = P_ + 2;
        if (pn < 16) stageH2(pn, bf);
        else stageGn(pn - 16, bf, dnext);  // next tile G chunks (0,0),(0,1)
      }
    }
  }
  asm volatile("s_waitcnt vmcnt(0)" ::: "memory");

  // ---- epilogue: out[b][c][t] = std * (content - cm)*cr + mean ----
  f32x4 invq[4];
#pragma unroll
  for (int mt = 0; mt < 4; ++mt)
    invq[mt] = *(const f32x4*)&fin_invl[mt * 16 + lg * 4];
#pragma unroll
  for (int ch = 0; ch < 2; ++ch)
#pragma unroll
    for (int nt = 0; nt < 2; ++nt) {
      const int c = ch * 256 + w * 32 + nt * 16 + l15;
      const size_t row = (size_t)b * C_ + c;
      const float cm = cmean[row];
      const float cr = crstd[row];
      const float* cp = content + row * TC + t0;
      float* op = out + row * TC + t0;
#pragma unroll
      for (int mt = 0; mt < 4; ++mt) {
        const int q0 = mt * 16 + lg * 4;
        const float4 x = *(const float4*)(cp + q0);
        const f32x4 mu = pvm[mt][ch][nt] * invq[mt];
        const f32x4 se = pvs[mt][ch][nt] * invq[mt];
        float4 y;
        y.x = sqrtf(fmaxf(se[0] - mu[0] * mu[0], 0.f)) * ((x.x - cm) * cr) + mu[0];
        y.y = sqrtf(fmaxf(se[1] - mu[1] * mu[1], 0.f)) * ((x.y - cm) * cr) + mu[1];
        y.z = sqrtf(fmaxf(se[2] - mu[2] * mu[2], 0.f)) * ((x.z - cm) * cr) + mu[2];
        y.w = sqrtf(fmaxf(se[3] - mu[3] * mu[3], 0.f)) * ((x.w - cm) * cr) + mu[3];
        *(float4*)(op + q0) = y;
      }
    }
}

extern "C" void kernel_launch(void* const* d_in, const int* in_sizes, int n_in,
                              void* d_out, int out_size, void* d_ws, size_t ws_size,
                              hipStream_t stream) {
  (void)in_sizes;
  (void)n_in;
  (void)out_size;
  (void)ws_size;  // needs ~96 MB
  const float* content = (const float*)d_in[0];
  const float* style = (const float*)d_in[1];
  const float* content_key = (const float*)d_in[2];
  const float* style_key = (const float*)d_in[3];
  const float* Wf = (const float*)d_in[4];
  const float* bf = (const float*)d_in[5];
  const float* Wg = (const float*)d_in[6];
  const float* bg = (const float*)d_in[7];
  const float* Wh = (const float*)d_in[8];
  const float* bh = (const float*)d_in[9];
  float* out = (float*)d_out;

  char* ws = (char*)d_ws;
  float* Wfg = (float*)(ws);                       // 1 MB
  float* wbeta = (float*)(ws + 1048576);           // 2 KB
  float* bprime = (float*)(ws + 1048576 + 4096);   // 2 KB
  float* c0p = (float*)(ws + 1048576 + 8192);      // 4 B
  float* beta = (float*)(ws + 1048576 + 12288);    // 64 KB
  u16* Gt = (u16*)(ws + 67108864);
  u16* Hm = (u16*)(ws + 83886080);
  float* cmean = (float*)(ws + 100663296);
  float* crstd = (float*)(ws + 100663296 + 16384);

  k_content_stats<<<dim3(B_ * C_), dim3(256), 0, stream>>>(content, cmean, crstd);
  k_wfg<<<dim3(8, 2), dim3(256), 0, stream>>>(Wf, Wg, Wfg);
  k_wbeta<<<dim3(1), dim3(512), 0, stream>>>(Wf, Wg, bf, bg, wbeta, bprime, c0p);
  k_beta<<<dim3(8, 8), dim3(256), 0, stream>>>(style_key, wbeta, c0p, beta);
  // G'[b][s][i] = conv(Wfg, style_key) + b'
  k_conv<false><<<dim3(TS / 64, 2, B_), dim3(256), 0, stream>>>(style_key, Wfg, bprime, Gt, TS);
  // H[b][c][s] = conv(Wh, style) (transposed store)
  k_conv<true><<<dim3(TS / 64, 2, B_), dim3(256), 0, stream>>>(style, Wh, bh, Hm, TS);

  k_attn<<<dim3(1024), dim3(512), 0, stream>>>(content_key, Gt, Hm, beta, content,
                                               cmean, crstd, out);
}

// Round 9
// 686.926 us; speedup vs baseline: 2.3349x; 1.0653x over previous
//
#include <hip/hip_runtime.h>
#include <hip/hip_fp16.h>

// AdaAttN fused pipeline, fp16 MFMA path, single-pass flash attention.
// B=8, C=512, Tc=8192, Ts=2048.
//
// Algebraic fusion: score = F.G = (Wf ck + bf).(Wg sk + bg)
//   = ck . G' + beta,  G' = conv(Wfg, sk) + b',  Wfg = Wf^T Wg,
//   b' = Wf^T bg, beta[s] = (Wg^T bf).sk[:,s] + bf.bg
// -> no Ft tensor, content_key staged directly as the QK B-operand.
//
// ws layout (bytes):
//   Wfg  [512][512] f32 :         0 .. 1,048,576
//   wbeta[512] f32      : 1,048,576
//   bprime[512] f32     : 1,052,672  (offset 1,048,576+4096)
//   c0   [1] f32        : 1,056,768
//   beta [8][2048] f32  : 1,060,864 .. 1,126,400
//   Gt(G')[8][2048][512] fp16 : 67,108,864 .. 83,886,080
//   H   [8][512][2048] fp16   : 83,886,080 .. 100,663,296
//   cmean [4096] f32          : 100,663,296
//   crstd [4096] f32          : 100,679,680

#define B_ 8
#define C_ 512
#define TC 8192
#define TS 2048

typedef unsigned short u16;
typedef __attribute__((ext_vector_type(8))) _Float16 f16x8;
typedef __attribute__((ext_vector_type(4))) float f32x4;

__device__ __forceinline__ u16 f2h(float f) {
  return __half_as_ushort(__float2half(f));
}

__device__ __forceinline__ f32x4 mfma16(f16x8 a, f16x8 b, f32x4 c) {
  return __builtin_amdgcn_mfma_f32_16x16x32_f16(a, b, c, 0, 0, 0);
}

// async global->LDS, 16B per lane; LDS dest = wave-uniform base + lane*16
__device__ __forceinline__ void stage16(const u16* g, u16* l) {
  __builtin_amdgcn_global_load_lds(
      (__attribute__((address_space(1))) void*)(const void*)g,
      (__attribute__((address_space(3))) void*)l, 16, 0, 0);
}

// raw barrier: flush LDS ops, no vmcnt drain (keeps staging loads in flight)
#define BARSYNC()                                         \
  do {                                                    \
    asm volatile("s_waitcnt lgkmcnt(0)" ::: "memory");    \
    __builtin_amdgcn_s_barrier();                         \
    __builtin_amdgcn_sched_barrier(0);                    \
  } while (0)

// ---------------- K0: per-(b,c) content stats (ddof=1) ----------------
__global__ __launch_bounds__(256) void k_content_stats(
    const float* __restrict__ x, float* __restrict__ cmean, float* __restrict__ crstd) {
  const int row = blockIdx.x;  // b*512 + c
  const float4* p = (const float4*)(x + (size_t)row * TC);
  float s = 0.f, ss = 0.f;
  for (int i = threadIdx.x; i < TC / 4; i += 256) {
    float4 v = p[i];
    s += v.x + v.y + v.z + v.w;
    ss += v.x * v.x + v.y * v.y + v.z * v.z + v.w * v.w;
  }
#pragma unroll
  for (int d = 1; d < 64; d <<= 1) {
    s += __shfl_xor(s, d);
    ss += __shfl_xor(ss, d);
  }
  __shared__ float rs[4], rss[4];
  if ((threadIdx.x & 63) == 0) {
    rs[threadIdx.x >> 6] = s;
    rss[threadIdx.x >> 6] = ss;
  }
  __syncthreads();
  if (threadIdx.x == 0) {
    float S = rs[0] + rs[1] + rs[2] + rs[3];
    float SS = rss[0] + rss[1] + rss[2] + rss[3];
    float mean = S / (float)TC;
    float var = (SS - S * mean) / (float)(TC - 1);
    cmean[row] = mean;
    crstd[row] = rsqrtf(var + 1e-5f);
  }
}

// ---------------- K-WFG: Wfg[i][j] = sum_o Wf[o][i] * Wg[o][j]  (fp32 out) ----
__global__ __launch_bounds__(256) void k_wfg(
    const float* __restrict__ Wf, const float* __restrict__ Wg,
    float* __restrict__ Wfg) {
  const int i0 = blockIdx.x * 64;
  const int j0 = blockIdx.y * 256;
  const int tid = threadIdx.x;
  const int w = tid >> 6, ln = tid & 63, lg = ln >> 4, l15 = ln & 15;
  __shared__ u16 As[64][72];
  __shared__ u16 Bs[256][72];
  const f32x4 vzero = {0.f, 0.f, 0.f, 0.f};
  f32x4 acc[4][4];
#pragma unroll
  for (int i = 0; i < 4; ++i)
#pragma unroll
    for (int j = 0; j < 4; ++j) acc[i][j] = vzero;

  for (int o0 = 0; o0 < 512; o0 += 64) {
    __syncthreads();
    {  // A: Wf[o0..+64][i0..+64] -> As[i][o]  (4x4 reg transpose)
      const int iq = tid & 15, oq = tid >> 4;
      const float* src = Wf + (size_t)(o0 + oq * 4) * 512 + i0 + iq * 4;
      float4 r0 = *(const float4*)(src);
      float4 r1 = *(const float4*)(src + 512);
      float4 r2 = *(const float4*)(src + 1024);
      float4 r3 = *(const float4*)(src + 1536);
      *(ushort4*)&As[iq * 4 + 0][oq * 4] = make_ushort4(f2h(r0.x), f2h(r1.x), f2h(r2.x), f2h(r3.x));
      *(ushort4*)&As[iq * 4 + 1][oq * 4] = make_ushort4(f2h(r0.y), f2h(r1.y), f2h(r2.y), f2h(r3.y));
      *(ushort4*)&As[iq * 4 + 2][oq * 4] = make_ushort4(f2h(r0.z), f2h(r1.z), f2h(r2.z), f2h(r3.z));
      *(ushort4*)&As[iq * 4 + 3][oq * 4] = make_ushort4(f2h(r0.w), f2h(r1.w), f2h(r2.w), f2h(r3.w));
    }
    {  // B: Wg[o0..+64][j0..+256] -> Bs[j][o]  (4 tiles per thread)
      const int jq = tid & 63, og = tid >> 6;
#pragma unroll
      for (int ii = 0; ii < 4; ++ii) {
        const int oq = og * 4 + ii;
        const float* src = Wg + (size_t)(o0 + oq * 4) * 512 + j0 + jq * 4;
        float4 r0 = *(const float4*)(src);
        float4 r1 = *(const float4*)(src + 512);
        float4 r2 = *(const float4*)(src + 1024);
        float4 r3 = *(const float4*)(src + 1536);
        *(ushort4*)&Bs[jq * 4 + 0][oq * 4] = make_ushort4(f2h(r0.x), f2h(r1.x), f2h(r2.x), f2h(r3.x));
        *(ushort4*)&Bs[jq * 4 + 1][oq * 4] = make_ushort4(f2h(r0.y), f2h(r1.y), f2h(r2.y), f2h(r3.y));
        *(ushort4*)&Bs[jq * 4 + 2][oq * 4] = make_ushort4(f2h(r0.z), f2h(r1.z), f2h(r2.z), f2h(r3.z));
        *(ushort4*)&Bs[jq * 4 + 3][oq * 4] = make_ushort4(f2h(r0.w), f2h(r1.w), f2h(r2.w), f2h(r3.w));
      }
    }
    __syncthreads();
#pragma unroll
    for (int ks = 0; ks < 2; ++ks) {
      f16x8 a[4], bb[4];
#pragma unroll
      for (int mt = 0; mt < 4; ++mt)
        a[mt] = *(const f16x8*)&As[mt * 16 + l15][ks * 32 + lg * 8];
#pragma unroll
      for (int nt = 0; nt < 4; ++nt)
        bb[nt] = *(const f16x8*)&Bs[w * 64 + nt * 16 + l15][ks * 32 + lg * 8];
#pragma unroll
      for (int mt = 0; mt < 4; ++mt)
#pragma unroll
        for (int nt = 0; nt < 4; ++nt)
          acc[mt][nt] = mfma16(a[mt], bb[nt], acc[mt][nt]);
    }
  }
#pragma unroll
  for (int nt = 0; nt < 4; ++nt) {
    const int n = j0 + w * 64 + nt * 16 + l15;
#pragma unroll
    for (int mt = 0; mt < 4; ++mt) {
      const int mb = i0 + mt * 16 + lg * 4;
      f32x4 v = acc[mt][nt];
      float* yp = Wfg + (size_t)mb * 512 + n;
      yp[0 * 512] = v[0];
      yp[1 * 512] = v[1];
      yp[2 * 512] = v[2];
      yp[3 * 512] = v[3];
    }
  }
}

// ---------------- K-WBETA: wb = Wg^T bf, bp = Wf^T bg, c0 = bf.bg ----------------
// grid(8) x 256 thr: j = blk*64 + (t&63), o split 4 ways, LDS reduce.
__global__ __launch_bounds__(256) void k_wbeta(
    const float* __restrict__ Wf, const float* __restrict__ Wg,
    const float* __restrict__ bfv, const float* __restrict__ bgv,
    float* __restrict__ wb, float* __restrict__ bp, float* __restrict__ c0) {
  __shared__ float ra[4][64], rb[4][64];
  const int t = threadIdx.x;
  const int j = blockIdx.x * 64 + (t & 63);
  const int os = t >> 6;  // 0..3
  float a = 0.f, b2 = 0.f;
  for (int i = 0; i < 128; ++i) {
    const int o = os * 128 + i;
    a += bfv[o] * Wg[(size_t)o * 512 + j];
    b2 += bgv[o] * Wf[(size_t)o * 512 + j];
  }
  ra[os][t & 63] = a;
  rb[os][t & 63] = b2;
  __syncthreads();
  if (os == 0) {
    wb[j] = a + ra[1][t] + ra[2][t] + ra[3][t];
    bp[j] = b2 + rb[1][t] + rb[2][t] + rb[3][t];
  }
  if (blockIdx.x == 0) {
    float c = 0.f;
    for (int o = t; o < 512; o += 256) c += bfv[o] * bgv[o];
#pragma unroll
    for (int d = 1; d < 64; d <<= 1) c += __shfl_xor(c, d);
    __shared__ float rc[4];
    if ((t & 63) == 0) rc[t >> 6] = c;
    __syncthreads();
    if (t == 0) *c0 = rc[0] + rc[1] + rc[2] + rc[3];
  }
}

// ---------------- K-BETA: beta[b][s] = sum_j wb[j]*sk[b][j][s] + c0 ----------------
// grid(TS/64, B) x 256 thr: s = blk*64 + (t&63) (coalesced 256B rows),
// j split 4 ways, LDS reduce.
__global__ __launch_bounds__(256) void k_beta(
    const float* __restrict__ sk, const float* __restrict__ wb,
    const float* __restrict__ c0, float* __restrict__ beta) {
  __shared__ float r[4][64];
  const int b = blockIdx.y;
  const int t = threadIdx.x;
  const int s = blockIdx.x * 64 + (t & 63);
  const int ks = t >> 6;  // 0..3
  const float* p = sk + (size_t)b * 512 * TS + s;
  float acc = 0.f;
  for (int i = 0; i < 128; ++i) {
    const int j = ks * 128 + i;
    acc += wb[j] * p[(size_t)j * TS];
  }
  r[ks][t & 63] = acc;
  __syncthreads();
  if (ks == 0)
    beta[b * TS + s] = acc + r[1][t] + r[2][t] + r[3][t] + *c0;
}

// ---------------- conv1x1 GEMM (round-7, verified) ----------------
template <bool TRANS_OUT>
__global__ __launch_bounds__(256, 3) void k_conv(
    const float* __restrict__ X, const float* __restrict__ W,
    const float* __restrict__ bias, u16* __restrict__ Y, int M) {
  const int b = blockIdx.z;
  const int m0 = blockIdx.x * 64;
  const int n0 = blockIdx.y * 256;
  const int tid = threadIdx.x;
  const int w = tid >> 6, ln = tid & 63, lg = ln >> 4, l15 = ln & 15;
  __shared__ u16 As[64][72];
  __shared__ u16 Bs[256][72];
  const float* Xb = X + (size_t)b * C_ * M;
  const f32x4 vzero = {0.f, 0.f, 0.f, 0.f};
  f32x4 acc[4][4];
#pragma unroll
  for (int i = 0; i < 4; ++i)
#pragma unroll
    for (int j = 0; j < 4; ++j) acc[i][j] = vzero;

  const int mq = tid & 15, kq = tid >> 4;  // m-quad (coalesced), k-quad
  for (int k0 = 0; k0 < 512; k0 += 64) {
    __syncthreads();
    {  // stage A: X[k0..+64][m0..+64] -> As[m][k], 4x4 reg transpose
      const float* src = Xb + (size_t)(k0 + kq * 4) * M + m0 + mq * 4;
      float4 r0 = *(const float4*)(src);
      float4 r1 = *(const float4*)(src + M);
      float4 r2 = *(const float4*)(src + 2 * M);
      float4 r3 = *(const float4*)(src + 3 * M);
      *(ushort4*)&As[mq * 4 + 0][kq * 4] =
          make_ushort4(f2h(r0.x), f2h(r1.x), f2h(r2.x), f2h(r3.x));
      *(ushort4*)&As[mq * 4 + 1][kq * 4] =
          make_ushort4(f2h(r0.y), f2h(r1.y), f2h(r2.y), f2h(r3.y));
      *(ushort4*)&As[mq * 4 + 2][kq * 4] =
          make_ushort4(f2h(r0.z), f2h(r1.z), f2h(r2.z), f2h(r3.z));
      *(ushort4*)&As[mq * 4 + 3][kq * 4] =
          make_ushort4(f2h(r0.w), f2h(r1.w), f2h(r2.w), f2h(r3.w));
    }
    {  // stage B
      const float* src = W + (size_t)(n0 + tid) * 512 + k0;
#pragma unroll
      for (int i = 0; i < 16; ++i) {
        float4 v = *(const float4*)(src + i * 4);
        ushort4 hq = make_ushort4(f2h(v.x), f2h(v.y), f2h(v.z), f2h(v.w));
        *(ushort4*)&Bs[tid][i * 4] = hq;
      }
    }
    __syncthreads();
#pragma unroll
    for (int ks = 0; ks < 2; ++ks) {
      f16x8 a[4], bb[4];
#pragma unroll
      for (int mt = 0; mt < 4; ++mt)
        a[mt] = *(const f16x8*)&As[mt * 16 + l15][ks * 32 + lg * 8];
#pragma unroll
      for (int nt = 0; nt < 4; ++nt)
        bb[nt] = *(const f16x8*)&Bs[w * 64 + nt * 16 + l15][ks * 32 + lg * 8];
#pragma unroll
      for (int mt = 0; mt < 4; ++mt)
#pragma unroll
        for (int nt = 0; nt < 4; ++nt)
          acc[mt][nt] = mfma16(a[mt], bb[nt], acc[mt][nt]);
    }
  }
#pragma unroll
  for (int nt = 0; nt < 4; ++nt) {
    const int n = n0 + w * 64 + nt * 16 + l15;
    const float bv = bias[n];
#pragma unroll
    for (int mt = 0; mt < 4; ++mt) {
      const int mb = m0 + mt * 16 + lg * 4;
      f32x4 v = acc[mt][nt];
      if (!TRANS_OUT) {
        u16* yp = Y + (size_t)b * M * 512 + (size_t)mb * 512 + n;
        yp[0 * 512] = f2h(v[0] + bv);
        yp[1 * 512] = f2h(v[1] + bv);
        yp[2 * 512] = f2h(v[2] + bv);
        yp[3 * 512] = f2h(v[3] + bv);
      } else {
        ushort4 hq = make_ushort4(f2h(v[0] + bv), f2h(v[1] + bv),
                                  f2h(v[2] + bv), f2h(v[3] + bv));
        *(ushort4*)(Y + (size_t)b * 512 * M + (size_t)n * M + mb) = hq;
      }
    }
  }
}

// ---------------- K5: flash attention, Wf folded into G' (round-8, verified) ----
__global__ __launch_bounds__(512, 2) void k_attn(
    const float* __restrict__ ck, const u16* __restrict__ Gt,
    const u16* __restrict__ Hm, const float* __restrict__ betap,
    const float* __restrict__ content, const float* __restrict__ cmean,
    const float* __restrict__ crstd, float* __restrict__ out) {
  __shared__ u16 Fq[64 * 512];     // ckT: byte = t*1024 + sw*16, sw=(g&56)|((g^t)&7)
  __shared__ u16 UG[2][128 * 64];  // G' chunk [128 s][64 i]
  __shared__ u16 UH[2][256 * 32];  // H chunk [256 c][32 s]
  __shared__ u16 Ps[64 * 128];     // [t][s-local]
  __shared__ float red[64][20];    // [t-row][wave*2]: (max2, sum), stride 80B
  __shared__ float fin_fac[64];
  __shared__ float fin_invl[64];
  __shared__ float flagv[2];

  const int bid = blockIdx.x;
  const int swz = (bid & 7) * 128 + (bid >> 3);  // XCD-contiguous (1024%8==0)
  const int b = swz >> 7;
  const int t0 = (swz & 127) * 64;
  const int tid = threadIdx.x;
  const int w = tid >> 6, ln = tid & 63, lg = ln >> 4, l15 = ln & 15;

  const u16* Gtb = Gt + (size_t)b * TS * C_;
  const u16* Hb = Hm + (size_t)b * C_ * TS;

  // ---- ckT stage: content_key[b][j][t0..+64] fp32 -> Fq[t][j] fp16 swizzled ----
  {
    const int tq = tid & 15;         // t-quad
    const int jq0 = (tid >> 4) * 4;  // j-quad base (0..124)
    const float* ckb = ck + (size_t)b * C_ * TC + t0;
#pragma unroll
    for (int i = 0; i < 4; ++i) {
      const int jq = jq0 + i;
      const float* src = ckb + (size_t)(jq * 4) * TC + tq * 4;
      float4 r0 = *(const float4*)(src);
      float4 r1 = *(const float4*)(src + TC);
      float4 r2 = *(const float4*)(src + 2 * TC);
      float4 r3 = *(const float4*)(src + 3 * TC);
      const int g = jq >> 1, half = (jq & 1) * 8;
      const float* q0 = (const float*)&r0;
      const float* q1 = (const float*)&r1;
      const float* q2 = (const float*)&r2;
      const float* q3 = (const float*)&r3;
#pragma unroll
      for (int dt = 0; dt < 4; ++dt) {
        const int t = tq * 4 + dt;
        const int sw = (g & 56) | ((g ^ t) & 7);
        ushort4 pk = make_ushort4(f2h(q0[dt]), f2h(q1[dt]), f2h(q2[dt]), f2h(q3[dt]));
        *(ushort4*)((char*)Fq + t * 1024 + sw * 16 + half) = pk;
      }
    }
  }
  if (tid < 2) flagv[tid] = 0.f;
  __syncthreads();  // full drain once; ledger starts clean

  // ---- per-lane swizzle base pointers (all reads = base + const imm) ----
  const int cF = lg ^ (l15 & 7);
  const char* pF0 = (const char*)Fq + l15 * 1024 + cF * 16;
  const char* pF1 = (const char*)Fq + l15 * 1024 + (cF ^ 4) * 16;
  const char* pG0 = (const char*)UG + (w * 16 + l15) * 128 + cF * 16;
  const char* pG1 = (const char*)UG + (w * 16 + l15) * 128 + (cF ^ 4) * 16;
  const int cH = lg ^ (l15 & 3) ^ ((l15 >> 2) & 3);
  const char* pH = (const char*)UH + (w * 32 + l15) * 64 + cH * 16;
  const char* pP0 = (const char*)Ps + l15 * 256 + cF * 16;
  const char* pP1 = (const char*)Ps + l15 * 256 + (cF ^ 4) * 16;
  const int cW = ((((w & 3) << 1) | (lg >> 1)) ^ (l15 & 7));
  char* pPw = (char*)Ps + l15 * 256 + (w & 4) * 32 + cW * 16 + (lg & 1) * 8;

  auto readF = [&](int tt, int kc_, int ks) -> f16x8 {
    return *(const f16x8*)((ks ? pF1 : pF0) + tt * 16384 + kc_ * 128);
  };
  auto readG = [&](int bf, int ks) -> f16x8 {
    return *(const f16x8*)((ks ? pG1 : pG0) + bf * 16384);
  };
  auto readH = [&](int bf, int nt) -> f16x8 {
    return *(const f16x8*)(pH + bf * 16384 + nt * 1024);
  };
  auto readPa = [&](int mt, int ksl) -> f16x8 {
    return *(const f16x8*)(((ksl & 1) ? pP1 : pP0) + mt * 4096 + (ksl & 2) * 64);
  };

  // ---- loop-carried staging source pointers (u16 units) ----
  const int gl = (ln & 7) ^ ((ln >> 3) & 7);
  const u16* sG[2][2];
#pragma unroll
  for (int sh = 0; sh < 2; ++sh)
#pragma unroll
    for (int i = 0; i < 2; ++i)
      sG[sh][i] = Gtb + (size_t)(sh * 128 + w * 16 + i * 8 + (ln >> 3)) * 512 + gl * 8;
  const int hl = (ln & 3) ^ ((ln >> 2) & 3) ^ ((ln >> 4) & 3);
  const u16* sH[2][2];
#pragma unroll
  for (int ch = 0; ch < 2; ++ch)
#pragma unroll
    for (int i = 0; i < 2; ++i)
      sH[ch][i] = Hb + (size_t)(ch * 256 + w * 32 + i * 16 + (ln >> 2)) * 2048 + hl * 8;

  auto stageG2 = [&](int kc_, int sh, int bf) {
    stage16(sG[sh][0] + kc_ * 64, (u16*)((char*)UG + bf * 16384 + (w * 16 + 0) * 128));
    stage16(sG[sh][1] + kc_ * 64, (u16*)((char*)UG + bf * 16384 + (w * 16 + 8) * 128));
  };
  auto stageH2 = [&](int hc, int bf) {
    const int ch = hc & 1, kslg = hc >> 1;
    stage16(sH[ch][0] + kslg * 32, (u16*)((char*)UH + bf * 16384 + (w * 32 + 0) * 64));
    stage16(sH[ch][1] + kslg * 32, (u16*)((char*)UH + bf * 16384 + (w * 32 + 16) * 64));
  };
  auto stageGn = [&](int sh, int bf, int dnext) {  // next tile, chunk (kc=0, sh)
    stage16(sG[sh][0] + dnext, (u16*)((char*)UG + bf * 16384 + (w * 16 + 0) * 128));
    stage16(sG[sh][1] + dnext, (u16*)((char*)UG + bf * 16384 + (w * 16 + 8) * 128));
  };

  // prologue stages: tile 0, G chunks (0,0)->buf0, (0,1)->buf1
  stageG2(0, 0, 0);
  stageG2(0, 1, 1);

  const f32x4 vzero = {0.f, 0.f, 0.f, 0.f};
  f32x4 pvm[4][2][2], pvs[4][2][2];
#pragma unroll
  for (int mt = 0; mt < 4; ++mt)
#pragma unroll
    for (int ch = 0; ch < 2; ++ch)
#pragma unroll
      for (int nt = 0; nt < 2; ++nt) {
        pvm[mt][ch][nt] = vzero;
        pvs[mt][ch][nt] = vzero;
      }
  // per-lane online state for its 4 t-rows (tt*16 + l15), base-2 units
  float m_run[4] = {-1e30f, -1e30f, -1e30f, -1e30f};
  float l_run[4] = {0.f, 0.f, 0.f, 0.f};
  const float LOG2E = 1.44269504f;
  const float* betab = betap + b * TS + w * 16 + lg * 4;

  for (int st = 0; st < 8; ++st) {
    if (st > 0) {
#pragma unroll
      for (int sh = 0; sh < 2; ++sh)
#pragma unroll
        for (int i = 0; i < 2; ++i) {
          sG[sh][i] += 131072;  // +256 s-rows
          sH[sh][i] += 256;     // +512 B along s
        }
    }
    const int dnext = (st == 7) ? -917504 : 131072;
    f32x4 sacc[2][4];  // [sh][tt]
#pragma unroll
    for (int sh = 0; sh < 2; ++sh)
#pragma unroll
      for (int tt = 0; tt < 4; ++tt) sacc[sh][tt] = vzero;

    // ---- QK: 16 phases (kc x sh); F-frags read at sh==0, reused at sh==1 ----
#pragma unroll
    for (int kc = 0; kc < 8; ++kc) {
      f16x8 fA[2][4];
#pragma unroll
      for (int sh = 0; sh < 2; ++sh) {
        const int q = kc * 2 + sh;
        asm volatile("s_waitcnt vmcnt(2)" ::: "memory");
        const int bf = q & 1;
        if (sh == 0) {
#pragma unroll
          for (int ks = 0; ks < 2; ++ks)
#pragma unroll
            for (int tt = 0; tt < 4; ++tt) fA[ks][tt] = readF(tt, kc, ks);
        }
        __builtin_amdgcn_s_setprio(1);
#pragma unroll
        for (int ks = 0; ks < 2; ++ks) {
          f16x8 gv = readG(bf, ks);
          sacc[sh][0] = mfma16(gv, fA[ks][0], sacc[sh][0]);
          sacc[sh][1] = mfma16(gv, fA[ks][1], sacc[sh][1]);
          sacc[sh][2] = mfma16(gv, fA[ks][2], sacc[sh][2]);
          sacc[sh][3] = mfma16(gv, fA[ks][3], sacc[sh][3]);
        }
        __builtin_amdgcn_s_setprio(0);
        const int qn = q + 2;
        if (qn < 16) stageG2(qn >> 1, qn & 1, bf);
        else stageH2(qn - 16, bf);  // qn=16,17 -> H chunks 0,1
      }
    }

    // ---- beta add: rows = s; same for all tt ----
    {
      const float4 be0 = *(const float4*)(betab + st * 256);
      const float4 be1 = *(const float4*)(betab + st * 256 + 128);
      f32x4 bv0 = {be0.x, be0.y, be0.z, be0.w};
      f32x4 bv1 = {be1.x, be1.y, be1.z, be1.w};
#pragma unroll
      for (int tt = 0; tt < 4; ++tt) {
        sacc[0][tt] += bv0;
        sacc[1][tt] += bv1;
      }
    }

    // ---- per-wave partial stats over this wave's 32 s (2 sh x 4 rg + lg) ----
    float mx4[4];
#pragma unroll
    for (int tt = 0; tt < 4; ++tt) {
      f32x4 v0 = sacc[0][tt] * LOG2E;
      f32x4 v1 = sacc[1][tt] * LOG2E;
      float mx = fmaxf(fmaxf(fmaxf(v0[0], v0[1]), fmaxf(v0[2], v0[3])),
                       fmaxf(fmaxf(v1[0], v1[1]), fmaxf(v1[2], v1[3])));
      mx = fmaxf(mx, __shfl_xor(mx, 16));
      mx = fmaxf(mx, __shfl_xor(mx, 32));
      f32x4 p0, p1;
#pragma unroll
      for (int rg = 0; rg < 4; ++rg) {
        p0[rg] = exp2f(v0[rg] - mx);
        p1[rg] = exp2f(v1[rg] - mx);
      }
      float sm = p0[0] + p0[1] + p0[2] + p0[3] + p1[0] + p1[1] + p1[2] + p1[3];
      sm += __shfl_xor(sm, 16);
      sm += __shfl_xor(sm, 32);
      sacc[0][tt] = p0;
      sacc[1][tt] = p1;
      mx4[tt] = mx;
      if (lg == 0)
        *(float2*)&red[tt * 16 + l15][w * 2] = make_float2(mx, sm);
    }
    BARSYNC();  // [A]

    // ---- per-lane redundant merge for rows t = tt*16 + l15 ----
    float fac_p[4];
    {
      bool changed = false;
#pragma unroll
      for (int tt = 0; tt < 4; ++tt) {
        const int row = tt * 16 + l15;
        float4 r0 = *(const float4*)&red[row][0];
        float4 r1 = *(const float4*)&red[row][4];
        float4 r2 = *(const float4*)&red[row][8];
        float4 r3 = *(const float4*)&red[row][12];
        float mc = fmaxf(m_run[tt],
                   fmaxf(fmaxf(fmaxf(r0.x, r0.z), fmaxf(r1.x, r1.z)),
                         fmaxf(fmaxf(r2.x, r2.z), fmaxf(r3.x, r3.z))));
        const float m_new = (mc - m_run[tt] <= 11.0f) ? m_run[tt] : mc;
        float l_new = l_run[tt] * exp2f(m_run[tt] - m_new);
        l_new += r0.y * exp2f(r0.x - m_new) + r0.w * exp2f(r0.z - m_new);
        l_new += r1.y * exp2f(r1.x - m_new) + r1.w * exp2f(r1.z - m_new);
        l_new += r2.y * exp2f(r2.x - m_new) + r2.w * exp2f(r2.z - m_new);
        l_new += r3.y * exp2f(r3.x - m_new) + r3.w * exp2f(r3.z - m_new);
        fac_p[tt] = exp2f(mx4[tt] - m_new);
        if (m_new != m_run[tt]) changed = true;
        if (w == 0 && lg == 0) {
          fin_fac[row] = exp2f(m_run[tt] - m_new);
          if (st == 7) fin_invl[row] = 1.0f / l_new;
        }
        m_run[tt] = m_new;
        l_run[tt] = l_new;
      }
      if (w == 0 && changed) flagv[st & 1] = 1.0f;
    }
    // ---- P-write sh0: packed b64, swizzled [t][s-local] ----
#pragma unroll
    for (int tt = 0; tt < 4; ++tt) {
      const f32x4 pe = sacc[0][tt];
      const float fp = fac_p[tt];
      ushort4 pk = make_ushort4(f2h(pe[0] * fp), f2h(pe[1] * fp),
                                f2h(pe[2] * fp), f2h(pe[3] * fp));
      *(ushort4*)(pPw + tt * 4096) = pk;
    }
    BARSYNC();  // [B] — Ps(sh0) + fin stable

    // ---- rescale (uniform skip via defer-max flag) ----
    {
      const float fl = flagv[st & 1];
      if (fl != 0.f) {
#pragma unroll
        for (int mt = 0; mt < 4; ++mt) {
          const f32x4 fac = *(const f32x4*)&fin_fac[mt * 16 + lg * 4];
#pragma unroll
          for (int ch = 0; ch < 2; ++ch)
#pragma unroll
            for (int nt = 0; nt < 2; ++nt) {
              pvm[mt][ch][nt] *= fac;
              pvs[mt][ch][nt] *= fac;
            }
        }
      }
      if (tid == 0) flagv[(st + 1) & 1] = 0.f;
    }

    // ---- PV: 2 halves x 8 phases; P-frags held across ch ----
#pragma unroll
    for (int half = 0; half < 2; ++half) {
      if (half == 1) {
        BARSYNC();  // [C] — half0 done reading Ps
#pragma unroll
        for (int tt = 0; tt < 4; ++tt) {
          const f32x4 pe = sacc[1][tt];
          const float fp = fac_p[tt];
          ushort4 pk = make_ushort4(f2h(pe[0] * fp), f2h(pe[1] * fp),
                                    f2h(pe[2] * fp), f2h(pe[3] * fp));
          *(ushort4*)(pPw + tt * 4096) = pk;
        }
        BARSYNC();  // [D] — Ps(sh1) stable
      }
      f16x8 pf0, pf1, pf2, pf3;
#pragma unroll
      for (int pp = 0; pp < 8; ++pp) {
        const int P_ = half * 8 + pp;
        asm volatile("s_waitcnt vmcnt(2)" ::: "memory");
        const int bf = P_ & 1;
        const int ch = pp & 1, ksl = pp >> 1;
        if (ch == 0) {
          pf0 = readPa(0, ksl);
          pf1 = readPa(1, ksl);
          pf2 = readPa(2, ksl);
          pf3 = readPa(3, ksl);
        }
        f16x8 h0 = readH(bf, 0), h1 = readH(bf, 1);
        f16x8 q0 = h0 * h0, q1 = h1 * h1;
        __builtin_amdgcn_s_setprio(1);
        pvm[0][ch][0] = mfma16(pf0, h0, pvm[0][ch][0]);
        pvm[1][ch][0] = mfma16(pf1, h0, pvm[1][ch][0]);
        pvm[2][ch][0] = mfma16(pf2, h0, pvm[2][ch][0]);
        pvm[3][ch][0] = mfma16(pf3, h0, pvm[3][ch][0]);
        pvs[0][ch][0] = mfma16(pf0, q0, pvs[0][ch][0]);
        pvs[1][ch][0] = mfma16(pf1, q0, pvs[1][ch][0]);
        pvs[2][ch][0] = mfma16(pf2, q0, pvs[2][ch][0]);
        pvs[3][ch][0] = mfma16(pf3, q0, pvs[3][ch][0]);
        pvm[0][ch][1] = mfma16(pf0, h1, pvm[0][ch][1]);
        pvm[1][ch][1] = mfma16(pf1, h1, pvm[1][ch][1]);
        pvm[2][ch][1] = mfma16(pf2, h1, pvm[2][ch][1]);
        pvm[3][ch][1] = mfma16(pf3, h1, pvm[3][ch][1]);
        pvs[0][ch][1] = mfma16(pf0, q1, pvs[0][ch][1]);
        pvs[1][ch][1] = mfma16(pf1, q1, pvs[1][ch][1]);
        pvs[2][ch][1] = mfma16(pf2, q1, pvs[2][ch][1]);
        pvs[3][ch][1] = mfma16(pf3, q1, pvs[3][ch][1]);
        __builtin_amdgcn_s_setprio(0);
        const int pn = P_ + 2;
        if (pn < 16) stageH2(pn, bf);
        else stageGn(pn - 16, bf, dnext);  // next tile G chunks (0,0),(0,1)
      }
    }
  }
  asm volatile("s_waitcnt vmcnt(0)" ::: "memory");

  // ---- epilogue: out[b][c][t] = std * (content - cm)*cr + mean ----
  f32x4 invq[4];
#pragma unroll
  for (int mt = 0; mt < 4; ++mt)
    invq[mt] = *(const f32x4*)&fin_invl[mt * 16 + lg * 4];
#pragma unroll
  for (int ch = 0; ch < 2; ++ch)
#pragma unroll
    for (int nt = 0; nt < 2; ++nt) {
      const int c = ch * 256 + w * 32 + nt * 16 + l15;
      const size_t row = (size_t)b * C_ + c;
      const float cm = cmean[row];
      const float cr = crstd[row];
      const float* cp = content + row * TC + t0;
      float* op = out + row * TC + t0;
#pragma unroll
      for (int mt = 0; mt < 4; ++mt) {
        const int q0 = mt * 16 + lg * 4;
        const float4 x = *(const float4*)(cp + q0);
        const f32x4 mu = pvm[mt][ch][nt] * invq[mt];
        const f32x4 se = pvs[mt][ch][nt] * invq[mt];
        float4 y;
        y.x = sqrtf(fmaxf(se[0] - mu[0] * mu[0], 0.f)) * ((x.x - cm) * cr) + mu[0];
        y.y = sqrtf(fmaxf(se[1] - mu[1] * mu[1], 0.f)) * ((x.y - cm) * cr) + mu[1];
        y.z = sqrtf(fmaxf(se[2] - mu[2] * mu[2], 0.f)) * ((x.z - cm) * cr) + mu[2];
        y.w = sqrtf(fmaxf(se[3] - mu[3] * mu[3], 0.f)) * ((x.w - cm) * cr) + mu[3];
        *(float4*)(op + q0) = y;
      }
    }
}

extern "C" void kernel_launch(void* const* d_in, const int* in_sizes, int n_in,
                              void* d_out, int out_size, void* d_ws, size_t ws_size,
                              hipStream_t stream) {
  (void)in_sizes;
  (void)n_in;
  (void)out_size;
  (void)ws_size;  // needs ~96 MB
  const float* content = (const float*)d_in[0];
  const float* style = (const float*)d_in[1];
  const float* content_key = (const float*)d_in[2];
  const float* style_key = (const float*)d_in[3];
  const float* Wf = (const float*)d_in[4];
  const float* bf = (const float*)d_in[5];
  const float* Wg = (const float*)d_in[6];
  const float* bg = (const float*)d_in[7];
  const float* Wh = (const float*)d_in[8];
  const float* bh = (const float*)d_in[9];
  float* out = (float*)d_out;

  char* ws = (char*)d_ws;
  float* Wfg = (float*)(ws);                       // 1 MB
  float* wbeta = (float*)(ws + 1048576);           // 2 KB
  float* bprime = (float*)(ws + 1048576 + 4096);   // 2 KB
  float* c0p = (float*)(ws + 1048576 + 8192);      // 4 B
  float* beta = (float*)(ws + 1048576 + 12288);    // 64 KB
  u16* Gt = (u16*)(ws + 67108864);
  u16* Hm = (u16*)(ws + 83886080);
  float* cmean = (float*)(ws + 100663296);
  float* crstd = (float*)(ws + 100663296 + 16384);

  k_content_stats<<<dim3(B_ * C_), dim3(256), 0, stream>>>(content, cmean, crstd);
  k_wfg<<<dim3(8, 2), dim3(256), 0, stream>>>(Wf, Wg, Wfg);
  k_wbeta<<<dim3(8), dim3(256), 0, stream>>>(Wf, Wg, bf, bg, wbeta, bprime, c0p);
  k_beta<<<dim3(TS / 64, B_), dim3(256), 0, stream>>>(style_key, wbeta, c0p, beta);
  // G'[b][s][i] = conv(Wfg, style_key) + b'
  k_conv<false><<<dim3(TS / 64, 2, B_), dim3(256), 0, stream>>>(style_key, Wfg, bprime, Gt, TS);
  // H[b][c][s] = conv(Wh, style) (transposed store)
  k_conv<true><<<dim3(TS / 64, 2, B_), dim3(256), 0, stream>>>(style, Wh, bh, Hm, TS);

  k_attn<<<dim3(1024), dim3(512), 0, stream>>>(content_key, Gt, Hm, beta, content,
                                               cmean, crstd, out);
}

// Round 10
// 674.676 us; speedup vs baseline: 2.3773x; 1.0182x over previous
//
#include <hip/hip_runtime.h>
#include <hip/hip_fp16.h>

// AdaAttN fused pipeline, fp16 MFMA path, single-pass flash attention.
// B=8, C=512, Tc=8192, Ts=2048.
//
// Algebraic fusion: score = F.G = (Wf ck + bf).(Wg sk + bg)
//   = ck . G' + beta,  G' = conv(Wfg, sk) + b',  Wfg = Wf^T Wg,
//   b' = Wf^T bg, beta[s] = (Wg^T bf).sk[:,s] + bf.bg
// beta is computed INSIDE the G' conv (A-stage already holds sk in fp32 regs).
//
// ws layout (bytes):
//   Wfg  [512][512] f32 :         0 .. 1,048,576
//   wbeta[512] f32      : 1,048,576
//   bprime[512] f32     : 1,052,672
//   c0   [1] f32        : 1,056,768
//   beta [8][2048] f32  : 1,060,864 .. 1,126,400
//   Gt(G')[8][2048][512] fp16 : 67,108,864 .. 83,886,080
//   H   [8][512][2048] fp16   : 83,886,080 .. 100,663,296
//   cmean [4096] f32          : 100,663,296
//   crstd [4096] f32          : 100,679,680

#define B_ 8
#define C_ 512
#define TC 8192
#define TS 2048

typedef unsigned short u16;
typedef __attribute__((ext_vector_type(8))) _Float16 f16x8;
typedef __attribute__((ext_vector_type(4))) float f32x4;

__device__ __forceinline__ u16 f2h(float f) {
  return __half_as_ushort(__float2half(f));
}

__device__ __forceinline__ f32x4 mfma16(f16x8 a, f16x8 b, f32x4 c) {
  return __builtin_amdgcn_mfma_f32_16x16x32_f16(a, b, c, 0, 0, 0);
}

// async global->LDS, 16B per lane; LDS dest = wave-uniform base + lane*16
__device__ __forceinline__ void stage16(const u16* g, u16* l) {
  __builtin_amdgcn_global_load_lds(
      (__attribute__((address_space(1))) void*)(const void*)g,
      (__attribute__((address_space(3))) void*)l, 16, 0, 0);
}

// raw barrier: flush LDS ops, no vmcnt drain (keeps staging loads in flight)
#define BARSYNC()                                         \
  do {                                                    \
    asm volatile("s_waitcnt lgkmcnt(0)" ::: "memory");    \
    __builtin_amdgcn_s_barrier();                         \
    __builtin_amdgcn_sched_barrier(0);                    \
  } while (0)

// ---------------- K0: per-(b,c) content stats (ddof=1) ----------------
__global__ __launch_bounds__(256) void k_content_stats(
    const float* __restrict__ x, float* __restrict__ cmean, float* __restrict__ crstd) {
  const int row = blockIdx.x;  // b*512 + c
  const float4* p = (const float4*)(x + (size_t)row * TC);
  float s = 0.f, ss = 0.f;
  for (int i = threadIdx.x; i < TC / 4; i += 256) {
    float4 v = p[i];
    s += v.x + v.y + v.z + v.w;
    ss += v.x * v.x + v.y * v.y + v.z * v.z + v.w * v.w;
  }
#pragma unroll
  for (int d = 1; d < 64; d <<= 1) {
    s += __shfl_xor(s, d);
    ss += __shfl_xor(ss, d);
  }
  __shared__ float rs[4], rss[4];
  if ((threadIdx.x & 63) == 0) {
    rs[threadIdx.x >> 6] = s;
    rss[threadIdx.x >> 6] = ss;
  }
  __syncthreads();
  if (threadIdx.x == 0) {
    float S = rs[0] + rs[1] + rs[2] + rs[3];
    float SS = rss[0] + rss[1] + rss[2] + rss[3];
    float mean = S / (float)TC;
    float var = (SS - S * mean) / (float)(TC - 1);
    cmean[row] = mean;
    crstd[row] = rsqrtf(var + 1e-5f);
  }
}

// ---------------- K-WFG: Wfg[i][j] = sum_o Wf[o][i] * Wg[o][j]  (fp32 out) ----
__global__ __launch_bounds__(256) void k_wfg(
    const float* __restrict__ Wf, const float* __restrict__ Wg,
    float* __restrict__ Wfg) {
  const int i0 = blockIdx.x * 64;
  const int j0 = blockIdx.y * 256;
  const int tid = threadIdx.x;
  const int w = tid >> 6, ln = tid & 63, lg = ln >> 4, l15 = ln & 15;
  __shared__ u16 As[64][72];
  __shared__ u16 Bs[256][72];
  const f32x4 vzero = {0.f, 0.f, 0.f, 0.f};
  f32x4 acc[4][4];
#pragma unroll
  for (int i = 0; i < 4; ++i)
#pragma unroll
    for (int j = 0; j < 4; ++j) acc[i][j] = vzero;

  for (int o0 = 0; o0 < 512; o0 += 64) {
    __syncthreads();
    {  // A: Wf[o0..+64][i0..+64] -> As[i][o]  (4x4 reg transpose)
      const int iq = tid & 15, oq = tid >> 4;
      const float* src = Wf + (size_t)(o0 + oq * 4) * 512 + i0 + iq * 4;
      float4 r0 = *(const float4*)(src);
      float4 r1 = *(const float4*)(src + 512);
      float4 r2 = *(const float4*)(src + 1024);
      float4 r3 = *(const float4*)(src + 1536);
      *(ushort4*)&As[iq * 4 + 0][oq * 4] = make_ushort4(f2h(r0.x), f2h(r1.x), f2h(r2.x), f2h(r3.x));
      *(ushort4*)&As[iq * 4 + 1][oq * 4] = make_ushort4(f2h(r0.y), f2h(r1.y), f2h(r2.y), f2h(r3.y));
      *(ushort4*)&As[iq * 4 + 2][oq * 4] = make_ushort4(f2h(r0.z), f2h(r1.z), f2h(r2.z), f2h(r3.z));
      *(ushort4*)&As[iq * 4 + 3][oq * 4] = make_ushort4(f2h(r0.w), f2h(r1.w), f2h(r2.w), f2h(r3.w));
    }
    {  // B: Wg[o0..+64][j0..+256] -> Bs[j][o]  (4 tiles per thread)
      const int jq = tid & 63, og = tid >> 6;
#pragma unroll
      for (int ii = 0; ii < 4; ++ii) {
        const int oq = og * 4 + ii;
        const float* src = Wg + (size_t)(o0 + oq * 4) * 512 + j0 + jq * 4;
        float4 r0 = *(const float4*)(src);
        float4 r1 = *(const float4*)(src + 512);
        float4 r2 = *(const float4*)(src + 1024);
        float4 r3 = *(const float4*)(src + 1536);
        *(ushort4*)&Bs[jq * 4 + 0][oq * 4] = make_ushort4(f2h(r0.x), f2h(r1.x), f2h(r2.x), f2h(r3.x));
        *(ushort4*)&Bs[jq * 4 + 1][oq * 4] = make_ushort4(f2h(r0.y), f2h(r1.y), f2h(r2.y), f2h(r3.y));
        *(ushort4*)&Bs[jq * 4 + 2][oq * 4] = make_ushort4(f2h(r0.z), f2h(r1.z), f2h(r2.z), f2h(r3.z));
        *(ushort4*)&Bs[jq * 4 + 3][oq * 4] = make_ushort4(f2h(r0.w), f2h(r1.w), f2h(r2.w), f2h(r3.w));
      }
    }
    __syncthreads();
#pragma unroll
    for (int ks = 0; ks < 2; ++ks) {
      f16x8 a[4], bb[4];
#pragma unroll
      for (int mt = 0; mt < 4; ++mt)
        a[mt] = *(const f16x8*)&As[mt * 16 + l15][ks * 32 + lg * 8];
#pragma unroll
      for (int nt = 0; nt < 4; ++nt)
        bb[nt] = *(const f16x8*)&Bs[w * 64 + nt * 16 + l15][ks * 32 + lg * 8];
#pragma unroll
      for (int mt = 0; mt < 4; ++mt)
#pragma unroll
        for (int nt = 0; nt < 4; ++nt)
          acc[mt][nt] = mfma16(a[mt], bb[nt], acc[mt][nt]);
    }
  }
#pragma unroll
  for (int nt = 0; nt < 4; ++nt) {
    const int n = j0 + w * 64 + nt * 16 + l15;
#pragma unroll
    for (int mt = 0; mt < 4; ++mt) {
      const int mb = i0 + mt * 16 + lg * 4;
      f32x4 v = acc[mt][nt];
      float* yp = Wfg + (size_t)mb * 512 + n;
      yp[0 * 512] = v[0];
      yp[1 * 512] = v[1];
      yp[2 * 512] = v[2];
      yp[3 * 512] = v[3];
    }
  }
}

// ---------------- K-WBETA: wb = Wg^T bf, bp = Wf^T bg, c0 = bf.bg ----------------
__global__ __launch_bounds__(256) void k_wbeta(
    const float* __restrict__ Wf, const float* __restrict__ Wg,
    const float* __restrict__ bfv, const float* __restrict__ bgv,
    float* __restrict__ wb, float* __restrict__ bp, float* __restrict__ c0) {
  __shared__ float ra[4][64], rb[4][64];
  const int t = threadIdx.x;
  const int j = blockIdx.x * 64 + (t & 63);
  const int os = t >> 6;  // 0..3
  float a = 0.f, b2 = 0.f;
  for (int i = 0; i < 128; ++i) {
    const int o = os * 128 + i;
    a += bfv[o] * Wg[(size_t)o * 512 + j];
    b2 += bgv[o] * Wf[(size_t)o * 512 + j];
  }
  ra[os][t & 63] = a;
  rb[os][t & 63] = b2;
  __syncthreads();
  if (os == 0) {
    wb[j] = a + ra[1][t] + ra[2][t] + ra[3][t];
    bp[j] = b2 + rb[1][t] + rb[2][t] + rb[3][t];
  }
  if (blockIdx.x == 0) {
    float c = 0.f;
    for (int o = t; o < 512; o += 256) c += bfv[o] * bgv[o];
#pragma unroll
    for (int d = 1; d < 64; d <<= 1) c += __shfl_xor(c, d);
    __shared__ float rc[4];
    if ((t & 63) == 0) rc[t >> 6] = c;
    __syncthreads();
    if (t == 0) *c0 = rc[0] + rc[1] + rc[2] + rc[3];
  }
}

// ---------------- K-CONV2: both conv1x1s in one launch; beta fused in G' ----
// z = b + 8*which: which==0 -> G' = conv(Wfg, style_key)+b', normal store,
//                              + beta[b][s] = wb . sk[:,s] + c0 (n-block 0)
//                  which==1 -> H  = conv(Wh, style)+bh, transposed store
__global__ __launch_bounds__(256, 3) void k_conv2(
    const float* __restrict__ Xg, const float* __restrict__ Wgp,
    const float* __restrict__ bgp, u16* __restrict__ Yg,
    const float* __restrict__ Xh, const float* __restrict__ Whp,
    const float* __restrict__ bhp, u16* __restrict__ Yh,
    const float* __restrict__ wb, const float* __restrict__ c0,
    float* __restrict__ betao) {
  const int z = blockIdx.z;
  const int b = z & 7;
  const int which = z >> 3;
  const float* X = which ? Xh : Xg;
  const float* W = which ? Whp : Wgp;
  const float* bias = which ? bhp : bgp;
  u16* Y = which ? Yh : Yg;
  const int M = TS;
  const int m0 = blockIdx.x * 64;
  const int n0 = blockIdx.y * 256;
  const int tid = threadIdx.x;
  const int w = tid >> 6, ln = tid & 63, lg = ln >> 4, l15 = ln & 15;
  __shared__ u16 As[64][72];
  __shared__ u16 Bs[256][72];
  __shared__ float bred[16][65];
  const float* Xb = X + (size_t)b * C_ * M;
  const f32x4 vzero = {0.f, 0.f, 0.f, 0.f};
  f32x4 acc[4][4];
#pragma unroll
  for (int i = 0; i < 4; ++i)
#pragma unroll
    for (int j = 0; j < 4; ++j) acc[i][j] = vzero;
  float bacc[4] = {0.f, 0.f, 0.f, 0.f};

  const int mq = tid & 15, kq = tid >> 4;  // m-quad (coalesced), k-quad
  for (int k0 = 0; k0 < 512; k0 += 64) {
    __syncthreads();
    {  // stage A: X[k0..+64][m0..+64] -> As[m][k], 4x4 reg transpose
      const float* src = Xb + (size_t)(k0 + kq * 4) * M + m0 + mq * 4;
      float4 r0 = *(const float4*)(src);
      float4 r1 = *(const float4*)(src + M);
      float4 r2 = *(const float4*)(src + 2 * M);
      float4 r3 = *(const float4*)(src + 3 * M);
      if (which == 0) {  // beta partial: bacc[mi] += sum_j wb[k+j]*x[k+j][mi]
        const float4 wv = *(const float4*)(wb + k0 + kq * 4);
        bacc[0] += wv.x * r0.x + wv.y * r1.x + wv.z * r2.x + wv.w * r3.x;
        bacc[1] += wv.x * r0.y + wv.y * r1.y + wv.z * r2.y + wv.w * r3.y;
        bacc[2] += wv.x * r0.z + wv.y * r1.z + wv.z * r2.z + wv.w * r3.z;
        bacc[3] += wv.x * r0.w + wv.y * r1.w + wv.z * r2.w + wv.w * r3.w;
      }
      *(ushort4*)&As[mq * 4 + 0][kq * 4] =
          make_ushort4(f2h(r0.x), f2h(r1.x), f2h(r2.x), f2h(r3.x));
      *(ushort4*)&As[mq * 4 + 1][kq * 4] =
          make_ushort4(f2h(r0.y), f2h(r1.y), f2h(r2.y), f2h(r3.y));
      *(ushort4*)&As[mq * 4 + 2][kq * 4] =
          make_ushort4(f2h(r0.z), f2h(r1.z), f2h(r2.z), f2h(r3.z));
      *(ushort4*)&As[mq * 4 + 3][kq * 4] =
          make_ushort4(f2h(r0.w), f2h(r1.w), f2h(r2.w), f2h(r3.w));
    }
    {  // stage B
      const float* src = W + (size_t)(n0 + tid) * 512 + k0;
#pragma unroll
      for (int i = 0; i < 16; ++i) {
        float4 v = *(const float4*)(src + i * 4);
        ushort4 hq = make_ushort4(f2h(v.x), f2h(v.y), f2h(v.z), f2h(v.w));
        *(ushort4*)&Bs[tid][i * 4] = hq;
      }
    }
    __syncthreads();
#pragma unroll
    for (int ks = 0; ks < 2; ++ks) {
      f16x8 a[4], bb[4];
#pragma unroll
      for (int mt = 0; mt < 4; ++mt)
        a[mt] = *(const f16x8*)&As[mt * 16 + l15][ks * 32 + lg * 8];
#pragma unroll
      for (int nt = 0; nt < 4; ++nt)
        bb[nt] = *(const f16x8*)&Bs[w * 64 + nt * 16 + l15][ks * 32 + lg * 8];
#pragma unroll
      for (int mt = 0; mt < 4; ++mt)
#pragma unroll
        for (int nt = 0; nt < 4; ++nt)
          acc[mt][nt] = mfma16(a[mt], bb[nt], acc[mt][nt]);
    }
  }
  if (which == 0) {  // beta reduce over 16 k-groups, write once (n-block 0)
#pragma unroll
    for (int i = 0; i < 4; ++i) bred[kq][mq * 4 + i] = bacc[i];
    __syncthreads();
    if (blockIdx.y == 0 && tid < 64) {
      float s = *c0;
#pragma unroll
      for (int j = 0; j < 16; ++j) s += bred[j][tid];
      betao[b * TS + m0 + tid] = s;
    }
  }
#pragma unroll
  for (int nt = 0; nt < 4; ++nt) {
    const int n = n0 + w * 64 + nt * 16 + l15;
    const float bv = bias[n];
#pragma unroll
    for (int mt = 0; mt < 4; ++mt) {
      const int mb = m0 + mt * 16 + lg * 4;
      f32x4 v = acc[mt][nt];
      if (which == 0) {
        u16* yp = Y + (size_t)b * M * 512 + (size_t)mb * 512 + n;
        yp[0 * 512] = f2h(v[0] + bv);
        yp[1 * 512] = f2h(v[1] + bv);
        yp[2 * 512] = f2h(v[2] + bv);
        yp[3 * 512] = f2h(v[3] + bv);
      } else {
        ushort4 hq = make_ushort4(f2h(v[0] + bv), f2h(v[1] + bv),
                                  f2h(v[2] + bv), f2h(v[3] + bv));
        *(ushort4*)(Y + (size_t)b * 512 * M + (size_t)n * M + mb) = hq;
      }
    }
  }
}

// ---------------- K5: flash attention, Wf folded into G' (round-8, verified) ----
__global__ __launch_bounds__(512, 2) void k_attn(
    const float* __restrict__ ck, const u16* __restrict__ Gt,
    const u16* __restrict__ Hm, const float* __restrict__ betap,
    const float* __restrict__ content, const float* __restrict__ cmean,
    const float* __restrict__ crstd, float* __restrict__ out) {
  __shared__ u16 Fq[64 * 512];     // ckT: byte = t*1024 + sw*16, sw=(g&56)|((g^t)&7)
  __shared__ u16 UG[2][128 * 64];  // G' chunk [128 s][64 i]
  __shared__ u16 UH[2][256 * 32];  // H chunk [256 c][32 s]
  __shared__ u16 Ps[64 * 128];     // [t][s-local]
  __shared__ float red[64][20];    // [t-row][wave*2]: (max2, sum), stride 80B
  __shared__ float fin_fac[64];
  __shared__ float fin_invl[64];
  __shared__ float flagv[2];

  const int bid = blockIdx.x;
  const int swz = (bid & 7) * 128 + (bid >> 3);  // XCD-contiguous (1024%8==0)
  const int b = swz >> 7;
  const int t0 = (swz & 127) * 64;
  const int tid = threadIdx.x;
  const int w = tid >> 6, ln = tid & 63, lg = ln >> 4, l15 = ln & 15;

  const u16* Gtb = Gt + (size_t)b * TS * C_;
  const u16* Hb = Hm + (size_t)b * C_ * TS;

  // ---- ckT stage: content_key[b][j][t0..+64] fp32 -> Fq[t][j] fp16 swizzled ----
  {
    const int tq = tid & 15;         // t-quad
    const int jq0 = (tid >> 4) * 4;  // j-quad base (0..124)
    const float* ckb = ck + (size_t)b * C_ * TC + t0;
#pragma unroll
    for (int i = 0; i < 4; ++i) {
      const int jq = jq0 + i;
      const float* src = ckb + (size_t)(jq * 4) * TC + tq * 4;
      float4 r0 = *(const float4*)(src);
      float4 r1 = *(const float4*)(src + TC);
      float4 r2 = *(const float4*)(src + 2 * TC);
      float4 r3 = *(const float4*)(src + 3 * TC);
      const int g = jq >> 1, half = (jq & 1) * 8;
      const float* q0 = (const float*)&r0;
      const float* q1 = (const float*)&r1;
      const float* q2 = (const float*)&r2;
      const float* q3 = (const float*)&r3;
#pragma unroll
      for (int dt = 0; dt < 4; ++dt) {
        const int t = tq * 4 + dt;
        const int sw = (g & 56) | ((g ^ t) & 7);
        ushort4 pk = make_ushort4(f2h(q0[dt]), f2h(q1[dt]), f2h(q2[dt]), f2h(q3[dt]));
        *(ushort4*)((char*)Fq + t * 1024 + sw * 16 + half) = pk;
      }
    }
  }
  if (tid < 2) flagv[tid] = 0.f;
  __syncthreads();  // full drain once; ledger starts clean

  // ---- per-lane swizzle base pointers (all reads = base + const imm) ----
  const int cF = lg ^ (l15 & 7);
  const char* pF0 = (const char*)Fq + l15 * 1024 + cF * 16;
  const char* pF1 = (const char*)Fq + l15 * 1024 + (cF ^ 4) * 16;
  const char* pG0 = (const char*)UG + (w * 16 + l15) * 128 + cF * 16;
  const char* pG1 = (const char*)UG + (w * 16 + l15) * 128 + (cF ^ 4) * 16;
  const int cH = lg ^ (l15 & 3) ^ ((l15 >> 2) & 3);
  const char* pH = (const char*)UH + (w * 32 + l15) * 64 + cH * 16;
  const char* pP0 = (const char*)Ps + l15 * 256 + cF * 16;
  const char* pP1 = (const char*)Ps + l15 * 256 + (cF ^ 4) * 16;
  const int cW = ((((w & 3) << 1) | (lg >> 1)) ^ (l15 & 7));
  char* pPw = (char*)Ps + l15 * 256 + (w & 4) * 32 + cW * 16 + (lg & 1) * 8;

  auto readF = [&](int tt, int kc_, int ks) -> f16x8 {
    return *(const f16x8*)((ks ? pF1 : pF0) + tt * 16384 + kc_ * 128);
  };
  auto readG = [&](int bf, int ks) -> f16x8 {
    return *(const f16x8*)((ks ? pG1 : pG0) + bf * 16384);
  };
  auto readH = [&](int bf, int nt) -> f16x8 {
    return *(const f16x8*)(pH + bf * 16384 + nt * 1024);
  };
  auto readPa = [&](int mt, int ksl) -> f16x8 {
    return *(const f16x8*)(((ksl & 1) ? pP1 : pP0) + mt * 4096 + (ksl & 2) * 64);
  };

  // ---- loop-carried staging source pointers (u16 units) ----
  const int gl = (ln & 7) ^ ((ln >> 3) & 7);
  const u16* sG[2][2];
#pragma unroll
  for (int sh = 0; sh < 2; ++sh)
#pragma unroll
    for (int i = 0; i < 2; ++i)
      sG[sh][i] = Gtb + (size_t)(sh * 128 + w * 16 + i * 8 + (ln >> 3)) * 512 + gl * 8;
  const int hl = (ln & 3) ^ ((ln >> 2) & 3) ^ ((ln >> 4) & 3);
  const u16* sH[2][2];
#pragma unroll
  for (int ch = 0; ch < 2; ++ch)
#pragma unroll
    for (int i = 0; i < 2; ++i)
      sH[ch][i] = Hb + (size_t)(ch * 256 + w * 32 + i * 16 + (ln >> 2)) * 2048 + hl * 8;

  auto stageG2 = [&](int kc_, int sh, int bf) {
    stage16(sG[sh][0] + kc_ * 64, (u16*)((char*)UG + bf * 16384 + (w * 16 + 0) * 128));
    stage16(sG[sh][1] + kc_ * 64, (u16*)((char*)UG + bf * 16384 + (w * 16 + 8) * 128));
  };
  auto stageH2 = [&](int hc, int bf) {
    const int ch = hc & 1, kslg = hc >> 1;
    stage16(sH[ch][0] + kslg * 32, (u16*)((char*)UH + bf * 16384 + (w * 32 + 0) * 64));
    stage16(sH[ch][1] + kslg * 32, (u16*)((char*)UH + bf * 16384 + (w * 32 + 16) * 64));
  };
  auto stageGn = [&](int sh, int bf, int dnext) {  // next tile, chunk (kc=0, sh)
    stage16(sG[sh][0] + dnext, (u16*)((char*)UG + bf * 16384 + (w * 16 + 0) * 128));
    stage16(sG[sh][1] + dnext, (u16*)((char*)UG + bf * 16384 + (w * 16 + 8) * 128));
  };

  // prologue stages: tile 0, G chunks (0,0)->buf0, (0,1)->buf1
  stageG2(0, 0, 0);
  stageG2(0, 1, 1);

  const f32x4 vzero = {0.f, 0.f, 0.f, 0.f};
  f32x4 pvm[4][2][2], pvs[4][2][2];
#pragma unroll
  for (int mt = 0; mt < 4; ++mt)
#pragma unroll
    for (int ch = 0; ch < 2; ++ch)
#pragma unroll
      for (int nt = 0; nt < 2; ++nt) {
        pvm[mt][ch][nt] = vzero;
        pvs[mt][ch][nt] = vzero;
      }
  // per-lane online state for its 4 t-rows (tt*16 + l15), base-2 units
  float m_run[4] = {-1e30f, -1e30f, -1e30f, -1e30f};
  float l_run[4] = {0.f, 0.f, 0.f, 0.f};
  const float LOG2E = 1.44269504f;
  const float* betab = betap + b * TS + w * 16 + lg * 4;

  for (int st = 0; st < 8; ++st) {
    if (st > 0) {
#pragma unroll
      for (int sh = 0; sh < 2; ++sh)
#pragma unroll
        for (int i = 0; i < 2; ++i) {
          sG[sh][i] += 131072;  // +256 s-rows
          sH[sh][i] += 256;     // +512 B along s
        }
    }
    const int dnext = (st == 7) ? -917504 : 131072;
    f32x4 sacc[2][4];  // [sh][tt]
#pragma unroll
    for (int sh = 0; sh < 2; ++sh)
#pragma unroll
      for (int tt = 0; tt < 4; ++tt) sacc[sh][tt] = vzero;

    // ---- QK: 16 phases (kc x sh); F-frags read at sh==0, reused at sh==1 ----
#pragma unroll
    for (int kc = 0; kc < 8; ++kc) {
      f16x8 fA[2][4];
#pragma unroll
      for (int sh = 0; sh < 2; ++sh) {
        const int q = kc * 2 + sh;
        asm volatile("s_waitcnt vmcnt(2)" ::: "memory");
        const int bf = q & 1;
        if (sh == 0) {
#pragma unroll
          for (int ks = 0; ks < 2; ++ks)
#pragma unroll
            for (int tt = 0; tt < 4; ++tt) fA[ks][tt] = readF(tt, kc, ks);
        }
        __builtin_amdgcn_s_setprio(1);
#pragma unroll
        for (int ks = 0; ks < 2; ++ks) {
          f16x8 gv = readG(bf, ks);
          sacc[sh][0] = mfma16(gv, fA[ks][0], sacc[sh][0]);
          sacc[sh][1] = mfma16(gv, fA[ks][1], sacc[sh][1]);
          sacc[sh][2] = mfma16(gv, fA[ks][2], sacc[sh][2]);
          sacc[sh][3] = mfma16(gv, fA[ks][3], sacc[sh][3]);
        }
        __builtin_amdgcn_s_setprio(0);
        const int qn = q + 2;
        if (qn < 16) stageG2(qn >> 1, qn & 1, bf);
        else stageH2(qn - 16, bf);  // qn=16,17 -> H chunks 0,1
      }
    }

    // ---- beta add: rows = s; same for all tt ----
    {
      const float4 be0 = *(const float4*)(betab + st * 256);
      const float4 be1 = *(const float4*)(betab + st * 256 + 128);
      f32x4 bv0 = {be0.x, be0.y, be0.z, be0.w};
      f32x4 bv1 = {be1.x, be1.y, be1.z, be1.w};
#pragma unroll
      for (int tt = 0; tt < 4; ++tt) {
        sacc[0][tt] += bv0;
        sacc[1][tt] += bv1;
      }
    }

    // ---- per-wave partial stats over this wave's 32 s (2 sh x 4 rg + lg) ----
    float mx4[4];
#pragma unroll
    for (int tt = 0; tt < 4; ++tt) {
      f32x4 v0 = sacc[0][tt] * LOG2E;
      f32x4 v1 = sacc[1][tt] * LOG2E;
      float mx = fmaxf(fmaxf(fmaxf(v0[0], v0[1]), fmaxf(v0[2], v0[3])),
                       fmaxf(fmaxf(v1[0], v1[1]), fmaxf(v1[2], v1[3])));
      mx = fmaxf(mx, __shfl_xor(mx, 16));
      mx = fmaxf(mx, __shfl_xor(mx, 32));
      f32x4 p0, p1;
#pragma unroll
      for (int rg = 0; rg < 4; ++rg) {
        p0[rg] = exp2f(v0[rg] - mx);
        p1[rg] = exp2f(v1[rg] - mx);
      }
      float sm = p0[0] + p0[1] + p0[2] + p0[3] + p1[0] + p1[1] + p1[2] + p1[3];
      sm += __shfl_xor(sm, 16);
      sm += __shfl_xor(sm, 32);
      sacc[0][tt] = p0;
      sacc[1][tt] = p1;
      mx4[tt] = mx;
      if (lg == 0)
        *(float2*)&red[tt * 16 + l15][w * 2] = make_float2(mx, sm);
    }
    BARSYNC();  // [A]

    // ---- per-lane redundant merge for rows t = tt*16 + l15 ----
    float fac_p[4];
    {
      bool changed = false;
#pragma unroll
      for (int tt = 0; tt < 4; ++tt) {
        const int row = tt * 16 + l15;
        float4 r0 = *(const float4*)&red[row][0];
        float4 r1 = *(const float4*)&red[row][4];
        float4 r2 = *(const float4*)&red[row][8];
        float4 r3 = *(const float4*)&red[row][12];
        float mc = fmaxf(m_run[tt],
                   fmaxf(fmaxf(fmaxf(r0.x, r0.z), fmaxf(r1.x, r1.z)),
                         fmaxf(fmaxf(r2.x, r2.z), fmaxf(r3.x, r3.z))));
        const float m_new = (mc - m_run[tt] <= 11.0f) ? m_run[tt] : mc;
        float l_new = l_run[tt] * exp2f(m_run[tt] - m_new);
        l_new += r0.y * exp2f(r0.x - m_new) + r0.w * exp2f(r0.z - m_new);
        l_new += r1.y * exp2f(r1.x - m_new) + r1.w * exp2f(r1.z - m_new);
        l_new += r2.y * exp2f(r2.x - m_new) + r2.w * exp2f(r2.z - m_new);
        l_new += r3.y * exp2f(r3.x - m_new) + r3.w * exp2f(r3.z - m_new);
        fac_p[tt] = exp2f(mx4[tt] - m_new);
        if (m_new != m_run[tt]) changed = true;
        if (w == 0 && lg == 0) {
          fin_fac[row] = exp2f(m_run[tt] - m_new);
          if (st == 7) fin_invl[row] = 1.0f / l_new;
        }
        m_run[tt] = m_new;
        l_run[tt] = l_new;
      }
      if (w == 0 && changed) flagv[st & 1] = 1.0f;
    }
    // ---- P-write sh0: packed b64, swizzled [t][s-local] ----
#pragma unroll
    for (int tt = 0; tt < 4; ++tt) {
      const f32x4 pe = sacc[0][tt];
      const float fp = fac_p[tt];
      ushort4 pk = make_ushort4(f2h(pe[0] * fp), f2h(pe[1] * fp),
                                f2h(pe[2] * fp), f2h(pe[3] * fp));
      *(ushort4*)(pPw + tt * 4096) = pk;
    }
    BARSYNC();  // [B] — Ps(sh0) + fin stable

    // ---- rescale (uniform skip via defer-max flag) ----
    {
      const float fl = flagv[st & 1];
      if (fl != 0.f) {
#pragma unroll
        for (int mt = 0; mt < 4; ++mt) {
          const f32x4 fac = *(const f32x4*)&fin_fac[mt * 16 + lg * 4];
#pragma unroll
          for (int ch = 0; ch < 2; ++ch)
#pragma unroll
            for (int nt = 0; nt < 2; ++nt) {
              pvm[mt][ch][nt] *= fac;
              pvs[mt][ch][nt] *= fac;
            }
        }
      }
      if (tid == 0) flagv[(st + 1) & 1] = 0.f;
    }

    // ---- PV: 2 halves x 8 phases; P-frags held across ch ----
#pragma unroll
    for (int half = 0; half < 2; ++half) {
      if (half == 1) {
        BARSYNC();  // [C] — half0 done reading Ps
#pragma unroll
        for (int tt = 0; tt < 4; ++tt) {
          const f32x4 pe = sacc[1][tt];
          const float fp = fac_p[tt];
          ushort4 pk = make_ushort4(f2h(pe[0] * fp), f2h(pe[1] * fp),
                                    f2h(pe[2] * fp), f2h(pe[3] * fp));
          *(ushort4*)(pPw + tt * 4096) = pk;
        }
        BARSYNC();  // [D] — Ps(sh1) stable
      }
      f16x8 pf0, pf1, pf2, pf3;
#pragma unroll
      for (int pp = 0; pp < 8; ++pp) {
        const int P_ = half * 8 + pp;
        asm volatile("s_waitcnt vmcnt(2)" ::: "memory");
        const int bf = P_ & 1;
        const int ch = pp & 1, ksl = pp >> 1;
        if (ch == 0) {
          pf0 = readPa(0, ksl);
          pf1 = readPa(1, ksl);
          pf2 = readPa(2, ksl);
          pf3 = readPa(3, ksl);
        }
        f16x8 h0 = readH(bf, 0), h1 = readH(bf, 1);
        f16x8 q0 = h0 * h0, q1 = h1 * h1;
        __builtin_amdgcn_s_setprio(1);
        pvm[0][ch][0] = mfma16(pf0, h0, pvm[0][ch][0]);
        pvm[1][ch][0] = mfma16(pf1, h0, pvm[1][ch][0]);
        pvm[2][ch][0] = mfma16(pf2, h0, pvm[2][ch][0]);
        pvm[3][ch][0] = mfma16(pf3, h0, pvm[3][ch][0]);
        pvs[0][ch][0] = mfma16(pf0, q0, pvs[0][ch][0]);
        pvs[1][ch][0] = mfma16(pf1, q0, pvs[1][ch][0]);
        pvs[2][ch][0] = mfma16(pf2, q0, pvs[2][ch][0]);
        pvs[3][ch][0] = mfma16(pf3, q0, pvs[3][ch][0]);
        pvm[0][ch][1] = mfma16(pf0, h1, pvm[0][ch][1]);
        pvm[1][ch][1] = mfma16(pf1, h1, pvm[1][ch][1]);
        pvm[2][ch][1] = mfma16(pf2, h1, pvm[2][ch][1]);
        pvm[3][ch][1] = mfma16(pf3, h1, pvm[3][ch][1]);
        pvs[0][ch][1] = mfma16(pf0, q1, pvs[0][ch][1]);
        pvs[1][ch][1] = mfma16(pf1, q1, pvs[1][ch][1]);
        pvs[2][ch][1] = mfma16(pf2, q1, pvs[2][ch][1]);
        pvs[3][ch][1] = mfma16(pf3, q1, pvs[3][ch][1]);
        __builtin_amdgcn_s_setprio(0);
        const int pn = P_ + 2;
        if (pn < 16) stageH2(pn, bf);
        else stageGn(pn - 16, bf, dnext);  // next tile G chunks (0,0),(0,1)
      }
    }
  }
  asm volatile("s_waitcnt vmcnt(0)" ::: "memory");

  // ---- epilogue: out[b][c][t] = std * (content - cm)*cr + mean ----
  f32x4 invq[4];
#pragma unroll
  for (int mt = 0; mt < 4; ++mt)
    invq[mt] = *(const f32x4*)&fin_invl[mt * 16 + lg * 4];
#pragma unroll
  for (int ch = 0; ch < 2; ++ch)
#pragma unroll
    for (int nt = 0; nt < 2; ++nt) {
      const int c = ch * 256 + w * 32 + nt * 16 + l15;
      const size_t row = (size_t)b * C_ + c;
      const float cm = cmean[row];
      const float cr = crstd[row];
      const float* cp = content + row * TC + t0;
      float* op = out + row * TC + t0;
#pragma unroll
      for (int mt = 0; mt < 4; ++mt) {
        const int q0 = mt * 16 + lg * 4;
        const float4 x = *(const float4*)(cp + q0);
        const f32x4 mu = pvm[mt][ch][nt] * invq[mt];
        const f32x4 se = pvs[mt][ch][nt] * invq[mt];
        float4 y;
        y.x = sqrtf(fmaxf(se[0] - mu[0] * mu[0], 0.f)) * ((x.x - cm) * cr) + mu[0];
        y.y = sqrtf(fmaxf(se[1] - mu[1] * mu[1], 0.f)) * ((x.y - cm) * cr) + mu[1];
        y.z = sqrtf(fmaxf(se[2] - mu[2] * mu[2], 0.f)) * ((x.z - cm) * cr) + mu[2];
        y.w = sqrtf(fmaxf(se[3] - mu[3] * mu[3], 0.f)) * ((x.w - cm) * cr) + mu[3];
        *(float4*)(op + q0) = y;
      }
    }
}

extern "C" void kernel_launch(void* const* d_in, const int* in_sizes, int n_in,
                              void* d_out, int out_size, void* d_ws, size_t ws_size,
                              hipStream_t stream) {
  (void)in_sizes;
  (void)n_in;
  (void)out_size;
  (void)ws_size;  // needs ~96 MB
  const float* content = (const float*)d_in[0];
  const float* style = (const float*)d_in[1];
  const float* content_key = (const float*)d_in[2];
  const float* style_key = (const float*)d_in[3];
  const float* Wf = (const float*)d_in[4];
  const float* bf = (const float*)d_in[5];
  const float* Wg = (const float*)d_in[6];
  const float* bg = (const float*)d_in[7];
  const float* Wh = (const float*)d_in[8];
  const float* bh = (const float*)d_in[9];
  float* out = (float*)d_out;

  char* ws = (char*)d_ws;
  float* Wfg = (float*)(ws);                       // 1 MB
  float* wbeta = (float*)(ws + 1048576);           // 2 KB
  float* bprime = (float*)(ws + 1048576 + 4096);   // 2 KB
  float* c0p = (float*)(ws + 1048576 + 8192);      // 4 B
  float* beta = (float*)(ws + 1048576 + 12288);    // 64 KB
  u16* Gt = (u16*)(ws + 67108864);
  u16* Hm = (u16*)(ws + 83886080);
  float* cmean = (float*)(ws + 100663296);
  float* crstd = (float*)(ws + 100663296 + 16384);

  k_content_stats<<<dim3(B_ * C_), dim3(256), 0, stream>>>(content, cmean, crstd);
  k_wfg<<<dim3(8, 2), dim3(256), 0, stream>>>(Wf, Wg, Wfg);
  k_wbeta<<<dim3(8), dim3(256), 0, stream>>>(Wf, Wg, bf, bg, wbeta, bprime, c0p);
  // G' conv (+beta fused) and H conv in one launch
  k_conv2<<<dim3(TS / 64, 2, 16), dim3(256), 0, stream>>>(
      style_key, Wfg, bprime, Gt, style, Wh, bh, Hm, wbeta, c0p, beta);

  k_attn<<<dim3(1024), dim3(512), 0, stream>>>(content_key, Gt, Hm, beta, content,
                                               cmean, crstd, out);
}